// Round 1
// baseline (1612.722 us; speedup 1.0000x reference)
//
#include <hip/hip_runtime.h>

#define IN_CH 500
#define KSTEPS 10

typedef unsigned int u32;
typedef unsigned short u16;
typedef short bf16x8 __attribute__((ext_vector_type(8)));
typedef float f32x4 __attribute__((ext_vector_type(4)));

__device__ __forceinline__ float bf2f(u16 u) {
    union { u32 i; float f; } v; v.i = ((u32)u) << 16; return v.f;
}
__device__ __forceinline__ u16 f2bf(float f) {
    union { float f; u32 i; } v; v.f = f;
    u32 x = v.i;
    return (u16)((x + 0x7FFFu + ((x >> 16) & 1u)) >> 16);  // RNE
}

// ---------------- runtime dtype detection ----------------
// flags[0] = 1 if float tensors are f32 storage (else bf16)
// flags[1] = 1 if edge_index is int64 storage (else int32)
__global__ void detect_kernel(const u16* __restrict__ w1raw,
                              const int* __restrict__ ei,
                              u32* __restrict__ flags) {
    int t = threadIdx.x;  // 64 threads
    float m = fabsf(bf2f(w1raw[t]));
    m = fmaxf(m, fabsf(bf2f(w1raw[64 + t])));
    m = fmaxf(m, fabsf(bf2f(w1raw[128 + t])));
    for (int off = 32; off; off >>= 1) m = fmaxf(m, __shfl_down(m, off));
    u32 o = (u32)ei[2 * t + 1];
    o |= (u32)ei[2 * t + 129];
    for (int off = 32; off; off >>= 1) o |= __shfl_down(o, off);
    if (t == 0) {
        flags[0] = (m > 10.0f) ? 1u : 0u;
        flags[1] = (o == 0u) ? 1u : 0u;
    }
}

// ---------------- W1 transpose precompute (bf16 path) ----------------
// W1T[hid][k] bf16, [64][512], zero-padded for k >= 500. Lives in dead
// workspace (oGB region, not written until prop step 1).
__global__ void w1t_kernel(const void* __restrict__ W1v, u16* __restrict__ w1tg,
                           const u32* __restrict__ flags) {
    int i = blockIdx.x * 256 + threadIdx.x;   // 0 .. 32767
    if (i >= 64 * 512) return;
    int hid = i >> 9;
    int k = i & 511;
    u16 v = 0;
    if (k < IN_CH) {
        if (flags[0]) v = f2bf(((const float*)W1v)[(size_t)k * 64 + hid]);
        else          v = ((const u16*)W1v)[(size_t)k * 64 + hid];
    }
    w1tg[(size_t)hid * 512 + k] = v;
}

// ---------------- MLP, bf16 storage: MFMA path ----------------
// Block = 64 nodes, 256 threads (4 waves). Wave w computes nodes 16w..16w+15
// x all 64 hid via 4x mfma_f32_16x16x32_bf16 per K-chunk.
// A = W1T (M=hid) from LDS, B = x (N=node) straight from global (read once).
// W1T LDS (66560B) is reused as the f32 hh buffer for layer 2 after a barrier.
__global__ __launch_bounds__(256) void mlp_mfma_kernel(
    const u16* __restrict__ xh, const u16* __restrict__ w1tg,
    const void* __restrict__ b1v, const void* __restrict__ W2v,
    const void* __restrict__ b2v, float* __restrict__ h0,
    const u32* __restrict__ flags, int N)
{
    if (flags[0] != 0u) return;          // f32 storage -> mlp_kernel handles it

    __shared__ u16 w1s[64 * 520];        // W1T staged, stride 520 (16B-aligned rows)
    __shared__ float w2s[64][16];
    __shared__ float b1s[64];
    __shared__ float b2s[16];
    float* hh = (float*)w1s;             // aliased after K-loop: [hid][65] f32

    const u16* b1h = (const u16*)b1v;
    const u16* W2h = (const u16*)W2v;
    const u16* b2h = (const u16*)b2v;

    const int t = threadIdx.x;
    const int w = t >> 6;                // wave 0..3
    const int l = t & 63;                // lane
    const int ln = l & 15;
    const int g = l >> 4;                // k-group 0..3
    const int nodeBase = blockIdx.x * 64;

    for (int i = t; i < 1024; i += 256) w2s[i >> 4][i & 15] = bf2f(W2h[i]);
    if (t < 64) b1s[t] = bf2f(b1h[t]);
    if (t < 16) b2s[t] = bf2f(b2h[t]);

    // stage W1T global -> LDS: one row (64 x 16B chunks) per wave-iteration
#pragma unroll
    for (int i = 0; i < 16; ++i) {
        int idx = t + i * 256;
        int row = idx >> 6, c8 = idx & 63;
        *(bf16x8*)&w1s[row * 520 + c8 * 8] =
            *(const bf16x8*)(w1tg + (size_t)row * 512 + c8 * 8);
    }
    __syncthreads();

    const int node = nodeBase + w * 16 + ln;     // this lane's B-column node
    const bool nv = (node < N);
    const u16* xrow = xh + (size_t)node * IN_CH;

    f32x4 acc0 = {0.f, 0.f, 0.f, 0.f};
    f32x4 acc1 = {0.f, 0.f, 0.f, 0.f};
    f32x4 acc2 = {0.f, 0.f, 0.f, 0.f};
    f32x4 acc3 = {0.f, 0.f, 0.f, 0.f};

#pragma unroll
    for (int ki = 0; ki < 15; ++ki) {            // k = 0 .. 479, all full
        const int kb = ki * 32 + g * 8;
        bf16x8 b = {0, 0, 0, 0, 0, 0, 0, 0};
        if (nv) b = *(const bf16x8*)(xrow + kb);
        const u16* wp = &w1s[ln * 520 + kb];
        bf16x8 a0 = *(const bf16x8*)(wp);
        bf16x8 a1 = *(const bf16x8*)(wp + 16 * 520);
        bf16x8 a2 = *(const bf16x8*)(wp + 32 * 520);
        bf16x8 a3 = *(const bf16x8*)(wp + 48 * 520);
        acc0 = __builtin_amdgcn_mfma_f32_16x16x32_bf16(a0, b, acc0, 0, 0, 0);
        acc1 = __builtin_amdgcn_mfma_f32_16x16x32_bf16(a1, b, acc1, 0, 0, 0);
        acc2 = __builtin_amdgcn_mfma_f32_16x16x32_bf16(a2, b, acc2, 0, 0, 0);
        acc3 = __builtin_amdgcn_mfma_f32_16x16x32_bf16(a3, b, acc3, 0, 0, 0);
    }
    {   // tail: k = 480..499 valid; W1T zero-padded to 512 so only fault-safety
        const int kb = 480 + g * 8;
        bf16x8 b = {0, 0, 0, 0, 0, 0, 0, 0};
        if (nv) {
            if (g < 2) {
                b = *(const bf16x8*)(xrow + kb);
            } else if (g == 2) {                  // k = 496..499 only
                ushort4 v4 = *(const ushort4*)(xrow + 496);
                b[0] = (short)v4.x; b[1] = (short)v4.y;
                b[2] = (short)v4.z; b[3] = (short)v4.w;
            }
        }
        const u16* wp = &w1s[ln * 520 + kb];
        bf16x8 a0 = *(const bf16x8*)(wp);
        bf16x8 a1 = *(const bf16x8*)(wp + 16 * 520);
        bf16x8 a2 = *(const bf16x8*)(wp + 32 * 520);
        bf16x8 a3 = *(const bf16x8*)(wp + 48 * 520);
        acc0 = __builtin_amdgcn_mfma_f32_16x16x32_bf16(a0, b, acc0, 0, 0, 0);
        acc1 = __builtin_amdgcn_mfma_f32_16x16x32_bf16(a1, b, acc1, 0, 0, 0);
        acc2 = __builtin_amdgcn_mfma_f32_16x16x32_bf16(a2, b, acc2, 0, 0, 0);
        acc3 = __builtin_amdgcn_mfma_f32_16x16x32_bf16(a3, b, acc3, 0, 0, 0);
    }
    __syncthreads();    // all waves done reading w1s; reuse it as hh

    // layer-1 epilogue: bias + relu -> hh[hid][node_local]
    // D layout: col = lane&15 (node), row = (lane>>4)*4 + r (hid within tile)
    const int nl = w * 16 + ln;
    const int rbase = g * 4;
#pragma unroll
    for (int r = 0; r < 4; ++r) {
        float v0 = acc0[r] + b1s[rbase + r];
        float v1 = acc1[r] + b1s[16 + rbase + r];
        float v2 = acc2[r] + b1s[32 + rbase + r];
        float v3 = acc3[r] + b1s[48 + rbase + r];
        hh[(rbase + r) * 65 + nl]      = v0 > 0.f ? v0 : 0.f;
        hh[(16 + rbase + r) * 65 + nl] = v1 > 0.f ? v1 : 0.f;
        hh[(32 + rbase + r) * 65 + nl] = v2 > 0.f ? v2 : 0.f;
        hh[(48 + rbase + r) * 65 + nl] = v3 > 0.f ? v3 : 0.f;
    }
    __syncthreads();

    // layer 2: [64 nodes] x [64 hid] @ [64][16] + b2
    {
        int n = t >> 2;
        int o4 = (t & 3) * 4;
        float o0 = b2s[o4], o1 = b2s[o4 + 1], o2 = b2s[o4 + 2], o3 = b2s[o4 + 3];
#pragma unroll
        for (int j = 0; j < 64; ++j) {
            float hv = hh[j * 65 + n];
            o0 += hv * w2s[j][o4];     o1 += hv * w2s[j][o4 + 1];
            o2 += hv * w2s[j][o4 + 2]; o3 += hv * w2s[j][o4 + 3];
        }
        int gn = nodeBase + n;
        if (gn < N) {
            float4 o = {o0, o1, o2, o3};
            *(float4*)(h0 + (size_t)gn * 16 + o4) = o;
        }
    }
}

// ---------------- MLP, f32 storage: exact VALU fallback ----------------
__global__ __launch_bounds__(256) void mlp_kernel(
    const void* __restrict__ xv, const void* __restrict__ W1v,
    const void* __restrict__ b1v, const void* __restrict__ W2v,
    const void* __restrict__ b2v, float* __restrict__ h0,
    const u32* __restrict__ flags, int N)
{
    if (flags[0] == 0u) return;          // bf16 storage -> mlp_mfma_kernel

    __shared__ float xs[32][64];    // [k][node]
    __shared__ float ws1[32][64];   // [k][hid]
    __shared__ float hh[64][65];    // [node][hid], +1 pad
    __shared__ float w2s[64][16];
    __shared__ float b1s[64];
    __shared__ float b2s[16];

    const float* xf  = (const float*)xv;
    const float* W1f = (const float*)W1v;
    const float* b1f = (const float*)b1v;
    const float* W2f = (const float*)W2v;
    const float* b2f = (const float*)b2v;

    const int t = threadIdx.x;
    const int tx = t & 15;          // hid quad: tx*4
    const int ty = t >> 4;          // node quad: ty*4
    const int nodeBase = blockIdx.x * 64;

    for (int i = t; i < 1024; i += 256) w2s[i >> 4][i & 15] = W2f[i];
    if (t < 64) b1s[t] = b1f[t];
    if (t < 16) b2s[t] = b2f[t];

    float acc[4][4];
#pragma unroll
    for (int r = 0; r < 4; ++r)
#pragma unroll
        for (int c = 0; c < 4; ++c) acc[r][c] = 0.f;

    for (int k0 = 0; k0 < 512; k0 += 32) {   // K padded 500->512 with zeros
        __syncthreads();
#pragma unroll
        for (int rr = 0; rr < 2; ++rr) {
            int r = t + rr * 256;
            int n = r >> 3, q = r & 7;
            int k = k0 + q * 4;
            int gn = nodeBase + n;
            float f0 = 0.f, f1 = 0.f, f2 = 0.f, f3 = 0.f;
            if (gn < N && k + 3 < IN_CH) {
                float4 v = *(const float4*)(xf + (size_t)gn * IN_CH + k);
                f0 = v.x; f1 = v.y; f2 = v.z; f3 = v.w;
            }
            xs[q * 4 + 0][n] = f0; xs[q * 4 + 1][n] = f1;
            xs[q * 4 + 2][n] = f2; xs[q * 4 + 3][n] = f3;
        }
#pragma unroll
        for (int rr = 0; rr < 2; ++rr) {
            int r = t + rr * 256;
            int krow = r >> 4, cq = r & 15;
            int k = k0 + krow;
            float f0 = 0.f, f1 = 0.f, f2 = 0.f, f3 = 0.f;
            if (k < IN_CH) {
                float4 v = *(const float4*)(W1f + (size_t)k * 64 + cq * 4);
                f0 = v.x; f1 = v.y; f2 = v.z; f3 = v.w;
            }
            ws1[krow][cq * 4 + 0] = f0; ws1[krow][cq * 4 + 1] = f1;
            ws1[krow][cq * 4 + 2] = f2; ws1[krow][cq * 4 + 3] = f3;
        }
        __syncthreads();
#pragma unroll
        for (int kk = 0; kk < 32; ++kk) {
            const float4 a = *(const float4*)&xs[kk][ty * 4];
            const float4 b = *(const float4*)&ws1[kk][tx * 4];
            float av[4] = {a.x, a.y, a.z, a.w};
            float bv[4] = {b.x, b.y, b.z, b.w};
#pragma unroll
            for (int r = 0; r < 4; ++r)
#pragma unroll
                for (int c = 0; c < 4; ++c) acc[r][c] += av[r] * bv[c];
        }
    }
#pragma unroll
    for (int r = 0; r < 4; ++r)
#pragma unroll
        for (int c = 0; c < 4; ++c) {
            float v = acc[r][c] + b1s[tx * 4 + c];
            hh[ty * 4 + r][tx * 4 + c] = v > 0.f ? v : 0.f;
        }
    __syncthreads();
    {
        int n = t >> 2;
        int o4 = (t & 3) * 4;
        float o0 = b2s[o4], o1 = b2s[o4 + 1], o2 = b2s[o4 + 2], o3 = b2s[o4 + 3];
#pragma unroll
        for (int j = 0; j < 64; ++j) {
            float hv = hh[n][j];
            o0 += hv * w2s[j][o4];     o1 += hv * w2s[j][o4 + 1];
            o2 += hv * w2s[j][o4 + 2]; o3 += hv * w2s[j][o4 + 3];
        }
        int gn = nodeBase + n;
        if (gn < N) {
            float4 o = {o0, o1, o2, o3};
            *(float4*)(h0 + (size_t)gn * 16 + o4) = o;
        }
    }
}

// ---------------- graph preprocessing ----------------
__global__ void zero_u32(u32* __restrict__ p, int n) {
    int i = blockIdx.x * 256 + threadIdx.x;
    if (i < n) p[i] = 0u;
}

__device__ __forceinline__ int ei_src(const int* ei, int E, int e, int i64) {
    return i64 ? ei[2 * e] : ei[e];
}
__device__ __forceinline__ int ei_dst(const int* ei, int E, int e, int i64) {
    return i64 ? ei[2 * (E + e)] : ei[E + e];
}

__global__ void deg_kernel(const int* __restrict__ ei, int E, u32* __restrict__ cnt,
                           const u32* __restrict__ flags) {
    int e = blockIdx.x * 256 + threadIdx.x;
    int i64 = (int)flags[1];
    if (e < E) atomicAdd(&cnt[ei_dst(ei, E, e, i64)], 1u);
}

__global__ void dinv_kernel(const u32* __restrict__ cnt, float* __restrict__ dinv, int N) {
    int i = blockIdx.x * 256 + threadIdx.x;
    if (i < N) {
        float d = (float)(cnt[i] + 1u);      // +1 self-loop
        dinv[i] = rsqrtf(d);
    }
}

__global__ __launch_bounds__(256) void scan1(const u32* __restrict__ cnt,
                                             u32* __restrict__ part, int N) {
    __shared__ u32 s[256];
    int i = blockIdx.x * 256 + threadIdx.x;
    s[threadIdx.x] = (i < N) ? cnt[i] : 0u;
    __syncthreads();
    for (int off = 128; off > 0; off >>= 1) {
        if (threadIdx.x < off) s[threadIdx.x] += s[threadIdx.x + off];
        __syncthreads();
    }
    if (threadIdx.x == 0) part[blockIdx.x] = s[0];
}

__global__ __launch_bounds__(512) void scan2(u32* __restrict__ part,
                                             u32* __restrict__ rowptr, int NB, int N) {
    __shared__ u32 s[512];
    int t = threadIdx.x;
    u32 v = (t < NB) ? part[t] : 0u;
    s[t] = v;
    __syncthreads();
    for (int off = 1; off < 512; off <<= 1) {
        u32 xv = (t >= off) ? s[t - off] : 0u;
        __syncthreads();
        s[t] += xv;
        __syncthreads();
    }
    if (t < NB) part[t] = s[t] - v;          // exclusive block offsets
    if (t == 511) rowptr[N] = s[511];        // total = E
}

__global__ __launch_bounds__(256) void scan3(const u32* __restrict__ cnt,
                                             const u32* __restrict__ part,
                                             u32* __restrict__ rowptr, int N) {
    __shared__ u32 s[256];
    int t = threadIdx.x;
    int i = blockIdx.x * 256 + t;
    u32 v = (i < N) ? cnt[i] : 0u;
    s[t] = v;
    __syncthreads();
    for (int off = 1; off < 256; off <<= 1) {
        u32 xv = (t >= off) ? s[t - off] : 0u;
        __syncthreads();
        s[t] += xv;
        __syncthreads();
    }
    if (i < N) rowptr[i] = part[blockIdx.x] + s[t] - v;
}

// CSR by target; payload = source index only (weights folded into dinv scaling)
__global__ void fill_kernel(const int* __restrict__ ei, int E,
                            const u32* __restrict__ rowptr, u32* __restrict__ fillc,
                            u32* __restrict__ ent, const u32* __restrict__ flags) {
    int e = blockIdx.x * 256 + threadIdx.x;
    int i64 = (int)flags[1];
    if (e < E) {
        int r = ei_src(ei, E, e, i64), c = ei_dst(ei, E, e, i64);
        u32 p = rowptr[c] + atomicAdd(&fillc[c], 1u);
        ent[p] = (u32)r;
    }
}

// g0 = dinv .* h0
__global__ void init_g(const float* __restrict__ h0, const float* __restrict__ dinv,
                       float* __restrict__ g, int N) {
    int i = blockIdx.x * 256 + threadIdx.x;
    if (i < N * 16) g[i] = dinv[i >> 4] * h0[i];
}

// ---------------- APPNP pull step on scaled state g = D^-1/2 h ----------------
__global__ __launch_bounds__(256) void prop_kernel(
    const u32* __restrict__ ent, const u32* __restrict__ rowptr,
    const float* __restrict__ dinv, const float* __restrict__ gcur,
    const float* __restrict__ h0, float* __restrict__ gnext,
    void* __restrict__ outp, const u32* __restrict__ flags, int N)
{
    int g = blockIdx.x * 256 + threadIdx.x;
    int n = g >> 4;
    int c = g & 15;
    if (n >= N) return;
    u32 p = rowptr[n], pend = rowptr[n + 1];
    float s = gcur[(size_t)n * 16 + c];          // self loop
    for (; p < pend; ++p) {
        u32 r = ent[p];
        s += gcur[(size_t)r * 16 + c];
    }
    float dn = dinv[n];
    float h = 0.9f * dn * s + 0.1f * h0[(size_t)n * 16 + c];
    if (gnext) {
        gnext[(size_t)n * 16 + c] = dn * h;
    } else {
        if (flags[0]) ((float*)outp)[(size_t)n * 16 + c] = h;
        else          ((u16*)outp)[(size_t)n * 16 + c] = f2bf(h);
    }
}

extern "C" void kernel_launch(void* const* d_in, const int* in_sizes, int n_in,
                              void* d_out, int out_size, void* d_ws, size_t ws_size,
                              hipStream_t stream) {
    const void* x  = d_in[0];
    const int* ei  = (const int*)d_in[1];
    const void* W1 = d_in[2];
    const void* b1 = d_in[3];
    const void* W2 = d_in[4];
    const void* b2 = d_in[5];

    const int N = in_sizes[0] / IN_CH;     // 100000
    const int E = in_sizes[1] / 2;         // 3200000

    float* wf = (float*)d_ws;
    u32*   wu = (u32*)d_ws;

    // workspace layout (4B units), total ~ 33.5 MB
    size_t oH0   = 0;
    size_t oGA   = oH0 + (size_t)N * 16;
    size_t oGB   = oGA + (size_t)N * 16;
    size_t oCNT  = oGB + (size_t)N * 16;
    size_t oFILL = oCNT + N;
    size_t oDINV = oFILL + N;
    size_t oRP   = oDINV + N;
    size_t oPART = ((oRP + N + 1 + 3) & ~(size_t)3);
    size_t oFLG  = oPART + 512;
    size_t oENT  = oFLG + 4;

    // W1T scratch (64 KB) overlaid on oGB: dead until prop step 1 writes oGB,
    // and mlp runs strictly before that.
    u16* w1tg = (u16*)(wf + oGB);

    detect_kernel<<<1, 64, 0, stream>>>((const u16*)W1, ei, wu + oFLG);
    w1t_kernel<<<128, 256, 0, stream>>>(W1, w1tg, wu + oFLG);
    zero_u32<<<(2 * N + 255) / 256, 256, 0, stream>>>(wu + oCNT, 2 * N);
    mlp_kernel<<<(N + 63) / 64, 256, 0, stream>>>(x, W1, b1, W2, b2, wf + oH0,
                                                  wu + oFLG, N);
    mlp_mfma_kernel<<<(N + 63) / 64, 256, 0, stream>>>(
        (const u16*)x, w1tg, b1, W2, b2, wf + oH0, wu + oFLG, N);
    deg_kernel<<<(E + 255) / 256, 256, 0, stream>>>(ei, E, wu + oCNT, wu + oFLG);
    dinv_kernel<<<(N + 255) / 256, 256, 0, stream>>>(wu + oCNT, wf + oDINV, N);
    int NB = (N + 255) / 256;
    scan1<<<NB, 256, 0, stream>>>(wu + oCNT, wu + oPART, N);
    scan2<<<1, 512, 0, stream>>>(wu + oPART, wu + oRP, NB, N);
    scan3<<<NB, 256, 0, stream>>>(wu + oCNT, wu + oPART, wu + oRP, N);
    fill_kernel<<<(E + 255) / 256, 256, 0, stream>>>(ei, E, wu + oRP, wu + oFILL,
                                                     wu + oENT, wu + oFLG);
    init_g<<<(N * 16 + 255) / 256, 256, 0, stream>>>(wf + oH0, wf + oDINV, wf + oGA, N);

    const float* cur = wf + oGA;
    for (int k = 0; k < KSTEPS; ++k) {
        bool last = (k == KSTEPS - 1);
        float* nxt = last ? nullptr : (wf + ((k & 1) ? oGA : oGB));
        prop_kernel<<<(N * 16 + 255) / 256, 256, 0, stream>>>(
            wu + oENT, wu + oRP, wf + oDINV, cur, wf + oH0,
            nxt, last ? d_out : nullptr, wu + oFLG, N);
        if (!last) cur = nxt;
    }
}

// Round 2
// 1511.230 us; speedup vs baseline: 1.0672x; 1.0672x over previous
//
#include <hip/hip_runtime.h>

#define IN_CH 500
#define KSTEPS 10

typedef unsigned int u32;
typedef unsigned short u16;
typedef short bf16x8 __attribute__((ext_vector_type(8)));
typedef float f32x4 __attribute__((ext_vector_type(4)));

__device__ __forceinline__ float bf2f(u16 u) {
    union { u32 i; float f; } v; v.i = ((u32)u) << 16; return v.f;
}
__device__ __forceinline__ u16 f2bf(float f) {
    union { float f; u32 i; } v; v.f = f;
    u32 x = v.i;
    return (u16)((x + 0x7FFFu + ((x >> 16) & 1u)) >> 16);  // RNE
}
__device__ __forceinline__ u32 f_as_u(float f) {
    union { float f; u32 i; } v; v.f = f; return v.i;
}
__device__ __forceinline__ float u_as_f(u32 i) {
    union { u32 i; float f; } v; v.i = i; return v.f;
}

// ---------------- runtime dtype detection ----------------
// flags[0] = 1 if float tensors are f32 storage (else bf16)
// flags[1] = 1 if edge_index is int64 storage (else int32)
__global__ void detect_kernel(const u16* __restrict__ w1raw,
                              const int* __restrict__ ei,
                              u32* __restrict__ flags) {
    int t = threadIdx.x;  // 64 threads
    float m = fabsf(bf2f(w1raw[t]));
    m = fmaxf(m, fabsf(bf2f(w1raw[64 + t])));
    m = fmaxf(m, fabsf(bf2f(w1raw[128 + t])));
    for (int off = 32; off; off >>= 1) m = fmaxf(m, __shfl_down(m, off));
    u32 o = (u32)ei[2 * t + 1];
    o |= (u32)ei[2 * t + 129];
    for (int off = 32; off; off >>= 1) o |= __shfl_down(o, off);
    if (t == 0) {
        flags[0] = (m > 10.0f) ? 1u : 0u;
        flags[1] = (o == 0u) ? 1u : 0u;
    }
}

// ---------------- W1 transpose + hi/lo split precompute ----------------
// W1T_hi/W1T_lo [64 hid][512 k] bf16, zero-padded k>=500.
// f32 storage: hi = trunc-to-bf16(v), lo = trunc-to-bf16(v - hi)  (v-hi exact)
// bf16 storage: hi = value, lo = 0.
__global__ void w1t_kernel(const void* __restrict__ W1v,
                           u16* __restrict__ hi, u16* __restrict__ lo,
                           const u32* __restrict__ flags) {
    int i = blockIdx.x * 256 + threadIdx.x;   // 0 .. 32767
    if (i >= 64 * 512) return;
    int h = i >> 9;
    int k = i & 511;
    u16 vh = 0, vl = 0;
    if (k < IN_CH) {
        if (flags[0]) {
            float v = ((const float*)W1v)[(size_t)k * 64 + h];
            u32 bits = f_as_u(v);
            vh = (u16)(bits >> 16);
            float d = v - u_as_f(bits & 0xFFFF0000u);
            vl = (u16)(f_as_u(d) >> 16);
        } else {
            vh = ((const u16*)W1v)[(size_t)k * 64 + h];
        }
    }
    hi[(size_t)h * 512 + k] = vh;
    lo[(size_t)h * 512 + k] = vl;
}

// ---------------- MLP, f32 storage: split-bf16 MFMA path ----------------
// 128 nodes/block, 512 threads (8 waves, 2/SIMD). Wave w owns nodes
// base+16w..16w+15 x all 64 hid. x@W1 = xhi@Whi + xlo@Whi + xhi@Wlo
// (xlo@Wlo dropped, ~2^-16 rel). A = W1T from LDS (hi+lo, stride 520:
// 2-way banks = free), B = x f32 from global (read once), split in-reg.
// Epilogue: bias+relu -> LDS, exact f32 layer 2, write h0 AND g0=dinv*h0.
__global__ __launch_bounds__(512) void mlp_mfma_f32(
    const float* __restrict__ xf, const u16* __restrict__ w1hig,
    const u16* __restrict__ w1log, const float* __restrict__ b1f,
    const float* __restrict__ W2f, const float* __restrict__ b2f,
    const float* __restrict__ dinv, float* __restrict__ h0,
    float* __restrict__ gout, const u32* __restrict__ flags, int N)
{
    if (flags[0] == 0u) return;          // bf16 storage -> mlp_mfma_kernel

    __shared__ __align__(16) u16 w1hi[64 * 520];
    __shared__ __align__(16) u16 w1lo[64 * 520];
    __shared__ float w2s[64][16];
    __shared__ float b1s[64];
    __shared__ float b2s[16];
    float* hh = (float*)w1hi;            // aliased after K-loop: [64][130]

    const int t = threadIdx.x;
    const int w = t >> 6;                // wave 0..7
    const int l = t & 63;
    const int ln = l & 15;               // node within wave tile
    const int g = l >> 4;                // k-subgroup 0..3
    const int nodeBase = blockIdx.x * 128;

    for (int i = t; i < 1024; i += 512) w2s[i >> 4][i & 15] = W2f[i];
    if (t < 64) b1s[t] = b1f[t];
    if (t < 16) b2s[t] = b2f[t];

    // stage W1T hi+lo -> LDS (rows 1024B global, 1040B LDS stride)
#pragma unroll
    for (int i = 0; i < 8; ++i) {
        int c = t + i * 512;
        int row = c >> 6, c8 = c & 63;
        *(bf16x8*)&w1hi[row * 520 + c8 * 8] =
            *(const bf16x8*)(w1hig + (size_t)row * 512 + c8 * 8);
        *(bf16x8*)&w1lo[row * 520 + c8 * 8] =
            *(const bf16x8*)(w1log + (size_t)row * 512 + c8 * 8);
    }
    __syncthreads();

    const int node = nodeBase + w * 16 + ln;
    const bool nv = (node < N);
    const float* xrow = xf + (size_t)node * IN_CH;

    f32x4 acc0 = {0.f, 0.f, 0.f, 0.f};
    f32x4 acc1 = {0.f, 0.f, 0.f, 0.f};
    f32x4 acc2 = {0.f, 0.f, 0.f, 0.f};
    f32x4 acc3 = {0.f, 0.f, 0.f, 0.f};

#pragma unroll
    for (int ki = 0; ki < 16; ++ki) {
        const int kb = ki * 32 + g * 8;
        float xv[8];
#pragma unroll
        for (int e = 0; e < 8; ++e) xv[e] = 0.f;
        if (nv) {
            if (kb + 8 <= IN_CH) {                 // all iters except tail g>=2
                float4 v0 = *(const float4*)(xrow + kb);
                float4 v1 = *(const float4*)(xrow + kb + 4);
                xv[0] = v0.x; xv[1] = v0.y; xv[2] = v0.z; xv[3] = v0.w;
                xv[4] = v1.x; xv[5] = v1.y; xv[6] = v1.z; xv[7] = v1.w;
            } else if (kb < IN_CH) {               // kb==496: 4 valid floats
                float4 v0 = *(const float4*)(xrow + kb);
                xv[0] = v0.x; xv[1] = v0.y; xv[2] = v0.z; xv[3] = v0.w;
            }
        }
        bf16x8 bh, bl;
#pragma unroll
        for (int e = 0; e < 8; ++e) {
            u32 bits = f_as_u(xv[e]);
            bh[e] = (short)(bits >> 16);                       // trunc hi
            float d = xv[e] - u_as_f(bits & 0xFFFF0000u);      // exact residual
            bl[e] = (short)(f_as_u(d) >> 16);                  // trunc lo
        }
        const u16* ph = &w1hi[ln * 520 + kb];
        const u16* pl = &w1lo[ln * 520 + kb];
        bf16x8 ah0 = *(const bf16x8*)(ph);
        bf16x8 ah1 = *(const bf16x8*)(ph + 16 * 520);
        bf16x8 ah2 = *(const bf16x8*)(ph + 32 * 520);
        bf16x8 ah3 = *(const bf16x8*)(ph + 48 * 520);
        bf16x8 al0 = *(const bf16x8*)(pl);
        bf16x8 al1 = *(const bf16x8*)(pl + 16 * 520);
        bf16x8 al2 = *(const bf16x8*)(pl + 32 * 520);
        bf16x8 al3 = *(const bf16x8*)(pl + 48 * 520);
        acc0 = __builtin_amdgcn_mfma_f32_16x16x32_bf16(ah0, bh, acc0, 0, 0, 0);
        acc1 = __builtin_amdgcn_mfma_f32_16x16x32_bf16(ah1, bh, acc1, 0, 0, 0);
        acc2 = __builtin_amdgcn_mfma_f32_16x16x32_bf16(ah2, bh, acc2, 0, 0, 0);
        acc3 = __builtin_amdgcn_mfma_f32_16x16x32_bf16(ah3, bh, acc3, 0, 0, 0);
        acc0 = __builtin_amdgcn_mfma_f32_16x16x32_bf16(al0, bh, acc0, 0, 0, 0);
        acc1 = __builtin_amdgcn_mfma_f32_16x16x32_bf16(al1, bh, acc1, 0, 0, 0);
        acc2 = __builtin_amdgcn_mfma_f32_16x16x32_bf16(al2, bh, acc2, 0, 0, 0);
        acc3 = __builtin_amdgcn_mfma_f32_16x16x32_bf16(al3, bh, acc3, 0, 0, 0);
        acc0 = __builtin_amdgcn_mfma_f32_16x16x32_bf16(ah0, bl, acc0, 0, 0, 0);
        acc1 = __builtin_amdgcn_mfma_f32_16x16x32_bf16(ah1, bl, acc1, 0, 0, 0);
        acc2 = __builtin_amdgcn_mfma_f32_16x16x32_bf16(ah2, bl, acc2, 0, 0, 0);
        acc3 = __builtin_amdgcn_mfma_f32_16x16x32_bf16(ah3, bl, acc3, 0, 0, 0);
    }
    __syncthreads();    // all waves done reading w1hi; reuse it as hh

    // layer-1 epilogue: bias + relu -> hh[hid][node_local]
    // D layout: col = lane&15 (node), row = (lane>>4)*4 + r
    const int nl = w * 16 + ln;
    const int rb = g * 4;
#pragma unroll
    for (int r = 0; r < 4; ++r) {
        float v0 = acc0[r] + b1s[rb + r];
        float v1 = acc1[r] + b1s[16 + rb + r];
        float v2 = acc2[r] + b1s[32 + rb + r];
        float v3 = acc3[r] + b1s[48 + rb + r];
        hh[(rb + r) * 130 + nl]      = v0 > 0.f ? v0 : 0.f;
        hh[(16 + rb + r) * 130 + nl] = v1 > 0.f ? v1 : 0.f;
        hh[(32 + rb + r) * 130 + nl] = v2 > 0.f ? v2 : 0.f;
        hh[(48 + rb + r) * 130 + nl] = v3 > 0.f ? v3 : 0.f;
    }
    __syncthreads();

    // layer 2: [128 nodes] x [64 hid] @ [64][16] + b2; also g0 = dinv*h0
    {
        int n = t >> 2;                  // 0..127
        int o4 = (t & 3) * 4;
        float o0 = b2s[o4], o1 = b2s[o4 + 1], o2 = b2s[o4 + 2], o3 = b2s[o4 + 3];
#pragma unroll
        for (int j = 0; j < 64; ++j) {
            float hv = hh[j * 130 + n];
            o0 += hv * w2s[j][o4];     o1 += hv * w2s[j][o4 + 1];
            o2 += hv * w2s[j][o4 + 2]; o3 += hv * w2s[j][o4 + 3];
        }
        int gn = nodeBase + n;
        if (gn < N) {
            float4 o = {o0, o1, o2, o3};
            *(float4*)(h0 + (size_t)gn * 16 + o4) = o;
            float dn = dinv[gn];
            float4 gg = {o0 * dn, o1 * dn, o2 * dn, o3 * dn};
            *(float4*)(gout + (size_t)gn * 16 + o4) = gg;
        }
    }
}

// ---------------- MLP, bf16 storage: MFMA path (hi array only) ----------------
__global__ __launch_bounds__(256) void mlp_mfma_kernel(
    const u16* __restrict__ xh, const u16* __restrict__ w1tg,
    const void* __restrict__ b1v, const void* __restrict__ W2v,
    const void* __restrict__ b2v, const float* __restrict__ dinv,
    float* __restrict__ h0, float* __restrict__ gout,
    const u32* __restrict__ flags, int N)
{
    if (flags[0] != 0u) return;          // f32 storage -> mlp_mfma_f32

    __shared__ __align__(16) u16 w1s[64 * 520];
    __shared__ float w2s[64][16];
    __shared__ float b1s[64];
    __shared__ float b2s[16];
    float* hh = (float*)w1s;             // aliased after K-loop: [hid][65] f32

    const u16* b1h = (const u16*)b1v;
    const u16* W2h = (const u16*)W2v;
    const u16* b2h = (const u16*)b2v;

    const int t = threadIdx.x;
    const int w = t >> 6;                // wave 0..3
    const int l = t & 63;
    const int ln = l & 15;
    const int g = l >> 4;
    const int nodeBase = blockIdx.x * 64;

    for (int i = t; i < 1024; i += 256) w2s[i >> 4][i & 15] = bf2f(W2h[i]);
    if (t < 64) b1s[t] = bf2f(b1h[t]);
    if (t < 16) b2s[t] = bf2f(b2h[t]);

#pragma unroll
    for (int i = 0; i < 16; ++i) {
        int idx = t + i * 256;
        int row = idx >> 6, c8 = idx & 63;
        *(bf16x8*)&w1s[row * 520 + c8 * 8] =
            *(const bf16x8*)(w1tg + (size_t)row * 512 + c8 * 8);
    }
    __syncthreads();

    const int node = nodeBase + w * 16 + ln;
    const bool nv = (node < N);
    const u16* xrow = xh + (size_t)node * IN_CH;

    f32x4 acc0 = {0.f, 0.f, 0.f, 0.f};
    f32x4 acc1 = {0.f, 0.f, 0.f, 0.f};
    f32x4 acc2 = {0.f, 0.f, 0.f, 0.f};
    f32x4 acc3 = {0.f, 0.f, 0.f, 0.f};

#pragma unroll
    for (int ki = 0; ki < 15; ++ki) {
        const int kb = ki * 32 + g * 8;
        bf16x8 b = {0, 0, 0, 0, 0, 0, 0, 0};
        if (nv) b = *(const bf16x8*)(xrow + kb);
        const u16* wp = &w1s[ln * 520 + kb];
        bf16x8 a0 = *(const bf16x8*)(wp);
        bf16x8 a1 = *(const bf16x8*)(wp + 16 * 520);
        bf16x8 a2 = *(const bf16x8*)(wp + 32 * 520);
        bf16x8 a3 = *(const bf16x8*)(wp + 48 * 520);
        acc0 = __builtin_amdgcn_mfma_f32_16x16x32_bf16(a0, b, acc0, 0, 0, 0);
        acc1 = __builtin_amdgcn_mfma_f32_16x16x32_bf16(a1, b, acc1, 0, 0, 0);
        acc2 = __builtin_amdgcn_mfma_f32_16x16x32_bf16(a2, b, acc2, 0, 0, 0);
        acc3 = __builtin_amdgcn_mfma_f32_16x16x32_bf16(a3, b, acc3, 0, 0, 0);
    }
    {   // tail: k = 480..499 valid
        const int kb = 480 + g * 8;
        bf16x8 b = {0, 0, 0, 0, 0, 0, 0, 0};
        if (nv) {
            if (g < 2) {
                b = *(const bf16x8*)(xrow + kb);
            } else if (g == 2) {
                ushort4 v4 = *(const ushort4*)(xrow + 496);
                b[0] = (short)v4.x; b[1] = (short)v4.y;
                b[2] = (short)v4.z; b[3] = (short)v4.w;
            }
        }
        const u16* wp = &w1s[ln * 520 + kb];
        bf16x8 a0 = *(const bf16x8*)(wp);
        bf16x8 a1 = *(const bf16x8*)(wp + 16 * 520);
        bf16x8 a2 = *(const bf16x8*)(wp + 32 * 520);
        bf16x8 a3 = *(const bf16x8*)(wp + 48 * 520);
        acc0 = __builtin_amdgcn_mfma_f32_16x16x32_bf16(a0, b, acc0, 0, 0, 0);
        acc1 = __builtin_amdgcn_mfma_f32_16x16x32_bf16(a1, b, acc1, 0, 0, 0);
        acc2 = __builtin_amdgcn_mfma_f32_16x16x32_bf16(a2, b, acc2, 0, 0, 0);
        acc3 = __builtin_amdgcn_mfma_f32_16x16x32_bf16(a3, b, acc3, 0, 0, 0);
    }
    __syncthreads();

    const int nl = w * 16 + ln;
    const int rb = g * 4;
#pragma unroll
    for (int r = 0; r < 4; ++r) {
        float v0 = acc0[r] + b1s[rb + r];
        float v1 = acc1[r] + b1s[16 + rb + r];
        float v2 = acc2[r] + b1s[32 + rb + r];
        float v3 = acc3[r] + b1s[48 + rb + r];
        hh[(rb + r) * 65 + nl]      = v0 > 0.f ? v0 : 0.f;
        hh[(16 + rb + r) * 65 + nl] = v1 > 0.f ? v1 : 0.f;
        hh[(32 + rb + r) * 65 + nl] = v2 > 0.f ? v2 : 0.f;
        hh[(48 + rb + r) * 65 + nl] = v3 > 0.f ? v3 : 0.f;
    }
    __syncthreads();

    {
        int n = t >> 2;
        int o4 = (t & 3) * 4;
        float o0 = b2s[o4], o1 = b2s[o4 + 1], o2 = b2s[o4 + 2], o3 = b2s[o4 + 3];
#pragma unroll
        for (int j = 0; j < 64; ++j) {
            float hv = hh[j * 65 + n];
            o0 += hv * w2s[j][o4];     o1 += hv * w2s[j][o4 + 1];
            o2 += hv * w2s[j][o4 + 2]; o3 += hv * w2s[j][o4 + 3];
        }
        int gn = nodeBase + n;
        if (gn < N) {
            float4 o = {o0, o1, o2, o3};
            *(float4*)(h0 + (size_t)gn * 16 + o4) = o;
            float dn = dinv[gn];
            float4 gg = {o0 * dn, o1 * dn, o2 * dn, o3 * dn};
            *(float4*)(gout + (size_t)gn * 16 + o4) = gg;
        }
    }
}

// ---------------- graph preprocessing ----------------
__global__ void zero_u32(u32* __restrict__ p, int n) {
    int i = blockIdx.x * 256 + threadIdx.x;
    if (i < n) p[i] = 0u;
}

__device__ __forceinline__ int ei_src(const int* ei, int E, int e, int i64) {
    return i64 ? ei[2 * e] : ei[e];
}
__device__ __forceinline__ int ei_dst(const int* ei, int E, int e, int i64) {
    return i64 ? ei[2 * (E + e)] : ei[E + e];
}

__global__ void deg_kernel(const int* __restrict__ ei, int E, u32* __restrict__ cnt,
                           const u32* __restrict__ flags) {
    int e = blockIdx.x * 256 + threadIdx.x;
    int i64 = (int)flags[1];
    if (e < E) atomicAdd(&cnt[ei_dst(ei, E, e, i64)], 1u);
}

__global__ void dinv_kernel(const u32* __restrict__ cnt, float* __restrict__ dinv, int N) {
    int i = blockIdx.x * 256 + threadIdx.x;
    if (i < N) {
        float d = (float)(cnt[i] + 1u);      // +1 self-loop
        dinv[i] = rsqrtf(d);
    }
}

__global__ __launch_bounds__(256) void scan1(const u32* __restrict__ cnt,
                                             u32* __restrict__ part, int N) {
    __shared__ u32 s[256];
    int i = blockIdx.x * 256 + threadIdx.x;
    s[threadIdx.x] = (i < N) ? cnt[i] : 0u;
    __syncthreads();
    for (int off = 128; off > 0; off >>= 1) {
        if (threadIdx.x < off) s[threadIdx.x] += s[threadIdx.x + off];
        __syncthreads();
    }
    if (threadIdx.x == 0) part[blockIdx.x] = s[0];
}

__global__ __launch_bounds__(512) void scan2(u32* __restrict__ part,
                                             u32* __restrict__ rowptr, int NB, int N) {
    __shared__ u32 s[512];
    int t = threadIdx.x;
    u32 v = (t < NB) ? part[t] : 0u;
    s[t] = v;
    __syncthreads();
    for (int off = 1; off < 512; off <<= 1) {
        u32 xv = (t >= off) ? s[t - off] : 0u;
        __syncthreads();
        s[t] += xv;
        __syncthreads();
    }
    if (t < NB) part[t] = s[t] - v;          // exclusive block offsets
    if (t == 511) rowptr[N] = s[511];        // total = E
}

__global__ __launch_bounds__(256) void scan3(const u32* __restrict__ cnt,
                                             const u32* __restrict__ part,
                                             u32* __restrict__ rowptr, int N) {
    __shared__ u32 s[256];
    int t = threadIdx.x;
    int i = blockIdx.x * 256 + t;
    u32 v = (i < N) ? cnt[i] : 0u;
    s[t] = v;
    __syncthreads();
    for (int off = 1; off < 256; off <<= 1) {
        u32 xv = (t >= off) ? s[t - off] : 0u;
        __syncthreads();
        s[t] += xv;
        __syncthreads();
    }
    if (i < N) rowptr[i] = part[blockIdx.x] + s[t] - v;
}

// CSR by target; payload = source index only (weights folded into dinv scaling)
__global__ void fill_kernel(const int* __restrict__ ei, int E,
                            const u32* __restrict__ rowptr, u32* __restrict__ fillc,
                            u32* __restrict__ ent, const u32* __restrict__ flags) {
    int e = blockIdx.x * 256 + threadIdx.x;
    int i64 = (int)flags[1];
    if (e < E) {
        int r = ei_src(ei, E, e, i64), c = ei_dst(ei, E, e, i64);
        u32 p = rowptr[c] + atomicAdd(&fillc[c], 1u);
        ent[p] = (u32)r;
    }
}

// ---------------- APPNP pull step on scaled state g = D^-1/2 h ----------------
__global__ __launch_bounds__(256) void prop_kernel(
    const u32* __restrict__ ent, const u32* __restrict__ rowptr,
    const float* __restrict__ dinv, const float* __restrict__ gcur,
    const float* __restrict__ h0, float* __restrict__ gnext,
    void* __restrict__ outp, const u32* __restrict__ flags, int N)
{
    int g = blockIdx.x * 256 + threadIdx.x;
    int n = g >> 4;
    int c = g & 15;
    if (n >= N) return;
    u32 p = rowptr[n], pend = rowptr[n + 1];
    float s = gcur[(size_t)n * 16 + c];          // self loop
    for (; p < pend; ++p) {
        u32 r = ent[p];
        s += gcur[(size_t)r * 16 + c];
    }
    float dn = dinv[n];
    float h = 0.9f * dn * s + 0.1f * h0[(size_t)n * 16 + c];
    if (gnext) {
        gnext[(size_t)n * 16 + c] = dn * h;
    } else {
        if (flags[0]) ((float*)outp)[(size_t)n * 16 + c] = h;
        else          ((u16*)outp)[(size_t)n * 16 + c] = f2bf(h);
    }
}

extern "C" void kernel_launch(void* const* d_in, const int* in_sizes, int n_in,
                              void* d_out, int out_size, void* d_ws, size_t ws_size,
                              hipStream_t stream) {
    const void* x  = d_in[0];
    const int* ei  = (const int*)d_in[1];
    const void* W1 = d_in[2];
    const void* b1 = d_in[3];
    const void* W2 = d_in[4];
    const void* b2 = d_in[5];

    const int N = in_sizes[0] / IN_CH;     // 100000
    const int E = in_sizes[1] / 2;         // 3200000

    float* wf = (float*)d_ws;
    u32*   wu = (u32*)d_ws;

    // workspace layout (4B units), total ~ 33.5 MB
    size_t oH0   = 0;
    size_t oGA   = oH0 + (size_t)N * 16;
    size_t oGB   = oGA + (size_t)N * 16;
    size_t oCNT  = oGB + (size_t)N * 16;
    size_t oFILL = oCNT + N;
    size_t oDINV = oFILL + N;
    size_t oRP   = oDINV + N;
    size_t oPART = ((oRP + N + 1 + 3) & ~(size_t)3);
    size_t oFLG  = oPART + 512;
    size_t oENT  = oFLG + 4;

    // W1T hi/lo scratch (128 KB) overlaid on oGB: dead until prop step 1
    // writes oGB, and the mlp kernels run strictly before that.
    u16* w1hig = (u16*)(wf + oGB);
    u16* w1log = w1hig + 64 * 512;

    detect_kernel<<<1, 64, 0, stream>>>((const u16*)W1, ei, wu + oFLG);
    w1t_kernel<<<128, 256, 0, stream>>>(W1, w1hig, w1log, wu + oFLG);
    zero_u32<<<(2 * N + 255) / 256, 256, 0, stream>>>(wu + oCNT, 2 * N);
    deg_kernel<<<(E + 255) / 256, 256, 0, stream>>>(ei, E, wu + oCNT, wu + oFLG);
    dinv_kernel<<<(N + 255) / 256, 256, 0, stream>>>(wu + oCNT, wf + oDINV, N);
    mlp_mfma_f32<<<(N + 127) / 128, 512, 0, stream>>>(
        (const float*)x, w1hig, w1log, (const float*)b1, (const float*)W2,
        (const float*)b2, wf + oDINV, wf + oH0, wf + oGA, wu + oFLG, N);
    mlp_mfma_kernel<<<(N + 63) / 64, 256, 0, stream>>>(
        (const u16*)x, w1hig, b1, W2, b2, wf + oDINV, wf + oH0, wf + oGA,
        wu + oFLG, N);
    int NB = (N + 255) / 256;
    scan1<<<NB, 256, 0, stream>>>(wu + oCNT, wu + oPART, N);
    scan2<<<1, 512, 0, stream>>>(wu + oPART, wu + oRP, NB, N);
    scan3<<<NB, 256, 0, stream>>>(wu + oCNT, wu + oPART, wu + oRP, N);
    fill_kernel<<<(E + 255) / 256, 256, 0, stream>>>(ei, E, wu + oRP, wu + oFILL,
                                                     wu + oENT, wu + oFLG);

    const float* cur = wf + oGA;
    for (int k = 0; k < KSTEPS; ++k) {
        bool last = (k == KSTEPS - 1);
        float* nxt = last ? nullptr : (wf + ((k & 1) ? oGA : oGB));
        prop_kernel<<<(N * 16 + 255) / 256, 256, 0, stream>>>(
            wu + oENT, wu + oRP, wf + oDINV, cur, wf + oH0,
            nxt, last ? d_out : nullptr, wu + oFLG, N);
        if (!last) cur = nxt;
    }
}

// Round 3
// 1282.108 us; speedup vs baseline: 1.2579x; 1.1787x over previous
//
#include <hip/hip_runtime.h>

#define IN_CH 500
#define KSTEPS 10

typedef unsigned int u32;
typedef unsigned short u16;
typedef short bf16x8 __attribute__((ext_vector_type(8)));
typedef float f32x4 __attribute__((ext_vector_type(4)));

__device__ __forceinline__ float bf2f(u16 u) {
    union { u32 i; float f; } v; v.i = ((u32)u) << 16; return v.f;
}
__device__ __forceinline__ u16 f2bf(float f) {
    union { float f; u32 i; } v; v.f = f;
    u32 x = v.i;
    return (u16)((x + 0x7FFFu + ((x >> 16) & 1u)) >> 16);  // RNE
}
__device__ __forceinline__ u32 f_as_u(float f) {
    union { float f; u32 i; } v; v.f = f; return v.i;
}
__device__ __forceinline__ float u_as_f(u32 i) {
    union { u32 i; float f; } v; v.i = i; return v.f;
}

// ---------------- runtime dtype detection ----------------
// flags[0] = 1 if float tensors are f32 storage (else bf16)
// flags[1] = 1 if edge_index is int64 storage (else int32)
__global__ void detect_kernel(const u16* __restrict__ w1raw,
                              const int* __restrict__ ei,
                              u32* __restrict__ flags) {
    int t = threadIdx.x;  // 64 threads
    float m = fabsf(bf2f(w1raw[t]));
    m = fmaxf(m, fabsf(bf2f(w1raw[64 + t])));
    m = fmaxf(m, fabsf(bf2f(w1raw[128 + t])));
    for (int off = 32; off; off >>= 1) m = fmaxf(m, __shfl_down(m, off));
    u32 o = (u32)ei[2 * t + 1];
    o |= (u32)ei[2 * t + 129];
    for (int off = 32; off; off >>= 1) o |= __shfl_down(o, off);
    if (t == 0) {
        flags[0] = (m > 10.0f) ? 1u : 0u;
        flags[1] = (o == 0u) ? 1u : 0u;
    }
}

// ---------------- W1 transpose + hi/lo split precompute ----------------
// W1T_hi/W1T_lo [64 hid][512 k] bf16, zero-padded k>=500.
// f32 storage: hi = trunc-to-bf16(v), lo = trunc-to-bf16(v - hi)  (v-hi exact)
// bf16 storage: hi = value, lo = 0.
__global__ void w1t_kernel(const void* __restrict__ W1v,
                           u16* __restrict__ hi, u16* __restrict__ lo,
                           const u32* __restrict__ flags) {
    int i = blockIdx.x * 256 + threadIdx.x;   // 0 .. 32767
    if (i >= 64 * 512) return;
    int h = i >> 9;
    int k = i & 511;
    u16 vh = 0, vl = 0;
    if (k < IN_CH) {
        if (flags[0]) {
            float v = ((const float*)W1v)[(size_t)k * 64 + h];
            u32 bits = f_as_u(v);
            vh = (u16)(bits >> 16);
            float d = v - u_as_f(bits & 0xFFFF0000u);
            vl = (u16)(f_as_u(d) >> 16);
        } else {
            vh = ((const u16*)W1v)[(size_t)k * 64 + h];
        }
    }
    hi[(size_t)h * 512 + k] = vh;
    lo[(size_t)h * 512 + k] = vl;
}

// ---------------- MLP, f32 storage: split-bf16 MFMA path ----------------
// 128 nodes/block, 512 threads (8 waves, 2/SIMD). Wave w owns nodes
// base+16w..16w+15 x all 64 hid. x@W1 = xhi@Whi + xlo@Whi + xhi@Wlo
// (xlo@Wlo dropped, ~2^-16 rel). A = W1T from LDS (hi+lo, stride 520:
// 2-way banks = free), B = x f32 from global (read once), split in-reg.
// Epilogue: bias+relu -> LDS, exact f32 layer 2, write h0 AND g0=dinv*h0.
__global__ __launch_bounds__(512) void mlp_mfma_f32(
    const float* __restrict__ xf, const u16* __restrict__ w1hig,
    const u16* __restrict__ w1log, const float* __restrict__ b1f,
    const float* __restrict__ W2f, const float* __restrict__ b2f,
    const float* __restrict__ dinv, float* __restrict__ h0,
    float* __restrict__ gout, const u32* __restrict__ flags, int N)
{
    if (flags[0] == 0u) return;          // bf16 storage -> mlp_mfma_kernel

    __shared__ __align__(16) u16 w1hi[64 * 520];
    __shared__ __align__(16) u16 w1lo[64 * 520];
    __shared__ float w2s[64][16];
    __shared__ float b1s[64];
    __shared__ float b2s[16];
    float* hh = (float*)w1hi;            // aliased after K-loop: [64][130]

    const int t = threadIdx.x;
    const int w = t >> 6;                // wave 0..7
    const int l = t & 63;
    const int ln = l & 15;               // node within wave tile
    const int g = l >> 4;                // k-subgroup 0..3
    const int nodeBase = blockIdx.x * 128;

    for (int i = t; i < 1024; i += 512) w2s[i >> 4][i & 15] = W2f[i];
    if (t < 64) b1s[t] = b1f[t];
    if (t < 16) b2s[t] = b2f[t];

    // stage W1T hi+lo -> LDS (rows 1024B global, 1040B LDS stride)
#pragma unroll
    for (int i = 0; i < 8; ++i) {
        int c = t + i * 512;
        int row = c >> 6, c8 = c & 63;
        *(bf16x8*)&w1hi[row * 520 + c8 * 8] =
            *(const bf16x8*)(w1hig + (size_t)row * 512 + c8 * 8);
        *(bf16x8*)&w1lo[row * 520 + c8 * 8] =
            *(const bf16x8*)(w1log + (size_t)row * 512 + c8 * 8);
    }
    __syncthreads();

    const int node = nodeBase + w * 16 + ln;
    const bool nv = (node < N);
    const float* xrow = xf + (size_t)node * IN_CH;

    f32x4 acc0 = {0.f, 0.f, 0.f, 0.f};
    f32x4 acc1 = {0.f, 0.f, 0.f, 0.f};
    f32x4 acc2 = {0.f, 0.f, 0.f, 0.f};
    f32x4 acc3 = {0.f, 0.f, 0.f, 0.f};

#pragma unroll
    for (int ki = 0; ki < 16; ++ki) {
        const int kb = ki * 32 + g * 8;
        float xv[8];
#pragma unroll
        for (int e = 0; e < 8; ++e) xv[e] = 0.f;
        if (nv) {
            if (kb + 8 <= IN_CH) {                 // all iters except tail g>=2
                float4 v0 = *(const float4*)(xrow + kb);
                float4 v1 = *(const float4*)(xrow + kb + 4);
                xv[0] = v0.x; xv[1] = v0.y; xv[2] = v0.z; xv[3] = v0.w;
                xv[4] = v1.x; xv[5] = v1.y; xv[6] = v1.z; xv[7] = v1.w;
            } else if (kb < IN_CH) {               // kb==496: 4 valid floats
                float4 v0 = *(const float4*)(xrow + kb);
                xv[0] = v0.x; xv[1] = v0.y; xv[2] = v0.z; xv[3] = v0.w;
            }
        }
        bf16x8 bh, bl;
#pragma unroll
        for (int e = 0; e < 8; ++e) {
            u32 bits = f_as_u(xv[e]);
            bh[e] = (short)(bits >> 16);                       // trunc hi
            float d = xv[e] - u_as_f(bits & 0xFFFF0000u);      // exact residual
            bl[e] = (short)(f_as_u(d) >> 16);                  // trunc lo
        }
        const u16* ph = &w1hi[ln * 520 + kb];
        const u16* pl = &w1lo[ln * 520 + kb];
        bf16x8 ah0 = *(const bf16x8*)(ph);
        bf16x8 ah1 = *(const bf16x8*)(ph + 16 * 520);
        bf16x8 ah2 = *(const bf16x8*)(ph + 32 * 520);
        bf16x8 ah3 = *(const bf16x8*)(ph + 48 * 520);
        bf16x8 al0 = *(const bf16x8*)(pl);
        bf16x8 al1 = *(const bf16x8*)(pl + 16 * 520);
        bf16x8 al2 = *(const bf16x8*)(pl + 32 * 520);
        bf16x8 al3 = *(const bf16x8*)(pl + 48 * 520);
        acc0 = __builtin_amdgcn_mfma_f32_16x16x32_bf16(ah0, bh, acc0, 0, 0, 0);
        acc1 = __builtin_amdgcn_mfma_f32_16x16x32_bf16(ah1, bh, acc1, 0, 0, 0);
        acc2 = __builtin_amdgcn_mfma_f32_16x16x32_bf16(ah2, bh, acc2, 0, 0, 0);
        acc3 = __builtin_amdgcn_mfma_f32_16x16x32_bf16(ah3, bh, acc3, 0, 0, 0);
        acc0 = __builtin_amdgcn_mfma_f32_16x16x32_bf16(al0, bh, acc0, 0, 0, 0);
        acc1 = __builtin_amdgcn_mfma_f32_16x16x32_bf16(al1, bh, acc1, 0, 0, 0);
        acc2 = __builtin_amdgcn_mfma_f32_16x16x32_bf16(al2, bh, acc2, 0, 0, 0);
        acc3 = __builtin_amdgcn_mfma_f32_16x16x32_bf16(al3, bh, acc3, 0, 0, 0);
        acc0 = __builtin_amdgcn_mfma_f32_16x16x32_bf16(ah0, bl, acc0, 0, 0, 0);
        acc1 = __builtin_amdgcn_mfma_f32_16x16x32_bf16(ah1, bl, acc1, 0, 0, 0);
        acc2 = __builtin_amdgcn_mfma_f32_16x16x32_bf16(ah2, bl, acc2, 0, 0, 0);
        acc3 = __builtin_amdgcn_mfma_f32_16x16x32_bf16(ah3, bl, acc3, 0, 0, 0);
    }
    __syncthreads();    // all waves done reading w1hi; reuse it as hh

    // layer-1 epilogue: bias + relu -> hh[hid][node_local]
    // D layout: col = lane&15 (node), row = (lane>>4)*4 + r
    const int nl = w * 16 + ln;
    const int rb = g * 4;
#pragma unroll
    for (int r = 0; r < 4; ++r) {
        float v0 = acc0[r] + b1s[rb + r];
        float v1 = acc1[r] + b1s[16 + rb + r];
        float v2 = acc2[r] + b1s[32 + rb + r];
        float v3 = acc3[r] + b1s[48 + rb + r];
        hh[(rb + r) * 130 + nl]      = v0 > 0.f ? v0 : 0.f;
        hh[(16 + rb + r) * 130 + nl] = v1 > 0.f ? v1 : 0.f;
        hh[(32 + rb + r) * 130 + nl] = v2 > 0.f ? v2 : 0.f;
        hh[(48 + rb + r) * 130 + nl] = v3 > 0.f ? v3 : 0.f;
    }
    __syncthreads();

    // layer 2: [128 nodes] x [64 hid] @ [64][16] + b2; also g0 = dinv*h0
    {
        int n = t >> 2;                  // 0..127
        int o4 = (t & 3) * 4;
        float o0 = b2s[o4], o1 = b2s[o4 + 1], o2 = b2s[o4 + 2], o3 = b2s[o4 + 3];
#pragma unroll
        for (int j = 0; j < 64; ++j) {
            float hv = hh[j * 130 + n];
            o0 += hv * w2s[j][o4];     o1 += hv * w2s[j][o4 + 1];
            o2 += hv * w2s[j][o4 + 2]; o3 += hv * w2s[j][o4 + 3];
        }
        int gn = nodeBase + n;
        if (gn < N) {
            float4 o = {o0, o1, o2, o3};
            *(float4*)(h0 + (size_t)gn * 16 + o4) = o;
            float dn = dinv[gn];
            float4 gg = {o0 * dn, o1 * dn, o2 * dn, o3 * dn};
            *(float4*)(gout + (size_t)gn * 16 + o4) = gg;
        }
    }
}

// ---------------- MLP, bf16 storage: MFMA path (hi array only) ----------------
__global__ __launch_bounds__(256) void mlp_mfma_kernel(
    const u16* __restrict__ xh, const u16* __restrict__ w1tg,
    const void* __restrict__ b1v, const void* __restrict__ W2v,
    const void* __restrict__ b2v, const float* __restrict__ dinv,
    float* __restrict__ h0, float* __restrict__ gout,
    const u32* __restrict__ flags, int N)
{
    if (flags[0] != 0u) return;          // f32 storage -> mlp_mfma_f32

    __shared__ __align__(16) u16 w1s[64 * 520];
    __shared__ float w2s[64][16];
    __shared__ float b1s[64];
    __shared__ float b2s[16];
    float* hh = (float*)w1s;             // aliased after K-loop: [hid][65] f32

    const u16* b1h = (const u16*)b1v;
    const u16* W2h = (const u16*)W2v;
    const u16* b2h = (const u16*)b2v;

    const int t = threadIdx.x;
    const int w = t >> 6;                // wave 0..3
    const int l = t & 63;
    const int ln = l & 15;
    const int g = l >> 4;
    const int nodeBase = blockIdx.x * 64;

    for (int i = t; i < 1024; i += 256) w2s[i >> 4][i & 15] = bf2f(W2h[i]);
    if (t < 64) b1s[t] = bf2f(b1h[t]);
    if (t < 16) b2s[t] = bf2f(b2h[t]);

#pragma unroll
    for (int i = 0; i < 16; ++i) {
        int idx = t + i * 256;
        int row = idx >> 6, c8 = idx & 63;
        *(bf16x8*)&w1s[row * 520 + c8 * 8] =
            *(const bf16x8*)(w1tg + (size_t)row * 512 + c8 * 8);
    }
    __syncthreads();

    const int node = nodeBase + w * 16 + ln;
    const bool nv = (node < N);
    const u16* xrow = xh + (size_t)node * IN_CH;

    f32x4 acc0 = {0.f, 0.f, 0.f, 0.f};
    f32x4 acc1 = {0.f, 0.f, 0.f, 0.f};
    f32x4 acc2 = {0.f, 0.f, 0.f, 0.f};
    f32x4 acc3 = {0.f, 0.f, 0.f, 0.f};

#pragma unroll
    for (int ki = 0; ki < 15; ++ki) {
        const int kb = ki * 32 + g * 8;
        bf16x8 b = {0, 0, 0, 0, 0, 0, 0, 0};
        if (nv) b = *(const bf16x8*)(xrow + kb);
        const u16* wp = &w1s[ln * 520 + kb];
        bf16x8 a0 = *(const bf16x8*)(wp);
        bf16x8 a1 = *(const bf16x8*)(wp + 16 * 520);
        bf16x8 a2 = *(const bf16x8*)(wp + 32 * 520);
        bf16x8 a3 = *(const bf16x8*)(wp + 48 * 520);
        acc0 = __builtin_amdgcn_mfma_f32_16x16x32_bf16(a0, b, acc0, 0, 0, 0);
        acc1 = __builtin_amdgcn_mfma_f32_16x16x32_bf16(a1, b, acc1, 0, 0, 0);
        acc2 = __builtin_amdgcn_mfma_f32_16x16x32_bf16(a2, b, acc2, 0, 0, 0);
        acc3 = __builtin_amdgcn_mfma_f32_16x16x32_bf16(a3, b, acc3, 0, 0, 0);
    }
    {   // tail: k = 480..499 valid
        const int kb = 480 + g * 8;
        bf16x8 b = {0, 0, 0, 0, 0, 0, 0, 0};
        if (nv) {
            if (g < 2) {
                b = *(const bf16x8*)(xrow + kb);
            } else if (g == 2) {
                ushort4 v4 = *(const ushort4*)(xrow + 496);
                b[0] = (short)v4.x; b[1] = (short)v4.y;
                b[2] = (short)v4.z; b[3] = (short)v4.w;
            }
        }
        const u16* wp = &w1s[ln * 520 + kb];
        bf16x8 a0 = *(const bf16x8*)(wp);
        bf16x8 a1 = *(const bf16x8*)(wp + 16 * 520);
        bf16x8 a2 = *(const bf16x8*)(wp + 32 * 520);
        bf16x8 a3 = *(const bf16x8*)(wp + 48 * 520);
        acc0 = __builtin_amdgcn_mfma_f32_16x16x32_bf16(a0, b, acc0, 0, 0, 0);
        acc1 = __builtin_amdgcn_mfma_f32_16x16x32_bf16(a1, b, acc1, 0, 0, 0);
        acc2 = __builtin_amdgcn_mfma_f32_16x16x32_bf16(a2, b, acc2, 0, 0, 0);
        acc3 = __builtin_amdgcn_mfma_f32_16x16x32_bf16(a3, b, acc3, 0, 0, 0);
    }
    __syncthreads();

    const int nl = w * 16 + ln;
    const int rb = g * 4;
#pragma unroll
    for (int r = 0; r < 4; ++r) {
        float v0 = acc0[r] + b1s[rb + r];
        float v1 = acc1[r] + b1s[16 + rb + r];
        float v2 = acc2[r] + b1s[32 + rb + r];
        float v3 = acc3[r] + b1s[48 + rb + r];
        hh[(rb + r) * 65 + nl]      = v0 > 0.f ? v0 : 0.f;
        hh[(16 + rb + r) * 65 + nl] = v1 > 0.f ? v1 : 0.f;
        hh[(32 + rb + r) * 65 + nl] = v2 > 0.f ? v2 : 0.f;
        hh[(48 + rb + r) * 65 + nl] = v3 > 0.f ? v3 : 0.f;
    }
    __syncthreads();

    {
        int n = t >> 2;
        int o4 = (t & 3) * 4;
        float o0 = b2s[o4], o1 = b2s[o4 + 1], o2 = b2s[o4 + 2], o3 = b2s[o4 + 3];
#pragma unroll
        for (int j = 0; j < 64; ++j) {
            float hv = hh[j * 65 + n];
            o0 += hv * w2s[j][o4];     o1 += hv * w2s[j][o4 + 1];
            o2 += hv * w2s[j][o4 + 2]; o3 += hv * w2s[j][o4 + 3];
        }
        int gn = nodeBase + n;
        if (gn < N) {
            float4 o = {o0, o1, o2, o3};
            *(float4*)(h0 + (size_t)gn * 16 + o4) = o;
            float dn = dinv[gn];
            float4 gg = {o0 * dn, o1 * dn, o2 * dn, o3 * dn};
            *(float4*)(gout + (size_t)gn * 16 + o4) = gg;
        }
    }
}

// ---------------- graph preprocessing ----------------
__global__ void zero_u32(u32* __restrict__ p, int n) {
    int i = blockIdx.x * 256 + threadIdx.x;
    if (i < n) p[i] = 0u;
}

__device__ __forceinline__ int ei_src(const int* ei, int E, int e, int i64) {
    return i64 ? ei[2 * e] : ei[e];
}
__device__ __forceinline__ int ei_dst(const int* ei, int E, int e, int i64) {
    return i64 ? ei[2 * (E + e)] : ei[E + e];
}

__global__ void deg_kernel(const int* __restrict__ ei, int E, u32* __restrict__ cnt,
                           const u32* __restrict__ flags) {
    int e = blockIdx.x * 256 + threadIdx.x;
    int i64 = (int)flags[1];
    if (e < E) atomicAdd(&cnt[ei_dst(ei, E, e, i64)], 1u);
}

__global__ void dinv_kernel(const u32* __restrict__ cnt, float* __restrict__ dinv, int N) {
    int i = blockIdx.x * 256 + threadIdx.x;
    if (i < N) {
        float d = (float)(cnt[i] + 1u);      // +1 self-loop
        dinv[i] = rsqrtf(d);
    }
}

__global__ __launch_bounds__(256) void scan1(const u32* __restrict__ cnt,
                                             u32* __restrict__ part, int N) {
    __shared__ u32 s[256];
    int i = blockIdx.x * 256 + threadIdx.x;
    s[threadIdx.x] = (i < N) ? cnt[i] : 0u;
    __syncthreads();
    for (int off = 128; off > 0; off >>= 1) {
        if (threadIdx.x < off) s[threadIdx.x] += s[threadIdx.x + off];
        __syncthreads();
    }
    if (threadIdx.x == 0) part[blockIdx.x] = s[0];
}

__global__ __launch_bounds__(512) void scan2(u32* __restrict__ part,
                                             u32* __restrict__ rowptr, int NB, int N) {
    __shared__ u32 s[512];
    int t = threadIdx.x;
    u32 v = (t < NB) ? part[t] : 0u;
    s[t] = v;
    __syncthreads();
    for (int off = 1; off < 512; off <<= 1) {
        u32 xv = (t >= off) ? s[t - off] : 0u;
        __syncthreads();
        s[t] += xv;
        __syncthreads();
    }
    if (t < NB) part[t] = s[t] - v;          // exclusive block offsets
    if (t == 511) rowptr[N] = s[511];        // total = E
}

__global__ __launch_bounds__(256) void scan3(const u32* __restrict__ cnt,
                                             const u32* __restrict__ part,
                                             u32* __restrict__ rowptr, int N) {
    __shared__ u32 s[256];
    int t = threadIdx.x;
    int i = blockIdx.x * 256 + t;
    u32 v = (i < N) ? cnt[i] : 0u;
    s[t] = v;
    __syncthreads();
    for (int off = 1; off < 256; off <<= 1) {
        u32 xv = (t >= off) ? s[t - off] : 0u;
        __syncthreads();
        s[t] += xv;
        __syncthreads();
    }
    if (i < N) rowptr[i] = part[blockIdx.x] + s[t] - v;
}

// CSR by target; payload = source index only (weights folded into dinv scaling)
// ent written nontemporal: random 4B scatter would otherwise RMW-churn 64B
// lines through L2 (measured 197MB WRITE_SIZE for 12.8MB payload).
__global__ void fill_kernel(const int* __restrict__ ei, int E,
                            const u32* __restrict__ rowptr, u32* __restrict__ fillc,
                            u32* __restrict__ ent, const u32* __restrict__ flags) {
    int e = blockIdx.x * 256 + threadIdx.x;
    int i64 = (int)flags[1];
    if (e < E) {
        int r = ei_src(ei, E, e, i64), c = ei_dst(ei, E, e, i64);
        u32 p = rowptr[c] + atomicAdd(&fillc[c], 1u);
        __builtin_nontemporal_store((u32)r, &ent[p]);
    }
}

// ---------------- APPNP pull step on scaled state g = D^-1/2 h ----------------
// Wave per node: lane = (e, c), e = lane>>4 in 0..3 strides the adjacency
// list by 4 with two independent accumulator chains; 2x shfl_xor reduce.
__global__ __launch_bounds__(256) void prop_kernel(
    const u32* __restrict__ ent, const u32* __restrict__ rowptr,
    const float* __restrict__ dinv, const float* __restrict__ gcur,
    const float* __restrict__ h0, float* __restrict__ gnext,
    void* __restrict__ outp, const u32* __restrict__ flags, int N)
{
    const int t = threadIdx.x;
    const int wv = t >> 6;               // wave 0..3 in block
    const int l = t & 63;
    const int c = l & 15;                // channel
    const int e = l >> 4;                // edge subgroup 0..3
    const int n = blockIdx.x * 4 + wv;
    if (n >= N) return;

    const u32 rs = rowptr[n], re = rowptr[n + 1];
    float s0 = 0.f, s1 = 0.f;
    u32 p = rs + e;
    for (; p + 4 < re; p += 8) {         // two independent load chains
        s0 += gcur[(size_t)ent[p] * 16 + c];
        s1 += gcur[(size_t)ent[p + 4] * 16 + c];
    }
    if (p < re) s0 += gcur[(size_t)ent[p] * 16 + c];
    float s = s0 + s1;
    s += __shfl_xor(s, 16);
    s += __shfl_xor(s, 32);

    if (e == 0) {
        s += gcur[(size_t)n * 16 + c];   // self loop
        float dn = dinv[n];
        float h = 0.9f * dn * s + 0.1f * h0[(size_t)n * 16 + c];
        if (gnext) {
            gnext[(size_t)n * 16 + c] = dn * h;
        } else {
            if (flags[0]) ((float*)outp)[(size_t)n * 16 + c] = h;
            else          ((u16*)outp)[(size_t)n * 16 + c] = f2bf(h);
        }
    }
}

extern "C" void kernel_launch(void* const* d_in, const int* in_sizes, int n_in,
                              void* d_out, int out_size, void* d_ws, size_t ws_size,
                              hipStream_t stream) {
    const void* x  = d_in[0];
    const int* ei  = (const int*)d_in[1];
    const void* W1 = d_in[2];
    const void* b1 = d_in[3];
    const void* W2 = d_in[4];
    const void* b2 = d_in[5];

    const int N = in_sizes[0] / IN_CH;     // 100000
    const int E = in_sizes[1] / 2;         // 3200000

    float* wf = (float*)d_ws;
    u32*   wu = (u32*)d_ws;

    // workspace layout (4B units), total ~ 33.5 MB
    size_t oH0   = 0;
    size_t oGA   = oH0 + (size_t)N * 16;
    size_t oGB   = oGA + (size_t)N * 16;
    size_t oCNT  = oGB + (size_t)N * 16;
    size_t oFILL = oCNT + N;
    size_t oDINV = oFILL + N;
    size_t oRP   = oDINV + N;
    size_t oPART = ((oRP + N + 1 + 3) & ~(size_t)3);
    size_t oFLG  = oPART + 512;
    size_t oENT  = oFLG + 4;

    // W1T hi/lo scratch (128 KB) overlaid on oGB: dead until prop step 1
    // writes oGB, and the mlp kernels run strictly before that.
    u16* w1hig = (u16*)(wf + oGB);
    u16* w1log = w1hig + 64 * 512;

    detect_kernel<<<1, 64, 0, stream>>>((const u16*)W1, ei, wu + oFLG);
    w1t_kernel<<<128, 256, 0, stream>>>(W1, w1hig, w1log, wu + oFLG);
    zero_u32<<<(2 * N + 255) / 256, 256, 0, stream>>>(wu + oCNT, 2 * N);
    deg_kernel<<<(E + 255) / 256, 256, 0, stream>>>(ei, E, wu + oCNT, wu + oFLG);
    dinv_kernel<<<(N + 255) / 256, 256, 0, stream>>>(wu + oCNT, wf + oDINV, N);
    mlp_mfma_f32<<<(N + 127) / 128, 512, 0, stream>>>(
        (const float*)x, w1hig, w1log, (const float*)b1, (const float*)W2,
        (const float*)b2, wf + oDINV, wf + oH0, wf + oGA, wu + oFLG, N);
    mlp_mfma_kernel<<<(N + 63) / 64, 256, 0, stream>>>(
        (const u16*)x, w1hig, b1, W2, b2, wf + oDINV, wf + oH0, wf + oGA,
        wu + oFLG, N);
    int NB = (N + 255) / 256;
    scan1<<<NB, 256, 0, stream>>>(wu + oCNT, wu + oPART, N);
    scan2<<<1, 512, 0, stream>>>(wu + oPART, wu + oRP, NB, N);
    scan3<<<NB, 256, 0, stream>>>(wu + oCNT, wu + oPART, wu + oRP, N);
    fill_kernel<<<(E + 255) / 256, 256, 0, stream>>>(ei, E, wu + oRP, wu + oFILL,
                                                     wu + oENT, wu + oFLG);

    const float* cur = wf + oGA;
    for (int k = 0; k < KSTEPS; ++k) {
        bool last = (k == KSTEPS - 1);
        float* nxt = last ? nullptr : (wf + ((k & 1) ? oGA : oGB));
        prop_kernel<<<(N + 3) / 4, 256, 0, stream>>>(
            wu + oENT, wu + oRP, wf + oDINV, cur, wf + oH0,
            nxt, last ? d_out : nullptr, wu + oFLG, N);
        if (!last) cur = nxt;
    }
}

// Round 4
// 1227.991 us; speedup vs baseline: 1.3133x; 1.0441x over previous
//
#include <hip/hip_runtime.h>

#define IN_CH 500
#define KSTEPS 10

typedef unsigned int u32;
typedef unsigned short u16;
typedef short bf16x8 __attribute__((ext_vector_type(8)));
typedef float f32x4 __attribute__((ext_vector_type(4)));

__device__ __forceinline__ float bf2f(u16 u) {
    union { u32 i; float f; } v; v.i = ((u32)u) << 16; return v.f;
}
__device__ __forceinline__ u16 f2bf(float f) {
    union { float f; u32 i; } v; v.f = f;
    u32 x = v.i;
    return (u16)((x + 0x7FFFu + ((x >> 16) & 1u)) >> 16);  // RNE
}
__device__ __forceinline__ u32 f_as_u(float f) {
    union { float f; u32 i; } v; v.f = f; return v.i;
}
__device__ __forceinline__ float u_as_f(u32 i) {
    union { u32 i; float f; } v; v.i = i; return v.f;
}

// ---------------- runtime dtype detection ----------------
// flags[0] = 1 if float tensors are f32 storage (else bf16)
// flags[1] = 1 if edge_index is int64 storage (else int32)
__global__ void detect_kernel(const u16* __restrict__ w1raw,
                              const int* __restrict__ ei,
                              u32* __restrict__ flags) {
    int t = threadIdx.x;  // 64 threads
    float m = fabsf(bf2f(w1raw[t]));
    m = fmaxf(m, fabsf(bf2f(w1raw[64 + t])));
    m = fmaxf(m, fabsf(bf2f(w1raw[128 + t])));
    for (int off = 32; off; off >>= 1) m = fmaxf(m, __shfl_down(m, off));
    u32 o = (u32)ei[2 * t + 1];
    o |= (u32)ei[2 * t + 129];
    for (int off = 32; off; off >>= 1) o |= __shfl_down(o, off);
    if (t == 0) {
        flags[0] = (m > 10.0f) ? 1u : 0u;
        flags[1] = (o == 0u) ? 1u : 0u;
    }
}

// ---------------- W1 transpose + hi/lo split precompute ----------------
// W1T_hi/W1T_lo [64 hid][512 k] bf16, zero-padded k>=500.
// f32 storage: hi = trunc-to-bf16(v), lo = trunc-to-bf16(v - hi)  (v-hi exact)
// bf16 storage: hi = value, lo = 0.
__global__ void w1t_kernel(const void* __restrict__ W1v,
                           u16* __restrict__ hi, u16* __restrict__ lo,
                           const u32* __restrict__ flags) {
    int i = blockIdx.x * 256 + threadIdx.x;   // 0 .. 32767
    if (i >= 64 * 512) return;
    int h = i >> 9;
    int k = i & 511;
    u16 vh = 0, vl = 0;
    if (k < IN_CH) {
        if (flags[0]) {
            float v = ((const float*)W1v)[(size_t)k * 64 + h];
            u32 bits = f_as_u(v);
            vh = (u16)(bits >> 16);
            float d = v - u_as_f(bits & 0xFFFF0000u);
            vl = (u16)(f_as_u(d) >> 16);
        } else {
            vh = ((const u16*)W1v)[(size_t)k * 64 + h];
        }
    }
    hi[(size_t)h * 512 + k] = vh;
    lo[(size_t)h * 512 + k] = vl;
}

// ---------------- MLP, f32 storage: split-bf16 MFMA path ----------------
// 128 nodes/block, 512 threads (8 waves, 2/SIMD). Wave w owns nodes
// base+16w..16w+15 x all 64 hid. x@W1 = xhi@Whi + xlo@Whi + xhi@Wlo
// (xlo@Wlo dropped, ~2^-16 rel). A = W1T from LDS (hi+lo, stride 520:
// 2-way banks = free), B = x f32 from global (read once), split in-reg.
// Epilogue: bias+relu -> LDS, exact f32 layer 2, write h0 AND g0=dinv*h0.
__global__ __launch_bounds__(512) void mlp_mfma_f32(
    const float* __restrict__ xf, const u16* __restrict__ w1hig,
    const u16* __restrict__ w1log, const float* __restrict__ b1f,
    const float* __restrict__ W2f, const float* __restrict__ b2f,
    const float* __restrict__ dinv, float* __restrict__ h0,
    float* __restrict__ gout, const u32* __restrict__ flags, int N)
{
    if (flags[0] == 0u) return;          // bf16 storage -> mlp_mfma_kernel

    __shared__ __align__(16) u16 w1hi[64 * 520];
    __shared__ __align__(16) u16 w1lo[64 * 520];
    __shared__ float w2s[64][16];
    __shared__ float b1s[64];
    __shared__ float b2s[16];
    float* hh = (float*)w1hi;            // aliased after K-loop: [64][130]

    const int t = threadIdx.x;
    const int w = t >> 6;                // wave 0..7
    const int l = t & 63;
    const int ln = l & 15;               // node within wave tile
    const int g = l >> 4;                // k-subgroup 0..3
    const int nodeBase = blockIdx.x * 128;

    for (int i = t; i < 1024; i += 512) w2s[i >> 4][i & 15] = W2f[i];
    if (t < 64) b1s[t] = b1f[t];
    if (t < 16) b2s[t] = b2f[t];

    // stage W1T hi+lo -> LDS (rows 1024B global, 1040B LDS stride)
#pragma unroll
    for (int i = 0; i < 8; ++i) {
        int c = t + i * 512;
        int row = c >> 6, c8 = c & 63;
        *(bf16x8*)&w1hi[row * 520 + c8 * 8] =
            *(const bf16x8*)(w1hig + (size_t)row * 512 + c8 * 8);
        *(bf16x8*)&w1lo[row * 520 + c8 * 8] =
            *(const bf16x8*)(w1log + (size_t)row * 512 + c8 * 8);
    }
    __syncthreads();

    const int node = nodeBase + w * 16 + ln;
    const bool nv = (node < N);
    const float* xrow = xf + (size_t)node * IN_CH;

    f32x4 acc0 = {0.f, 0.f, 0.f, 0.f};
    f32x4 acc1 = {0.f, 0.f, 0.f, 0.f};
    f32x4 acc2 = {0.f, 0.f, 0.f, 0.f};
    f32x4 acc3 = {0.f, 0.f, 0.f, 0.f};

#pragma unroll
    for (int ki = 0; ki < 16; ++ki) {
        const int kb = ki * 32 + g * 8;
        float xv[8];
#pragma unroll
        for (int e = 0; e < 8; ++e) xv[e] = 0.f;
        if (nv) {
            if (kb + 8 <= IN_CH) {                 // all iters except tail g>=2
                float4 v0 = *(const float4*)(xrow + kb);
                float4 v1 = *(const float4*)(xrow + kb + 4);
                xv[0] = v0.x; xv[1] = v0.y; xv[2] = v0.z; xv[3] = v0.w;
                xv[4] = v1.x; xv[5] = v1.y; xv[6] = v1.z; xv[7] = v1.w;
            } else if (kb < IN_CH) {               // kb==496: 4 valid floats
                float4 v0 = *(const float4*)(xrow + kb);
                xv[0] = v0.x; xv[1] = v0.y; xv[2] = v0.z; xv[3] = v0.w;
            }
        }
        bf16x8 bh, bl;
#pragma unroll
        for (int e = 0; e < 8; ++e) {
            u32 bits = f_as_u(xv[e]);
            bh[e] = (short)(bits >> 16);                       // trunc hi
            float d = xv[e] - u_as_f(bits & 0xFFFF0000u);      // exact residual
            bl[e] = (short)(f_as_u(d) >> 16);                  // trunc lo
        }
        const u16* ph = &w1hi[ln * 520 + kb];
        const u16* pl = &w1lo[ln * 520 + kb];
        bf16x8 ah0 = *(const bf16x8*)(ph);
        bf16x8 ah1 = *(const bf16x8*)(ph + 16 * 520);
        bf16x8 ah2 = *(const bf16x8*)(ph + 32 * 520);
        bf16x8 ah3 = *(const bf16x8*)(ph + 48 * 520);
        bf16x8 al0 = *(const bf16x8*)(pl);
        bf16x8 al1 = *(const bf16x8*)(pl + 16 * 520);
        bf16x8 al2 = *(const bf16x8*)(pl + 32 * 520);
        bf16x8 al3 = *(const bf16x8*)(pl + 48 * 520);
        acc0 = __builtin_amdgcn_mfma_f32_16x16x32_bf16(ah0, bh, acc0, 0, 0, 0);
        acc1 = __builtin_amdgcn_mfma_f32_16x16x32_bf16(ah1, bh, acc1, 0, 0, 0);
        acc2 = __builtin_amdgcn_mfma_f32_16x16x32_bf16(ah2, bh, acc2, 0, 0, 0);
        acc3 = __builtin_amdgcn_mfma_f32_16x16x32_bf16(ah3, bh, acc3, 0, 0, 0);
        acc0 = __builtin_amdgcn_mfma_f32_16x16x32_bf16(al0, bh, acc0, 0, 0, 0);
        acc1 = __builtin_amdgcn_mfma_f32_16x16x32_bf16(al1, bh, acc1, 0, 0, 0);
        acc2 = __builtin_amdgcn_mfma_f32_16x16x32_bf16(al2, bh, acc2, 0, 0, 0);
        acc3 = __builtin_amdgcn_mfma_f32_16x16x32_bf16(al3, bh, acc3, 0, 0, 0);
        acc0 = __builtin_amdgcn_mfma_f32_16x16x32_bf16(ah0, bl, acc0, 0, 0, 0);
        acc1 = __builtin_amdgcn_mfma_f32_16x16x32_bf16(ah1, bl, acc1, 0, 0, 0);
        acc2 = __builtin_amdgcn_mfma_f32_16x16x32_bf16(ah2, bl, acc2, 0, 0, 0);
        acc3 = __builtin_amdgcn_mfma_f32_16x16x32_bf16(ah3, bl, acc3, 0, 0, 0);
    }
    __syncthreads();    // all waves done reading w1hi; reuse it as hh

    // layer-1 epilogue: bias + relu -> hh[hid][node_local]
    // D layout: col = lane&15 (node), row = (lane>>4)*4 + r
    const int nl = w * 16 + ln;
    const int rb = g * 4;
#pragma unroll
    for (int r = 0; r < 4; ++r) {
        float v0 = acc0[r] + b1s[rb + r];
        float v1 = acc1[r] + b1s[16 + rb + r];
        float v2 = acc2[r] + b1s[32 + rb + r];
        float v3 = acc3[r] + b1s[48 + rb + r];
        hh[(rb + r) * 130 + nl]      = v0 > 0.f ? v0 : 0.f;
        hh[(16 + rb + r) * 130 + nl] = v1 > 0.f ? v1 : 0.f;
        hh[(32 + rb + r) * 130 + nl] = v2 > 0.f ? v2 : 0.f;
        hh[(48 + rb + r) * 130 + nl] = v3 > 0.f ? v3 : 0.f;
    }
    __syncthreads();

    // layer 2: [128 nodes] x [64 hid] @ [64][16] + b2; also g0 = dinv*h0
    {
        int n = t >> 2;                  // 0..127
        int o4 = (t & 3) * 4;
        float o0 = b2s[o4], o1 = b2s[o4 + 1], o2 = b2s[o4 + 2], o3 = b2s[o4 + 3];
#pragma unroll
        for (int j = 0; j < 64; ++j) {
            float hv = hh[j * 130 + n];
            o0 += hv * w2s[j][o4];     o1 += hv * w2s[j][o4 + 1];
            o2 += hv * w2s[j][o4 + 2]; o3 += hv * w2s[j][o4 + 3];
        }
        int gn = nodeBase + n;
        if (gn < N) {
            float4 o = {o0, o1, o2, o3};
            *(float4*)(h0 + (size_t)gn * 16 + o4) = o;
            float dn = dinv[gn];
            float4 gg = {o0 * dn, o1 * dn, o2 * dn, o3 * dn};
            *(float4*)(gout + (size_t)gn * 16 + o4) = gg;
        }
    }
}

// ---------------- MLP, bf16 storage: MFMA path (hi array only) ----------------
__global__ __launch_bounds__(256) void mlp_mfma_kernel(
    const u16* __restrict__ xh, const u16* __restrict__ w1tg,
    const void* __restrict__ b1v, const void* __restrict__ W2v,
    const void* __restrict__ b2v, const float* __restrict__ dinv,
    float* __restrict__ h0, float* __restrict__ gout,
    const u32* __restrict__ flags, int N)
{
    if (flags[0] != 0u) return;          // f32 storage -> mlp_mfma_f32

    __shared__ __align__(16) u16 w1s[64 * 520];
    __shared__ float w2s[64][16];
    __shared__ float b1s[64];
    __shared__ float b2s[16];
    float* hh = (float*)w1s;             // aliased after K-loop: [hid][65] f32

    const u16* b1h = (const u16*)b1v;
    const u16* W2h = (const u16*)W2v;
    const u16* b2h = (const u16*)b2v;

    const int t = threadIdx.x;
    const int w = t >> 6;                // wave 0..3
    const int l = t & 63;
    const int ln = l & 15;
    const int g = l >> 4;
    const int nodeBase = blockIdx.x * 64;

    for (int i = t; i < 1024; i += 256) w2s[i >> 4][i & 15] = bf2f(W2h[i]);
    if (t < 64) b1s[t] = bf2f(b1h[t]);
    if (t < 16) b2s[t] = bf2f(b2h[t]);

#pragma unroll
    for (int i = 0; i < 16; ++i) {
        int idx = t + i * 256;
        int row = idx >> 6, c8 = idx & 63;
        *(bf16x8*)&w1s[row * 520 + c8 * 8] =
            *(const bf16x8*)(w1tg + (size_t)row * 512 + c8 * 8);
    }
    __syncthreads();

    const int node = nodeBase + w * 16 + ln;
    const bool nv = (node < N);
    const u16* xrow = xh + (size_t)node * IN_CH;

    f32x4 acc0 = {0.f, 0.f, 0.f, 0.f};
    f32x4 acc1 = {0.f, 0.f, 0.f, 0.f};
    f32x4 acc2 = {0.f, 0.f, 0.f, 0.f};
    f32x4 acc3 = {0.f, 0.f, 0.f, 0.f};

#pragma unroll
    for (int ki = 0; ki < 15; ++ki) {
        const int kb = ki * 32 + g * 8;
        bf16x8 b = {0, 0, 0, 0, 0, 0, 0, 0};
        if (nv) b = *(const bf16x8*)(xrow + kb);
        const u16* wp = &w1s[ln * 520 + kb];
        bf16x8 a0 = *(const bf16x8*)(wp);
        bf16x8 a1 = *(const bf16x8*)(wp + 16 * 520);
        bf16x8 a2 = *(const bf16x8*)(wp + 32 * 520);
        bf16x8 a3 = *(const bf16x8*)(wp + 48 * 520);
        acc0 = __builtin_amdgcn_mfma_f32_16x16x32_bf16(a0, b, acc0, 0, 0, 0);
        acc1 = __builtin_amdgcn_mfma_f32_16x16x32_bf16(a1, b, acc1, 0, 0, 0);
        acc2 = __builtin_amdgcn_mfma_f32_16x16x32_bf16(a2, b, acc2, 0, 0, 0);
        acc3 = __builtin_amdgcn_mfma_f32_16x16x32_bf16(a3, b, acc3, 0, 0, 0);
    }
    {   // tail: k = 480..499 valid
        const int kb = 480 + g * 8;
        bf16x8 b = {0, 0, 0, 0, 0, 0, 0, 0};
        if (nv) {
            if (g < 2) {
                b = *(const bf16x8*)(xrow + kb);
            } else if (g == 2) {
                ushort4 v4 = *(const ushort4*)(xrow + 496);
                b[0] = (short)v4.x; b[1] = (short)v4.y;
                b[2] = (short)v4.z; b[3] = (short)v4.w;
            }
        }
        const u16* wp = &w1s[ln * 520 + kb];
        bf16x8 a0 = *(const bf16x8*)(wp);
        bf16x8 a1 = *(const bf16x8*)(wp + 16 * 520);
        bf16x8 a2 = *(const bf16x8*)(wp + 32 * 520);
        bf16x8 a3 = *(const bf16x8*)(wp + 48 * 520);
        acc0 = __builtin_amdgcn_mfma_f32_16x16x32_bf16(a0, b, acc0, 0, 0, 0);
        acc1 = __builtin_amdgcn_mfma_f32_16x16x32_bf16(a1, b, acc1, 0, 0, 0);
        acc2 = __builtin_amdgcn_mfma_f32_16x16x32_bf16(a2, b, acc2, 0, 0, 0);
        acc3 = __builtin_amdgcn_mfma_f32_16x16x32_bf16(a3, b, acc3, 0, 0, 0);
    }
    __syncthreads();

    const int nl = w * 16 + ln;
    const int rb = g * 4;
#pragma unroll
    for (int r = 0; r < 4; ++r) {
        float v0 = acc0[r] + b1s[rb + r];
        float v1 = acc1[r] + b1s[16 + rb + r];
        float v2 = acc2[r] + b1s[32 + rb + r];
        float v3 = acc3[r] + b1s[48 + rb + r];
        hh[(rb + r) * 65 + nl]      = v0 > 0.f ? v0 : 0.f;
        hh[(16 + rb + r) * 65 + nl] = v1 > 0.f ? v1 : 0.f;
        hh[(32 + rb + r) * 65 + nl] = v2 > 0.f ? v2 : 0.f;
        hh[(48 + rb + r) * 65 + nl] = v3 > 0.f ? v3 : 0.f;
    }
    __syncthreads();

    {
        int n = t >> 2;
        int o4 = (t & 3) * 4;
        float o0 = b2s[o4], o1 = b2s[o4 + 1], o2 = b2s[o4 + 2], o3 = b2s[o4 + 3];
#pragma unroll
        for (int j = 0; j < 64; ++j) {
            float hv = hh[j * 65 + n];
            o0 += hv * w2s[j][o4];     o1 += hv * w2s[j][o4 + 1];
            o2 += hv * w2s[j][o4 + 2]; o3 += hv * w2s[j][o4 + 3];
        }
        int gn = nodeBase + n;
        if (gn < N) {
            float4 o = {o0, o1, o2, o3};
            *(float4*)(h0 + (size_t)gn * 16 + o4) = o;
            float dn = dinv[gn];
            float4 gg = {o0 * dn, o1 * dn, o2 * dn, o3 * dn};
            *(float4*)(gout + (size_t)gn * 16 + o4) = gg;
        }
    }
}

// ---------------- graph preprocessing ----------------
__global__ void zero_u32(u32* __restrict__ p, int n) {
    int i = blockIdx.x * 256 + threadIdx.x;
    if (i < n) p[i] = 0u;
}

__device__ __forceinline__ int ei_src(const int* ei, int E, int e, int i64) {
    return i64 ? ei[2 * e] : ei[e];
}
__device__ __forceinline__ int ei_dst(const int* ei, int E, int e, int i64) {
    return i64 ? ei[2 * (E + e)] : ei[E + e];
}

__global__ void deg_kernel(const int* __restrict__ ei, int E, u32* __restrict__ cnt,
                           const u32* __restrict__ flags) {
    int e = blockIdx.x * 256 + threadIdx.x;
    int i64 = (int)flags[1];
    if (e < E) atomicAdd(&cnt[ei_dst(ei, E, e, i64)], 1u);
}

__global__ void dinv_kernel(const u32* __restrict__ cnt, float* __restrict__ dinv, int N) {
    int i = blockIdx.x * 256 + threadIdx.x;
    if (i < N) {
        float d = (float)(cnt[i] + 1u);      // +1 self-loop
        dinv[i] = rsqrtf(d);
    }
}

__global__ __launch_bounds__(256) void scan1(const u32* __restrict__ cnt,
                                             u32* __restrict__ part, int N) {
    __shared__ u32 s[256];
    int i = blockIdx.x * 256 + threadIdx.x;
    s[threadIdx.x] = (i < N) ? cnt[i] : 0u;
    __syncthreads();
    for (int off = 128; off > 0; off >>= 1) {
        if (threadIdx.x < off) s[threadIdx.x] += s[threadIdx.x + off];
        __syncthreads();
    }
    if (threadIdx.x == 0) part[blockIdx.x] = s[0];
}

__global__ __launch_bounds__(512) void scan2(u32* __restrict__ part,
                                             u32* __restrict__ rowptr, int NB, int N) {
    __shared__ u32 s[512];
    int t = threadIdx.x;
    u32 v = (t < NB) ? part[t] : 0u;
    s[t] = v;
    __syncthreads();
    for (int off = 1; off < 512; off <<= 1) {
        u32 xv = (t >= off) ? s[t - off] : 0u;
        __syncthreads();
        s[t] += xv;
        __syncthreads();
    }
    if (t < NB) part[t] = s[t] - v;          // exclusive block offsets
    if (t == 511) rowptr[N] = s[511];        // total = E
}

__global__ __launch_bounds__(256) void scan3(const u32* __restrict__ cnt,
                                             const u32* __restrict__ part,
                                             u32* __restrict__ rowptr, int N) {
    __shared__ u32 s[256];
    int t = threadIdx.x;
    int i = blockIdx.x * 256 + t;
    u32 v = (i < N) ? cnt[i] : 0u;
    s[t] = v;
    __syncthreads();
    for (int off = 1; off < 256; off <<= 1) {
        u32 xv = (t >= off) ? s[t - off] : 0u;
        __syncthreads();
        s[t] += xv;
        __syncthreads();
    }
    if (i < N) rowptr[i] = part[blockIdx.x] + s[t] - v;
}

// CSR by target; payload = source index only (weights folded into dinv scaling).
// XCD-grouped scatter: random 4B scatter across all 8 XCDs dirties each 64B
// ent line in up to 8 non-coherent per-XCD L2s -> ~16x write amplification
// (measured 199MB WRITE_SIZE for 12.8MB payload). Fix: group = blockIdx&7
// (blockIdx round-robins XCDs), each group owns a dst node range -> each ent
// line is written by one XCD only. Groups grid-stride the full edge list and
// filter by dst range; extra reads are L2/L3-resident.
#define FILL_BPG 128   // blocks per group; grid = 8 * FILL_BPG
__global__ __launch_bounds__(256) void fill_kernel(
    const int* __restrict__ ei, int E,
    const u32* __restrict__ rowptr, u32* __restrict__ fillc,
    u32* __restrict__ ent, const u32* __restrict__ flags, int N)
{
    const int group = blockIdx.x & 7;
    const int bchunk = blockIdx.x >> 3;          // 0..FILL_BPG-1
    const int gsz = (N + 7) / 8;
    const int lo = group * gsz;
    const int hi = (lo + gsz < N) ? lo + gsz : N;
    const int i64 = (int)flags[1];
    const int stride = FILL_BPG * 256;

    for (int e = bchunk * 256 + (int)threadIdx.x; e < E; e += stride) {
        int c = ei_dst(ei, E, e, i64);
        if (c >= lo && c < hi) {
            int r = ei_src(ei, E, e, i64);
            u32 p = rowptr[c] + atomicAdd(&fillc[c], 1u);
            ent[p] = (u32)r;
        }
    }
}

// ---------------- APPNP pull step on scaled state g = D^-1/2 h ----------------
// Wave per node: lane = (e, c), e = lane>>4 in 0..3 strides the adjacency
// list by 4 with two independent accumulator chains; 2x shfl_xor reduce.
__global__ __launch_bounds__(256) void prop_kernel(
    const u32* __restrict__ ent, const u32* __restrict__ rowptr,
    const float* __restrict__ dinv, const float* __restrict__ gcur,
    const float* __restrict__ h0, float* __restrict__ gnext,
    void* __restrict__ outp, const u32* __restrict__ flags, int N)
{
    const int t = threadIdx.x;
    const int wv = t >> 6;               // wave 0..3 in block
    const int l = t & 63;
    const int c = l & 15;                // channel
    const int e = l >> 4;                // edge subgroup 0..3
    const int n = blockIdx.x * 4 + wv;
    if (n >= N) return;

    const u32 rs = rowptr[n], re = rowptr[n + 1];
    float s0 = 0.f, s1 = 0.f;
    u32 p = rs + e;
    for (; p + 4 < re; p += 8) {         // two independent load chains
        s0 += gcur[(size_t)ent[p] * 16 + c];
        s1 += gcur[(size_t)ent[p + 4] * 16 + c];
    }
    if (p < re) s0 += gcur[(size_t)ent[p] * 16 + c];
    float s = s0 + s1;
    s += __shfl_xor(s, 16);
    s += __shfl_xor(s, 32);

    if (e == 0) {
        s += gcur[(size_t)n * 16 + c];   // self loop
        float dn = dinv[n];
        float h = 0.9f * dn * s + 0.1f * h0[(size_t)n * 16 + c];
        if (gnext) {
            gnext[(size_t)n * 16 + c] = dn * h;
        } else {
            if (flags[0]) ((float*)outp)[(size_t)n * 16 + c] = h;
            else          ((u16*)outp)[(size_t)n * 16 + c] = f2bf(h);
        }
    }
}

extern "C" void kernel_launch(void* const* d_in, const int* in_sizes, int n_in,
                              void* d_out, int out_size, void* d_ws, size_t ws_size,
                              hipStream_t stream) {
    const void* x  = d_in[0];
    const int* ei  = (const int*)d_in[1];
    const void* W1 = d_in[2];
    const void* b1 = d_in[3];
    const void* W2 = d_in[4];
    const void* b2 = d_in[5];

    const int N = in_sizes[0] / IN_CH;     // 100000
    const int E = in_sizes[1] / 2;         // 3200000

    float* wf = (float*)d_ws;
    u32*   wu = (u32*)d_ws;

    // workspace layout (4B units), total ~ 33.5 MB
    size_t oH0   = 0;
    size_t oGA   = oH0 + (size_t)N * 16;
    size_t oGB   = oGA + (size_t)N * 16;
    size_t oCNT  = oGB + (size_t)N * 16;
    size_t oFILL = oCNT + N;
    size_t oDINV = oFILL + N;
    size_t oRP   = oDINV + N;
    size_t oPART = ((oRP + N + 1 + 3) & ~(size_t)3);
    size_t oFLG  = oPART + 512;
    size_t oENT  = oFLG + 4;

    // W1T hi/lo scratch (128 KB) overlaid on oGB: dead until prop step 1
    // writes oGB, and the mlp kernels run strictly before that.
    u16* w1hig = (u16*)(wf + oGB);
    u16* w1log = w1hig + 64 * 512;

    detect_kernel<<<1, 64, 0, stream>>>((const u16*)W1, ei, wu + oFLG);
    w1t_kernel<<<128, 256, 0, stream>>>(W1, w1hig, w1log, wu + oFLG);
    zero_u32<<<(2 * N + 255) / 256, 256, 0, stream>>>(wu + oCNT, 2 * N);
    deg_kernel<<<(E + 255) / 256, 256, 0, stream>>>(ei, E, wu + oCNT, wu + oFLG);
    dinv_kernel<<<(N + 255) / 256, 256, 0, stream>>>(wu + oCNT, wf + oDINV, N);
    mlp_mfma_f32<<<(N + 127) / 128, 512, 0, stream>>>(
        (const float*)x, w1hig, w1log, (const float*)b1, (const float*)W2,
        (const float*)b2, wf + oDINV, wf + oH0, wf + oGA, wu + oFLG, N);
    mlp_mfma_kernel<<<(N + 63) / 64, 256, 0, stream>>>(
        (const u16*)x, w1hig, b1, W2, b2, wf + oDINV, wf + oH0, wf + oGA,
        wu + oFLG, N);
    int NB = (N + 255) / 256;
    scan1<<<NB, 256, 0, stream>>>(wu + oCNT, wu + oPART, N);
    scan2<<<1, 512, 0, stream>>>(wu + oPART, wu + oRP, NB, N);
    scan3<<<NB, 256, 0, stream>>>(wu + oCNT, wu + oPART, wu + oRP, N);
    fill_kernel<<<8 * FILL_BPG, 256, 0, stream>>>(ei, E, wu + oRP, wu + oFILL,
                                                  wu + oENT, wu + oFLG, N);

    const float* cur = wf + oGA;
    for (int k = 0; k < KSTEPS; ++k) {
        bool last = (k == KSTEPS - 1);
        float* nxt = last ? nullptr : (wf + ((k & 1) ? oGA : oGB));
        prop_kernel<<<(N + 3) / 4, 256, 0, stream>>>(
            wu + oENT, wu + oRP, wf + oDINV, cur, wf + oH0,
            nxt, last ? d_out : nullptr, wu + oFLG, N);
        if (!last) cur = nxt;
    }
}

// Round 5
// 1018.293 us; speedup vs baseline: 1.5838x; 1.2059x over previous
//
#include <hip/hip_runtime.h>

#define IN_CH 500
#define KSTEPS 10

typedef unsigned int u32;
typedef unsigned short u16;
typedef short bf16x8 __attribute__((ext_vector_type(8)));
typedef float f32x4 __attribute__((ext_vector_type(4)));

__device__ __forceinline__ float bf2f(u16 u) {
    union { u32 i; float f; } v; v.i = ((u32)u) << 16; return v.f;
}
__device__ __forceinline__ u16 f2bf(float f) {
    union { float f; u32 i; } v; v.f = f;
    u32 x = v.i;
    return (u16)((x + 0x7FFFu + ((x >> 16) & 1u)) >> 16);  // RNE
}
__device__ __forceinline__ u32 f_as_u(float f) {
    union { float f; u32 i; } v; v.f = f; return v.i;
}
__device__ __forceinline__ float u_as_f(u32 i) {
    union { u32 i; float f; } v; v.i = i; return v.f;
}

// ---------------- runtime dtype detection ----------------
// flags[0] = 1 if float tensors are f32 storage (else bf16)
// flags[1] = 1 if edge_index is int64 storage (else int32)
__global__ void detect_kernel(const u16* __restrict__ w1raw,
                              const int* __restrict__ ei,
                              u32* __restrict__ flags) {
    int t = threadIdx.x;  // 64 threads
    float m = fabsf(bf2f(w1raw[t]));
    m = fmaxf(m, fabsf(bf2f(w1raw[64 + t])));
    m = fmaxf(m, fabsf(bf2f(w1raw[128 + t])));
    for (int off = 32; off; off >>= 1) m = fmaxf(m, __shfl_down(m, off));
    u32 o = (u32)ei[2 * t + 1];
    o |= (u32)ei[2 * t + 129];
    for (int off = 32; off; off >>= 1) o |= __shfl_down(o, off);
    if (t == 0) {
        flags[0] = (m > 10.0f) ? 1u : 0u;
        flags[1] = (o == 0u) ? 1u : 0u;
    }
}

// ---------------- W1 transpose + hi/lo split precompute ----------------
__global__ void w1t_kernel(const void* __restrict__ W1v,
                           u16* __restrict__ hi, u16* __restrict__ lo,
                           const u32* __restrict__ flags) {
    int i = blockIdx.x * 256 + threadIdx.x;   // 0 .. 32767
    if (i >= 64 * 512) return;
    int h = i >> 9;
    int k = i & 511;
    u16 vh = 0, vl = 0;
    if (k < IN_CH) {
        if (flags[0]) {
            float v = ((const float*)W1v)[(size_t)k * 64 + h];
            u32 bits = f_as_u(v);
            vh = (u16)(bits >> 16);
            float d = v - u_as_f(bits & 0xFFFF0000u);
            vl = (u16)(f_as_u(d) >> 16);
        } else {
            vh = ((const u16*)W1v)[(size_t)k * 64 + h];
        }
    }
    hi[(size_t)h * 512 + k] = vh;
    lo[(size_t)h * 512 + k] = vl;
}

// ---------------- MLP, f32 storage: split-bf16 MFMA path ----------------
__global__ __launch_bounds__(512) void mlp_mfma_f32(
    const float* __restrict__ xf, const u16* __restrict__ w1hig,
    const u16* __restrict__ w1log, const float* __restrict__ b1f,
    const float* __restrict__ W2f, const float* __restrict__ b2f,
    const float* __restrict__ dinv, float* __restrict__ h0,
    float* __restrict__ gout, const u32* __restrict__ flags, int N)
{
    if (flags[0] == 0u) return;          // bf16 storage -> mlp_mfma_kernel

    __shared__ __align__(16) u16 w1hi[64 * 520];
    __shared__ __align__(16) u16 w1lo[64 * 520];
    __shared__ float w2s[64][16];
    __shared__ float b1s[64];
    __shared__ float b2s[16];
    float* hh = (float*)w1hi;            // aliased after K-loop: [64][130]

    const int t = threadIdx.x;
    const int w = t >> 6;                // wave 0..7
    const int l = t & 63;
    const int ln = l & 15;               // node within wave tile
    const int g = l >> 4;                // k-subgroup 0..3
    const int nodeBase = blockIdx.x * 128;

    for (int i = t; i < 1024; i += 512) w2s[i >> 4][i & 15] = W2f[i];
    if (t < 64) b1s[t] = b1f[t];
    if (t < 16) b2s[t] = b2f[t];

#pragma unroll
    for (int i = 0; i < 8; ++i) {
        int c = t + i * 512;
        int row = c >> 6, c8 = c & 63;
        *(bf16x8*)&w1hi[row * 520 + c8 * 8] =
            *(const bf16x8*)(w1hig + (size_t)row * 512 + c8 * 8);
        *(bf16x8*)&w1lo[row * 520 + c8 * 8] =
            *(const bf16x8*)(w1log + (size_t)row * 512 + c8 * 8);
    }
    __syncthreads();

    const int node = nodeBase + w * 16 + ln;
    const bool nv = (node < N);
    const float* xrow = xf + (size_t)node * IN_CH;

    f32x4 acc0 = {0.f, 0.f, 0.f, 0.f};
    f32x4 acc1 = {0.f, 0.f, 0.f, 0.f};
    f32x4 acc2 = {0.f, 0.f, 0.f, 0.f};
    f32x4 acc3 = {0.f, 0.f, 0.f, 0.f};

#pragma unroll
    for (int ki = 0; ki < 16; ++ki) {
        const int kb = ki * 32 + g * 8;
        float xv[8];
#pragma unroll
        for (int e = 0; e < 8; ++e) xv[e] = 0.f;
        if (nv) {
            if (kb + 8 <= IN_CH) {
                float4 v0 = *(const float4*)(xrow + kb);
                float4 v1 = *(const float4*)(xrow + kb + 4);
                xv[0] = v0.x; xv[1] = v0.y; xv[2] = v0.z; xv[3] = v0.w;
                xv[4] = v1.x; xv[5] = v1.y; xv[6] = v1.z; xv[7] = v1.w;
            } else if (kb < IN_CH) {
                float4 v0 = *(const float4*)(xrow + kb);
                xv[0] = v0.x; xv[1] = v0.y; xv[2] = v0.z; xv[3] = v0.w;
            }
        }
        bf16x8 bh, bl;
#pragma unroll
        for (int e = 0; e < 8; ++e) {
            u32 bits = f_as_u(xv[e]);
            bh[e] = (short)(bits >> 16);
            float d = xv[e] - u_as_f(bits & 0xFFFF0000u);
            bl[e] = (short)(f_as_u(d) >> 16);
        }
        const u16* ph = &w1hi[ln * 520 + kb];
        const u16* pl = &w1lo[ln * 520 + kb];
        bf16x8 ah0 = *(const bf16x8*)(ph);
        bf16x8 ah1 = *(const bf16x8*)(ph + 16 * 520);
        bf16x8 ah2 = *(const bf16x8*)(ph + 32 * 520);
        bf16x8 ah3 = *(const bf16x8*)(ph + 48 * 520);
        bf16x8 al0 = *(const bf16x8*)(pl);
        bf16x8 al1 = *(const bf16x8*)(pl + 16 * 520);
        bf16x8 al2 = *(const bf16x8*)(pl + 32 * 520);
        bf16x8 al3 = *(const bf16x8*)(pl + 48 * 520);
        acc0 = __builtin_amdgcn_mfma_f32_16x16x32_bf16(ah0, bh, acc0, 0, 0, 0);
        acc1 = __builtin_amdgcn_mfma_f32_16x16x32_bf16(ah1, bh, acc1, 0, 0, 0);
        acc2 = __builtin_amdgcn_mfma_f32_16x16x32_bf16(ah2, bh, acc2, 0, 0, 0);
        acc3 = __builtin_amdgcn_mfma_f32_16x16x32_bf16(ah3, bh, acc3, 0, 0, 0);
        acc0 = __builtin_amdgcn_mfma_f32_16x16x32_bf16(al0, bh, acc0, 0, 0, 0);
        acc1 = __builtin_amdgcn_mfma_f32_16x16x32_bf16(al1, bh, acc1, 0, 0, 0);
        acc2 = __builtin_amdgcn_mfma_f32_16x16x32_bf16(al2, bh, acc2, 0, 0, 0);
        acc3 = __builtin_amdgcn_mfma_f32_16x16x32_bf16(al3, bh, acc3, 0, 0, 0);
        acc0 = __builtin_amdgcn_mfma_f32_16x16x32_bf16(ah0, bl, acc0, 0, 0, 0);
        acc1 = __builtin_amdgcn_mfma_f32_16x16x32_bf16(ah1, bl, acc1, 0, 0, 0);
        acc2 = __builtin_amdgcn_mfma_f32_16x16x32_bf16(ah2, bl, acc2, 0, 0, 0);
        acc3 = __builtin_amdgcn_mfma_f32_16x16x32_bf16(ah3, bl, acc3, 0, 0, 0);
    }
    __syncthreads();    // all waves done reading w1hi; reuse it as hh

    const int nl = w * 16 + ln;
    const int rb = g * 4;
#pragma unroll
    for (int r = 0; r < 4; ++r) {
        float v0 = acc0[r] + b1s[rb + r];
        float v1 = acc1[r] + b1s[16 + rb + r];
        float v2 = acc2[r] + b1s[32 + rb + r];
        float v3 = acc3[r] + b1s[48 + rb + r];
        hh[(rb + r) * 130 + nl]      = v0 > 0.f ? v0 : 0.f;
        hh[(16 + rb + r) * 130 + nl] = v1 > 0.f ? v1 : 0.f;
        hh[(32 + rb + r) * 130 + nl] = v2 > 0.f ? v2 : 0.f;
        hh[(48 + rb + r) * 130 + nl] = v3 > 0.f ? v3 : 0.f;
    }
    __syncthreads();

    {
        int n = t >> 2;                  // 0..127
        int o4 = (t & 3) * 4;
        float o0 = b2s[o4], o1 = b2s[o4 + 1], o2 = b2s[o4 + 2], o3 = b2s[o4 + 3];
#pragma unroll
        for (int j = 0; j < 64; ++j) {
            float hv = hh[j * 130 + n];
            o0 += hv * w2s[j][o4];     o1 += hv * w2s[j][o4 + 1];
            o2 += hv * w2s[j][o4 + 2]; o3 += hv * w2s[j][o4 + 3];
        }
        int gn = nodeBase + n;
        if (gn < N) {
            float4 o = {o0, o1, o2, o3};
            *(float4*)(h0 + (size_t)gn * 16 + o4) = o;
            float dn = dinv[gn];
            float4 gg = {o0 * dn, o1 * dn, o2 * dn, o3 * dn};
            *(float4*)(gout + (size_t)gn * 16 + o4) = gg;
        }
    }
}

// ---------------- MLP, bf16 storage: MFMA path (hi array only) ----------------
__global__ __launch_bounds__(256) void mlp_mfma_kernel(
    const u16* __restrict__ xh, const u16* __restrict__ w1tg,
    const void* __restrict__ b1v, const void* __restrict__ W2v,
    const void* __restrict__ b2v, const float* __restrict__ dinv,
    float* __restrict__ h0, float* __restrict__ gout,
    const u32* __restrict__ flags, int N)
{
    if (flags[0] != 0u) return;          // f32 storage -> mlp_mfma_f32

    __shared__ __align__(16) u16 w1s[64 * 520];
    __shared__ float w2s[64][16];
    __shared__ float b1s[64];
    __shared__ float b2s[16];
    float* hh = (float*)w1s;

    const u16* b1h = (const u16*)b1v;
    const u16* W2h = (const u16*)W2v;
    const u16* b2h = (const u16*)b2v;

    const int t = threadIdx.x;
    const int w = t >> 6;
    const int l = t & 63;
    const int ln = l & 15;
    const int g = l >> 4;
    const int nodeBase = blockIdx.x * 64;

    for (int i = t; i < 1024; i += 256) w2s[i >> 4][i & 15] = bf2f(W2h[i]);
    if (t < 64) b1s[t] = bf2f(b1h[t]);
    if (t < 16) b2s[t] = bf2f(b2h[t]);

#pragma unroll
    for (int i = 0; i < 16; ++i) {
        int idx = t + i * 256;
        int row = idx >> 6, c8 = idx & 63;
        *(bf16x8*)&w1s[row * 520 + c8 * 8] =
            *(const bf16x8*)(w1tg + (size_t)row * 512 + c8 * 8);
    }
    __syncthreads();

    const int node = nodeBase + w * 16 + ln;
    const bool nv = (node < N);
    const u16* xrow = xh + (size_t)node * IN_CH;

    f32x4 acc0 = {0.f, 0.f, 0.f, 0.f};
    f32x4 acc1 = {0.f, 0.f, 0.f, 0.f};
    f32x4 acc2 = {0.f, 0.f, 0.f, 0.f};
    f32x4 acc3 = {0.f, 0.f, 0.f, 0.f};

#pragma unroll
    for (int ki = 0; ki < 15; ++ki) {
        const int kb = ki * 32 + g * 8;
        bf16x8 b = {0, 0, 0, 0, 0, 0, 0, 0};
        if (nv) b = *(const bf16x8*)(xrow + kb);
        const u16* wp = &w1s[ln * 520 + kb];
        bf16x8 a0 = *(const bf16x8*)(wp);
        bf16x8 a1 = *(const bf16x8*)(wp + 16 * 520);
        bf16x8 a2 = *(const bf16x8*)(wp + 32 * 520);
        bf16x8 a3 = *(const bf16x8*)(wp + 48 * 520);
        acc0 = __builtin_amdgcn_mfma_f32_16x16x32_bf16(a0, b, acc0, 0, 0, 0);
        acc1 = __builtin_amdgcn_mfma_f32_16x16x32_bf16(a1, b, acc1, 0, 0, 0);
        acc2 = __builtin_amdgcn_mfma_f32_16x16x32_bf16(a2, b, acc2, 0, 0, 0);
        acc3 = __builtin_amdgcn_mfma_f32_16x16x32_bf16(a3, b, acc3, 0, 0, 0);
    }
    {
        const int kb = 480 + g * 8;
        bf16x8 b = {0, 0, 0, 0, 0, 0, 0, 0};
        if (nv) {
            if (g < 2) {
                b = *(const bf16x8*)(xrow + kb);
            } else if (g == 2) {
                ushort4 v4 = *(const ushort4*)(xrow + 496);
                b[0] = (short)v4.x; b[1] = (short)v4.y;
                b[2] = (short)v4.z; b[3] = (short)v4.w;
            }
        }
        const u16* wp = &w1s[ln * 520 + kb];
        bf16x8 a0 = *(const bf16x8*)(wp);
        bf16x8 a1 = *(const bf16x8*)(wp + 16 * 520);
        bf16x8 a2 = *(const bf16x8*)(wp + 32 * 520);
        bf16x8 a3 = *(const bf16x8*)(wp + 48 * 520);
        acc0 = __builtin_amdgcn_mfma_f32_16x16x32_bf16(a0, b, acc0, 0, 0, 0);
        acc1 = __builtin_amdgcn_mfma_f32_16x16x32_bf16(a1, b, acc1, 0, 0, 0);
        acc2 = __builtin_amdgcn_mfma_f32_16x16x32_bf16(a2, b, acc2, 0, 0, 0);
        acc3 = __builtin_amdgcn_mfma_f32_16x16x32_bf16(a3, b, acc3, 0, 0, 0);
    }
    __syncthreads();

    const int nl = w * 16 + ln;
    const int rb = g * 4;
#pragma unroll
    for (int r = 0; r < 4; ++r) {
        float v0 = acc0[r] + b1s[rb + r];
        float v1 = acc1[r] + b1s[16 + rb + r];
        float v2 = acc2[r] + b1s[32 + rb + r];
        float v3 = acc3[r] + b1s[48 + rb + r];
        hh[(rb + r) * 65 + nl]      = v0 > 0.f ? v0 : 0.f;
        hh[(16 + rb + r) * 65 + nl] = v1 > 0.f ? v1 : 0.f;
        hh[(32 + rb + r) * 65 + nl] = v2 > 0.f ? v2 : 0.f;
        hh[(48 + rb + r) * 65 + nl] = v3 > 0.f ? v3 : 0.f;
    }
    __syncthreads();

    {
        int n = t >> 2;
        int o4 = (t & 3) * 4;
        float o0 = b2s[o4], o1 = b2s[o4 + 1], o2 = b2s[o4 + 2], o3 = b2s[o4 + 3];
#pragma unroll
        for (int j = 0; j < 64; ++j) {
            float hv = hh[j * 65 + n];
            o0 += hv * w2s[j][o4];     o1 += hv * w2s[j][o4 + 1];
            o2 += hv * w2s[j][o4 + 2]; o3 += hv * w2s[j][o4 + 3];
        }
        int gn = nodeBase + n;
        if (gn < N) {
            float4 o = {o0, o1, o2, o3};
            *(float4*)(h0 + (size_t)gn * 16 + o4) = o;
            float dn = dinv[gn];
            float4 gg = {o0 * dn, o1 * dn, o2 * dn, o3 * dn};
            *(float4*)(gout + (size_t)gn * 16 + o4) = gg;
        }
    }
}

// ---------------- graph preprocessing ----------------
__global__ void zero_u32(u32* __restrict__ p, int n) {
    int i = blockIdx.x * 256 + threadIdx.x;
    if (i < n) p[i] = 0u;
}

__device__ __forceinline__ int ei_src(const int* ei, int E, int e, int i64) {
    return i64 ? ei[2 * e] : ei[e];
}
__device__ __forceinline__ int ei_dst(const int* ei, int E, int e, int i64) {
    return i64 ? ei[2 * (E + e)] : ei[E + e];
}

__global__ void deg_kernel(const int* __restrict__ ei, int E, u32* __restrict__ cnt,
                           const u32* __restrict__ flags) {
    int e = blockIdx.x * 256 + threadIdx.x;
    int i64 = (int)flags[1];
    if (e < E) atomicAdd(&cnt[ei_dst(ei, E, e, i64)], 1u);
}

__global__ void dinv_kernel(const u32* __restrict__ cnt, float* __restrict__ dinv, int N) {
    int i = blockIdx.x * 256 + threadIdx.x;
    if (i < N) {
        float d = (float)(cnt[i] + 1u);      // +1 self-loop
        dinv[i] = rsqrtf(d);
    }
}

__global__ __launch_bounds__(256) void scan1(const u32* __restrict__ cnt,
                                             u32* __restrict__ part, int N) {
    __shared__ u32 s[256];
    int i = blockIdx.x * 256 + threadIdx.x;
    s[threadIdx.x] = (i < N) ? cnt[i] : 0u;
    __syncthreads();
    for (int off = 128; off > 0; off >>= 1) {
        if (threadIdx.x < off) s[threadIdx.x] += s[threadIdx.x + off];
        __syncthreads();
    }
    if (threadIdx.x == 0) part[blockIdx.x] = s[0];
}

__global__ __launch_bounds__(512) void scan2(u32* __restrict__ part,
                                             u32* __restrict__ rowptr, int NB, int N) {
    __shared__ u32 s[512];
    int t = threadIdx.x;
    u32 v = (t < NB) ? part[t] : 0u;
    s[t] = v;
    __syncthreads();
    for (int off = 1; off < 512; off <<= 1) {
        u32 xv = (t >= off) ? s[t - off] : 0u;
        __syncthreads();
        s[t] += xv;
        __syncthreads();
    }
    if (t < NB) part[t] = s[t] - v;          // exclusive block offsets
    if (t == 511) rowptr[N] = s[511];        // total = E
}

__global__ __launch_bounds__(256) void scan3(const u32* __restrict__ cnt,
                                             const u32* __restrict__ part,
                                             u32* __restrict__ rowptr, int N) {
    __shared__ u32 s[256];
    int t = threadIdx.x;
    int i = blockIdx.x * 256 + t;
    u32 v = (i < N) ? cnt[i] : 0u;
    s[t] = v;
    __syncthreads();
    for (int off = 1; off < 256; off <<= 1) {
        u32 xv = (t >= off) ? s[t - off] : 0u;
        __syncthreads();
        s[t] += xv;
        __syncthreads();
    }
    if (i < N) rowptr[i] = part[blockIdx.x] + s[t] - v;
}

// ---------------- CSR fill: two-phase bucket build ----------------
// Within-row order in ent is irrelevant (summed), so bucket b's staging
// region in tmp is exactly [rowptr[lo_b], rowptr[hi_b]) and appends can be
// in any order. Phase A: one pass, block-local LDS bucket counting, one
// global atomic per bucket per block reserves contiguous ranges -> frontier
// writes fill whole 64B lines (fixes measured 14x write amplification).
// Phase B: 8 XCD-pinned groups scatter only their own bucket (read 1.6MB +
// write 1.6MB + fillc 50KB, fits one XCD's 4MB L2).
__global__ void init_bf(const u32* __restrict__ rowptr, u32* __restrict__ bf,
                        int N, int gsz) {
    int t = threadIdx.x;   // 8 threads
    int lo = t * gsz; if (lo > N) lo = N;
    bf[t] = rowptr[lo];
}

#define CHUNK 4096
__global__ __launch_bounds__(256) void bucketA(
    const int* __restrict__ ei, int E, int gsz, int shiftN,
    u32* __restrict__ tmp, u32* __restrict__ bf, const u32* __restrict__ flags)
{
    __shared__ u32 wbuf[CHUNK];
    __shared__ u16 bbuf[CHUNK];
    __shared__ u32 cnt[8], gbase[8], lcnt[8];
    const int i64 = (int)flags[1];
    for (int base = blockIdx.x * CHUNK; base < E; base += gridDim.x * CHUNK) {
        int nval = E - base; if (nval > CHUNK) nval = CHUNK;
        if (threadIdx.x < 8) { cnt[threadIdx.x] = 0u; lcnt[threadIdx.x] = 0u; }
        __syncthreads();
        for (int j = threadIdx.x; j < nval; j += 256) {
            int e = base + j;
            u32 s = (u32)ei_src(ei, E, e, i64);
            u32 d = (u32)ei_dst(ei, E, e, i64);
            u32 b = d / (u32)gsz;
            wbuf[j] = s | ((d - b * (u32)gsz) << shiftN);
            bbuf[j] = (u16)b;
            atomicAdd(&cnt[b], 1u);
        }
        __syncthreads();
        if (threadIdx.x < 8)
            gbase[threadIdx.x] = atomicAdd(&bf[threadIdx.x], cnt[threadIdx.x]);
        __syncthreads();
        for (int j = threadIdx.x; j < nval; j += 256) {
            u32 b = (u32)bbuf[j];
            u32 off = atomicAdd(&lcnt[b], 1u);
            tmp[gbase[b] + off] = wbuf[j];
        }
        __syncthreads();
    }
}

#define FILLB_BPG 64   // blocks per group in phase B; grid = 8 * FILLB_BPG
__global__ __launch_bounds__(256) void bucketB(
    const u32* __restrict__ tmp, const u32* __restrict__ rowptr,
    u32* __restrict__ fillc, u32* __restrict__ ent,
    int N, int gsz, int shiftN)
{
    const int group = blockIdx.x & 7;
    const int bchunk = blockIdx.x >> 3;
    int lo = group * gsz; if (lo > N) lo = N;
    int hi = lo + gsz;    if (hi > N) hi = N;
    if (lo >= hi) return;
    const u32 pstart = rowptr[lo], pend = rowptr[hi];
    const u32 maskN = (1u << shiftN) - 1u;
    const u32 stride = FILLB_BPG * 256;
    for (u32 p = pstart + bchunk * 256 + threadIdx.x; p < pend; p += stride) {
        u32 wd = tmp[p];
        u32 src = wd & maskN;
        u32 c = (u32)lo + (wd >> shiftN);
        u32 pos = rowptr[c] + atomicAdd(&fillc[c], 1u);
        ent[pos] = src;
    }
}

// Fallback (ws too small / N too large to pack): round-4 grouped scatter.
#define FILL_BPG 128
__global__ __launch_bounds__(256) void fill_kernel(
    const int* __restrict__ ei, int E,
    const u32* __restrict__ rowptr, u32* __restrict__ fillc,
    u32* __restrict__ ent, const u32* __restrict__ flags, int N)
{
    const int group = blockIdx.x & 7;
    const int bchunk = blockIdx.x >> 3;
    const int gsz = (N + 7) / 8;
    const int lo = group * gsz;
    const int hi = (lo + gsz < N) ? lo + gsz : N;
    const int i64 = (int)flags[1];
    const int stride = FILL_BPG * 256;
    for (int e = bchunk * 256 + (int)threadIdx.x; e < E; e += stride) {
        int c = ei_dst(ei, E, e, i64);
        if (c >= lo && c < hi) {
            int r = ei_src(ei, E, e, i64);
            u32 p = rowptr[c] + atomicAdd(&fillc[c], 1u);
            ent[p] = (u32)r;
        }
    }
}

// ---------------- APPNP pull step on scaled state g = D^-1/2 h ----------------
// Wave per node. 16-lane group e takes 8 CONTIGUOUS ent entries per 32-edge
// chunk: 8 index loads then 8 independent gathers (no dependent ent->gather
// chain; 8-deep MLP). Channel lanes c=0..15 make each gather a full coalesced
// 64B line. Reduce across e-groups via shfl_xor.
__global__ __launch_bounds__(256) void prop_kernel(
    const u32* __restrict__ ent, const u32* __restrict__ rowptr,
    const float* __restrict__ dinv, const float* __restrict__ gcur,
    const float* __restrict__ h0, float* __restrict__ gnext,
    void* __restrict__ outp, const u32* __restrict__ flags, int N)
{
    const int t = threadIdx.x;
    const int wv = t >> 6;               // wave 0..3 in block
    const int l = t & 63;
    const int c = l & 15;                // channel
    const int e = l >> 4;                // edge subgroup 0..3
    const int n = blockIdx.x * 4 + wv;
    if (n >= N) return;

    const u32 rs = rowptr[n], re = rowptr[n + 1];
    float s = 0.f;
    for (u32 base = rs; base < re; base += 32) {
        const u32 p0 = base + (u32)e * 8;
        u32 idx[8];
#pragma unroll
        for (int j = 0; j < 8; ++j) {
            u32 pj = p0 + (u32)j;
            u32 pc = (pj < re) ? pj : (re - 1);   // re>rs here, re-1 valid
            idx[j] = ent[pc];
        }
#pragma unroll
        for (int j = 0; j < 8; ++j) {
            float v = gcur[(size_t)idx[j] * 16 + c];
            s += (p0 + (u32)j < re) ? v : 0.f;
        }
    }
    s += __shfl_xor(s, 16);
    s += __shfl_xor(s, 32);

    if (e == 0) {
        s += gcur[(size_t)n * 16 + c];   // self loop
        float dn = dinv[n];
        float h = 0.9f * dn * s + 0.1f * h0[(size_t)n * 16 + c];
        if (gnext) {
            gnext[(size_t)n * 16 + c] = dn * h;
        } else {
            if (flags[0]) ((float*)outp)[(size_t)n * 16 + c] = h;
            else          ((u16*)outp)[(size_t)n * 16 + c] = f2bf(h);
        }
    }
}

extern "C" void kernel_launch(void* const* d_in, const int* in_sizes, int n_in,
                              void* d_out, int out_size, void* d_ws, size_t ws_size,
                              hipStream_t stream) {
    const void* x  = d_in[0];
    const int* ei  = (const int*)d_in[1];
    const void* W1 = d_in[2];
    const void* b1 = d_in[3];
    const void* W2 = d_in[4];
    const void* b2 = d_in[5];

    const int N = in_sizes[0] / IN_CH;     // 100000
    const int E = in_sizes[1] / 2;         // 3200000

    float* wf = (float*)d_ws;
    u32*   wu = (u32*)d_ws;

    // workspace layout (4B units)
    size_t oH0   = 0;
    size_t oGA   = oH0 + (size_t)N * 16;
    size_t oGB   = oGA + (size_t)N * 16;
    size_t oCNT  = oGB + (size_t)N * 16;
    size_t oFILL = oCNT + N;
    size_t oDINV = oFILL + N;
    size_t oRP   = oDINV + N;
    size_t oPART = ((oRP + N + 1 + 3) & ~(size_t)3);
    size_t oFLG  = oPART + 512;
    size_t oENT  = oFLG + 4;
    size_t oTMP  = oENT + E;              // bucket staging (E words)
    size_t oBF   = oTMP + E;              // 8 bucket fill counters

    // bucket-path feasibility (packing + workspace)
    int gsz = (N + 7) / 8;
    int shiftN = 1; while ((1 << shiftN) < N && shiftN < 31) shiftN++;
    int shiftL = 1; while ((1 << shiftL) < gsz && shiftL < 31) shiftL++;
    bool canBucket = (ws_size >= (oBF + 8) * 4) && (shiftN + shiftL <= 32);

    // W1T hi/lo scratch (128 KB) overlaid on oGB (dead until prop step 1)
    u16* w1hig = (u16*)(wf + oGB);
    u16* w1log = w1hig + 64 * 512;

    detect_kernel<<<1, 64, 0, stream>>>((const u16*)W1, ei, wu + oFLG);
    w1t_kernel<<<128, 256, 0, stream>>>(W1, w1hig, w1log, wu + oFLG);
    zero_u32<<<(2 * N + 255) / 256, 256, 0, stream>>>(wu + oCNT, 2 * N);
    deg_kernel<<<(E + 255) / 256, 256, 0, stream>>>(ei, E, wu + oCNT, wu + oFLG);
    dinv_kernel<<<(N + 255) / 256, 256, 0, stream>>>(wu + oCNT, wf + oDINV, N);
    mlp_mfma_f32<<<(N + 127) / 128, 512, 0, stream>>>(
        (const float*)x, w1hig, w1log, (const float*)b1, (const float*)W2,
        (const float*)b2, wf + oDINV, wf + oH0, wf + oGA, wu + oFLG, N);
    mlp_mfma_kernel<<<(N + 63) / 64, 256, 0, stream>>>(
        (const u16*)x, w1hig, b1, W2, b2, wf + oDINV, wf + oH0, wf + oGA,
        wu + oFLG, N);
    int NB = (N + 255) / 256;
    scan1<<<NB, 256, 0, stream>>>(wu + oCNT, wu + oPART, N);
    scan2<<<1, 512, 0, stream>>>(wu + oPART, wu + oRP, NB, N);
    scan3<<<NB, 256, 0, stream>>>(wu + oCNT, wu + oPART, wu + oRP, N);

    if (canBucket) {
        init_bf<<<1, 8, 0, stream>>>(wu + oRP, wu + oBF, N, gsz);
        int nblkA = (E + CHUNK - 1) / CHUNK;
        bucketA<<<nblkA, 256, 0, stream>>>(ei, E, gsz, shiftN,
                                           wu + oTMP, wu + oBF, wu + oFLG);
        bucketB<<<8 * FILLB_BPG, 256, 0, stream>>>(wu + oTMP, wu + oRP,
                                                   wu + oFILL, wu + oENT,
                                                   N, gsz, shiftN);
    } else {
        fill_kernel<<<8 * FILL_BPG, 256, 0, stream>>>(ei, E, wu + oRP,
                                                      wu + oFILL, wu + oENT,
                                                      wu + oFLG, N);
    }

    const float* cur = wf + oGA;
    for (int k = 0; k < KSTEPS; ++k) {
        bool last = (k == KSTEPS - 1);
        float* nxt = last ? nullptr : (wf + ((k & 1) ? oGA : oGB));
        prop_kernel<<<(N + 3) / 4, 256, 0, stream>>>(
            wu + oENT, wu + oRP, wf + oDINV, cur, wf + oH0,
            nxt, last ? d_out : nullptr, wu + oFLG, N);
        if (!last) cur = nxt;
    }
}

// Round 6
// 992.488 us; speedup vs baseline: 1.6249x; 1.0260x over previous
//
#include <hip/hip_runtime.h>

#define IN_CH 500
#define KSTEPS 10

typedef unsigned int u32;
typedef unsigned short u16;
typedef short bf16x8 __attribute__((ext_vector_type(8)));
typedef float f32x4 __attribute__((ext_vector_type(4)));

__device__ __forceinline__ float bf2f(u16 u) {
    union { u32 i; float f; } v; v.i = ((u32)u) << 16; return v.f;
}
__device__ __forceinline__ u16 f2bf(float f) {
    union { float f; u32 i; } v; v.f = f;
    u32 x = v.i;
    return (u16)((x + 0x7FFFu + ((x >> 16) & 1u)) >> 16);  // RNE
}
__device__ __forceinline__ u32 f_as_u(float f) {
    union { float f; u32 i; } v; v.f = f; return v.i;
}
__device__ __forceinline__ float u_as_f(u32 i) {
    union { u32 i; float f; } v; v.i = i; return v.f;
}

// ---------------- runtime dtype detection ----------------
__global__ void detect_kernel(const u16* __restrict__ w1raw,
                              const int* __restrict__ ei,
                              u32* __restrict__ flags) {
    int t = threadIdx.x;  // 64 threads
    float m = fabsf(bf2f(w1raw[t]));
    m = fmaxf(m, fabsf(bf2f(w1raw[64 + t])));
    m = fmaxf(m, fabsf(bf2f(w1raw[128 + t])));
    for (int off = 32; off; off >>= 1) m = fmaxf(m, __shfl_down(m, off));
    u32 o = (u32)ei[2 * t + 1];
    o |= (u32)ei[2 * t + 129];
    for (int off = 32; off; off >>= 1) o |= __shfl_down(o, off);
    if (t == 0) {
        flags[0] = (m > 10.0f) ? 1u : 0u;
        flags[1] = (o == 0u) ? 1u : 0u;
    }
}

// ---------------- W1 transpose + hi/lo split precompute ----------------
__global__ void w1t_kernel(const void* __restrict__ W1v,
                           u16* __restrict__ hi, u16* __restrict__ lo,
                           const u32* __restrict__ flags) {
    int i = blockIdx.x * 256 + threadIdx.x;   // 0 .. 32767
    if (i >= 64 * 512) return;
    int h = i >> 9;
    int k = i & 511;
    u16 vh = 0, vl = 0;
    if (k < IN_CH) {
        if (flags[0]) {
            float v = ((const float*)W1v)[(size_t)k * 64 + h];
            u32 bits = f_as_u(v);
            vh = (u16)(bits >> 16);
            float d = v - u_as_f(bits & 0xFFFF0000u);
            vl = (u16)(f_as_u(d) >> 16);
        } else {
            vh = ((const u16*)W1v)[(size_t)k * 64 + h];
        }
    }
    hi[(size_t)h * 512 + k] = vh;
    lo[(size_t)h * 512 + k] = vl;
}

// ---------------- MLP, f32 storage: split-bf16 MFMA path ----------------
__global__ __launch_bounds__(512) void mlp_mfma_f32(
    const float* __restrict__ xf, const u16* __restrict__ w1hig,
    const u16* __restrict__ w1log, const float* __restrict__ b1f,
    const float* __restrict__ W2f, const float* __restrict__ b2f,
    const float* __restrict__ dinv, float* __restrict__ h0,
    float* __restrict__ gout, const u32* __restrict__ flags, int N)
{
    if (flags[0] == 0u) return;          // bf16 storage -> mlp_mfma_kernel

    __shared__ __align__(16) u16 w1hi[64 * 520];
    __shared__ __align__(16) u16 w1lo[64 * 520];
    __shared__ float w2s[64][16];
    __shared__ float b1s[64];
    __shared__ float b2s[16];
    float* hh = (float*)w1hi;            // aliased after K-loop: [64][130]

    const int t = threadIdx.x;
    const int w = t >> 6;                // wave 0..7
    const int l = t & 63;
    const int ln = l & 15;               // node within wave tile
    const int g = l >> 4;                // k-subgroup 0..3
    const int nodeBase = blockIdx.x * 128;

    for (int i = t; i < 1024; i += 512) w2s[i >> 4][i & 15] = W2f[i];
    if (t < 64) b1s[t] = b1f[t];
    if (t < 16) b2s[t] = b2f[t];

#pragma unroll
    for (int i = 0; i < 8; ++i) {
        int c = t + i * 512;
        int row = c >> 6, c8 = c & 63;
        *(bf16x8*)&w1hi[row * 520 + c8 * 8] =
            *(const bf16x8*)(w1hig + (size_t)row * 512 + c8 * 8);
        *(bf16x8*)&w1lo[row * 520 + c8 * 8] =
            *(const bf16x8*)(w1log + (size_t)row * 512 + c8 * 8);
    }
    __syncthreads();

    const int node = nodeBase + w * 16 + ln;
    const bool nv = (node < N);
    const float* xrow = xf + (size_t)node * IN_CH;

    f32x4 acc0 = {0.f, 0.f, 0.f, 0.f};
    f32x4 acc1 = {0.f, 0.f, 0.f, 0.f};
    f32x4 acc2 = {0.f, 0.f, 0.f, 0.f};
    f32x4 acc3 = {0.f, 0.f, 0.f, 0.f};

#pragma unroll
    for (int ki = 0; ki < 16; ++ki) {
        const int kb = ki * 32 + g * 8;
        float xv[8];
#pragma unroll
        for (int e = 0; e < 8; ++e) xv[e] = 0.f;
        if (nv) {
            if (kb + 8 <= IN_CH) {
                float4 v0 = *(const float4*)(xrow + kb);
                float4 v1 = *(const float4*)(xrow + kb + 4);
                xv[0] = v0.x; xv[1] = v0.y; xv[2] = v0.z; xv[3] = v0.w;
                xv[4] = v1.x; xv[5] = v1.y; xv[6] = v1.z; xv[7] = v1.w;
            } else if (kb < IN_CH) {
                float4 v0 = *(const float4*)(xrow + kb);
                xv[0] = v0.x; xv[1] = v0.y; xv[2] = v0.z; xv[3] = v0.w;
            }
        }
        bf16x8 bh, bl;
#pragma unroll
        for (int e = 0; e < 8; ++e) {
            u32 bits = f_as_u(xv[e]);
            bh[e] = (short)(bits >> 16);
            float d = xv[e] - u_as_f(bits & 0xFFFF0000u);
            bl[e] = (short)(f_as_u(d) >> 16);
        }
        const u16* ph = &w1hi[ln * 520 + kb];
        const u16* pl = &w1lo[ln * 520 + kb];
        bf16x8 ah0 = *(const bf16x8*)(ph);
        bf16x8 ah1 = *(const bf16x8*)(ph + 16 * 520);
        bf16x8 ah2 = *(const bf16x8*)(ph + 32 * 520);
        bf16x8 ah3 = *(const bf16x8*)(ph + 48 * 520);
        bf16x8 al0 = *(const bf16x8*)(pl);
        bf16x8 al1 = *(const bf16x8*)(pl + 16 * 520);
        bf16x8 al2 = *(const bf16x8*)(pl + 32 * 520);
        bf16x8 al3 = *(const bf16x8*)(pl + 48 * 520);
        acc0 = __builtin_amdgcn_mfma_f32_16x16x32_bf16(ah0, bh, acc0, 0, 0, 0);
        acc1 = __builtin_amdgcn_mfma_f32_16x16x32_bf16(ah1, bh, acc1, 0, 0, 0);
        acc2 = __builtin_amdgcn_mfma_f32_16x16x32_bf16(ah2, bh, acc2, 0, 0, 0);
        acc3 = __builtin_amdgcn_mfma_f32_16x16x32_bf16(ah3, bh, acc3, 0, 0, 0);
        acc0 = __builtin_amdgcn_mfma_f32_16x16x32_bf16(al0, bh, acc0, 0, 0, 0);
        acc1 = __builtin_amdgcn_mfma_f32_16x16x32_bf16(al1, bh, acc1, 0, 0, 0);
        acc2 = __builtin_amdgcn_mfma_f32_16x16x32_bf16(al2, bh, acc2, 0, 0, 0);
        acc3 = __builtin_amdgcn_mfma_f32_16x16x32_bf16(al3, bh, acc3, 0, 0, 0);
        acc0 = __builtin_amdgcn_mfma_f32_16x16x32_bf16(ah0, bl, acc0, 0, 0, 0);
        acc1 = __builtin_amdgcn_mfma_f32_16x16x32_bf16(ah1, bl, acc1, 0, 0, 0);
        acc2 = __builtin_amdgcn_mfma_f32_16x16x32_bf16(ah2, bl, acc2, 0, 0, 0);
        acc3 = __builtin_amdgcn_mfma_f32_16x16x32_bf16(ah3, bl, acc3, 0, 0, 0);
    }
    __syncthreads();    // all waves done reading w1hi; reuse it as hh

    const int nl = w * 16 + ln;
    const int rb = g * 4;
#pragma unroll
    for (int r = 0; r < 4; ++r) {
        float v0 = acc0[r] + b1s[rb + r];
        float v1 = acc1[r] + b1s[16 + rb + r];
        float v2 = acc2[r] + b1s[32 + rb + r];
        float v3 = acc3[r] + b1s[48 + rb + r];
        hh[(rb + r) * 130 + nl]      = v0 > 0.f ? v0 : 0.f;
        hh[(16 + rb + r) * 130 + nl] = v1 > 0.f ? v1 : 0.f;
        hh[(32 + rb + r) * 130 + nl] = v2 > 0.f ? v2 : 0.f;
        hh[(48 + rb + r) * 130 + nl] = v3 > 0.f ? v3 : 0.f;
    }
    __syncthreads();

    {
        int n = t >> 2;                  // 0..127
        int o4 = (t & 3) * 4;
        float o0 = b2s[o4], o1 = b2s[o4 + 1], o2 = b2s[o4 + 2], o3 = b2s[o4 + 3];
#pragma unroll
        for (int j = 0; j < 64; ++j) {
            float hv = hh[j * 130 + n];
            o0 += hv * w2s[j][o4];     o1 += hv * w2s[j][o4 + 1];
            o2 += hv * w2s[j][o4 + 2]; o3 += hv * w2s[j][o4 + 3];
        }
        int gn = nodeBase + n;
        if (gn < N) {
            float4 o = {o0, o1, o2, o3};
            *(float4*)(h0 + (size_t)gn * 16 + o4) = o;
            float dn = dinv[gn];
            float4 gg = {o0 * dn, o1 * dn, o2 * dn, o3 * dn};
            *(float4*)(gout + (size_t)gn * 16 + o4) = gg;
        }
    }
}

// ---------------- MLP, bf16 storage: MFMA path (hi array only) ----------------
__global__ __launch_bounds__(256) void mlp_mfma_kernel(
    const u16* __restrict__ xh, const u16* __restrict__ w1tg,
    const void* __restrict__ b1v, const void* __restrict__ W2v,
    const void* __restrict__ b2v, const float* __restrict__ dinv,
    float* __restrict__ h0, float* __restrict__ gout,
    const u32* __restrict__ flags, int N)
{
    if (flags[0] != 0u) return;          // f32 storage -> mlp_mfma_f32

    __shared__ __align__(16) u16 w1s[64 * 520];
    __shared__ float w2s[64][16];
    __shared__ float b1s[64];
    __shared__ float b2s[16];
    float* hh = (float*)w1s;

    const u16* b1h = (const u16*)b1v;
    const u16* W2h = (const u16*)W2v;
    const u16* b2h = (const u16*)b2v;

    const int t = threadIdx.x;
    const int w = t >> 6;
    const int l = t & 63;
    const int ln = l & 15;
    const int g = l >> 4;
    const int nodeBase = blockIdx.x * 64;

    for (int i = t; i < 1024; i += 256) w2s[i >> 4][i & 15] = bf2f(W2h[i]);
    if (t < 64) b1s[t] = bf2f(b1h[t]);
    if (t < 16) b2s[t] = bf2f(b2h[t]);

#pragma unroll
    for (int i = 0; i < 16; ++i) {
        int idx = t + i * 256;
        int row = idx >> 6, c8 = idx & 63;
        *(bf16x8*)&w1s[row * 520 + c8 * 8] =
            *(const bf16x8*)(w1tg + (size_t)row * 512 + c8 * 8);
    }
    __syncthreads();

    const int node = nodeBase + w * 16 + ln;
    const bool nv = (node < N);
    const u16* xrow = xh + (size_t)node * IN_CH;

    f32x4 acc0 = {0.f, 0.f, 0.f, 0.f};
    f32x4 acc1 = {0.f, 0.f, 0.f, 0.f};
    f32x4 acc2 = {0.f, 0.f, 0.f, 0.f};
    f32x4 acc3 = {0.f, 0.f, 0.f, 0.f};

#pragma unroll
    for (int ki = 0; ki < 15; ++ki) {
        const int kb = ki * 32 + g * 8;
        bf16x8 b = {0, 0, 0, 0, 0, 0, 0, 0};
        if (nv) b = *(const bf16x8*)(xrow + kb);
        const u16* wp = &w1s[ln * 520 + kb];
        bf16x8 a0 = *(const bf16x8*)(wp);
        bf16x8 a1 = *(const bf16x8*)(wp + 16 * 520);
        bf16x8 a2 = *(const bf16x8*)(wp + 32 * 520);
        bf16x8 a3 = *(const bf16x8*)(wp + 48 * 520);
        acc0 = __builtin_amdgcn_mfma_f32_16x16x32_bf16(a0, b, acc0, 0, 0, 0);
        acc1 = __builtin_amdgcn_mfma_f32_16x16x32_bf16(a1, b, acc1, 0, 0, 0);
        acc2 = __builtin_amdgcn_mfma_f32_16x16x32_bf16(a2, b, acc2, 0, 0, 0);
        acc3 = __builtin_amdgcn_mfma_f32_16x16x32_bf16(a3, b, acc3, 0, 0, 0);
    }
    {
        const int kb = 480 + g * 8;
        bf16x8 b = {0, 0, 0, 0, 0, 0, 0, 0};
        if (nv) {
            if (g < 2) {
                b = *(const bf16x8*)(xrow + kb);
            } else if (g == 2) {
                ushort4 v4 = *(const ushort4*)(xrow + 496);
                b[0] = (short)v4.x; b[1] = (short)v4.y;
                b[2] = (short)v4.z; b[3] = (short)v4.w;
            }
        }
        const u16* wp = &w1s[ln * 520 + kb];
        bf16x8 a0 = *(const bf16x8*)(wp);
        bf16x8 a1 = *(const bf16x8*)(wp + 16 * 520);
        bf16x8 a2 = *(const bf16x8*)(wp + 32 * 520);
        bf16x8 a3 = *(const bf16x8*)(wp + 48 * 520);
        acc0 = __builtin_amdgcn_mfma_f32_16x16x32_bf16(a0, b, acc0, 0, 0, 0);
        acc1 = __builtin_amdgcn_mfma_f32_16x16x32_bf16(a1, b, acc1, 0, 0, 0);
        acc2 = __builtin_amdgcn_mfma_f32_16x16x32_bf16(a2, b, acc2, 0, 0, 0);
        acc3 = __builtin_amdgcn_mfma_f32_16x16x32_bf16(a3, b, acc3, 0, 0, 0);
    }
    __syncthreads();

    const int nl = w * 16 + ln;
    const int rb = g * 4;
#pragma unroll
    for (int r = 0; r < 4; ++r) {
        float v0 = acc0[r] + b1s[rb + r];
        float v1 = acc1[r] + b1s[16 + rb + r];
        float v2 = acc2[r] + b1s[32 + rb + r];
        float v3 = acc3[r] + b1s[48 + rb + r];
        hh[(rb + r) * 65 + nl]      = v0 > 0.f ? v0 : 0.f;
        hh[(16 + rb + r) * 65 + nl] = v1 > 0.f ? v1 : 0.f;
        hh[(32 + rb + r) * 65 + nl] = v2 > 0.f ? v2 : 0.f;
        hh[(48 + rb + r) * 65 + nl] = v3 > 0.f ? v3 : 0.f;
    }
    __syncthreads();

    {
        int n = t >> 2;
        int o4 = (t & 3) * 4;
        float o0 = b2s[o4], o1 = b2s[o4 + 1], o2 = b2s[o4 + 2], o3 = b2s[o4 + 3];
#pragma unroll
        for (int j = 0; j < 64; ++j) {
            float hv = hh[j * 65 + n];
            o0 += hv * w2s[j][o4];     o1 += hv * w2s[j][o4 + 1];
            o2 += hv * w2s[j][o4 + 2]; o3 += hv * w2s[j][o4 + 3];
        }
        int gn = nodeBase + n;
        if (gn < N) {
            float4 o = {o0, o1, o2, o3};
            *(float4*)(h0 + (size_t)gn * 16 + o4) = o;
            float dn = dinv[gn];
            float4 gg = {o0 * dn, o1 * dn, o2 * dn, o3 * dn};
            *(float4*)(gout + (size_t)gn * 16 + o4) = gg;
        }
    }
}

// ---------------- graph preprocessing ----------------
__global__ void zero_u32(u32* __restrict__ p, int n) {
    int i = blockIdx.x * 256 + threadIdx.x;
    if (i < n) p[i] = 0u;
}

__device__ __forceinline__ int ei_src(const int* ei, int E, int e, int i64) {
    return i64 ? ei[2 * e] : ei[e];
}
__device__ __forceinline__ int ei_dst(const int* ei, int E, int e, int i64) {
    return i64 ? ei[2 * (E + e)] : ei[E + e];
}

__global__ void deg_kernel(const int* __restrict__ ei, int E, u32* __restrict__ cnt,
                           const u32* __restrict__ flags) {
    int e = blockIdx.x * 256 + threadIdx.x;
    int i64 = (int)flags[1];
    if (e < E) atomicAdd(&cnt[ei_dst(ei, E, e, i64)], 1u);
}

__global__ void dinv_kernel(const u32* __restrict__ cnt, float* __restrict__ dinv, int N) {
    int i = blockIdx.x * 256 + threadIdx.x;
    if (i < N) {
        float d = (float)(cnt[i] + 1u);      // +1 self-loop
        dinv[i] = rsqrtf(d);
    }
}

__global__ __launch_bounds__(256) void scan1(const u32* __restrict__ cnt,
                                             u32* __restrict__ part, int N) {
    __shared__ u32 s[256];
    int i = blockIdx.x * 256 + threadIdx.x;
    s[threadIdx.x] = (i < N) ? cnt[i] : 0u;
    __syncthreads();
    for (int off = 128; off > 0; off >>= 1) {
        if (threadIdx.x < off) s[threadIdx.x] += s[threadIdx.x + off];
        __syncthreads();
    }
    if (threadIdx.x == 0) part[blockIdx.x] = s[0];
}

__global__ __launch_bounds__(512) void scan2(u32* __restrict__ part,
                                             u32* __restrict__ rowptr, int NB, int N) {
    __shared__ u32 s[512];
    int t = threadIdx.x;
    u32 v = (t < NB) ? part[t] : 0u;
    s[t] = v;
    __syncthreads();
    for (int off = 1; off < 512; off <<= 1) {
        u32 xv = (t >= off) ? s[t - off] : 0u;
        __syncthreads();
        s[t] += xv;
        __syncthreads();
    }
    if (t < NB) part[t] = s[t] - v;          // exclusive block offsets
    if (t == 511) rowptr[N] = s[511];        // total = E
}

__global__ __launch_bounds__(256) void scan3(const u32* __restrict__ cnt,
                                             const u32* __restrict__ part,
                                             u32* __restrict__ rowptr, int N) {
    __shared__ u32 s[256];
    int t = threadIdx.x;
    int i = blockIdx.x * 256 + t;
    u32 v = (i < N) ? cnt[i] : 0u;
    s[t] = v;
    __syncthreads();
    for (int off = 1; off < 256; off <<= 1) {
        u32 xv = (t >= off) ? s[t - off] : 0u;
        __syncthreads();
        s[t] += xv;
        __syncthreads();
    }
    if (i < N) rowptr[i] = part[blockIdx.x] + s[t] - v;
}

// ---------------- CSR fill: two-phase bucket build, 512-node buckets ----------
// gsz = 512 nodes (pow2), NBUCK = ceil(N/512). Phase A: LDS bucket count ->
// one global atomic per bucket per block reserves contiguous tmp ranges ->
// packed append (runs ~16 words = one 64B line). Phase B: ONE BLOCK PER
// BUCKET, rowptr slice + fill counters in LDS, scatter confined to the
// block's private ~64KB ent region -> every ent line has a single writer
// block, so write amplification cannot occur regardless of which XCD the
// block lands on (round-5 lesson: XCD pinning via blockIdx%8 is unreliable;
// measured 136MB WRITE_SIZE for 12.8MB payload).
#define GSZ_SHIFT 9
#define GSZ 512
#define MAXBUCK 1024
__global__ void init_bf(const u32* __restrict__ rowptr, u32* __restrict__ bf,
                        int N, int nbuck) {
    int t = blockIdx.x * 256 + threadIdx.x;
    if (t < nbuck) {
        int lo = t << GSZ_SHIFT; if (lo > N) lo = N;
        bf[t] = rowptr[lo];
    }
}

#define CHUNK 4096
__global__ __launch_bounds__(256) void bucketA(
    const int* __restrict__ ei, int E, int shiftN, int nbuck,
    u32* __restrict__ tmp, u32* __restrict__ bf, const u32* __restrict__ flags)
{
    __shared__ u32 wbuf[CHUNK];
    __shared__ u16 bbuf[CHUNK];
    __shared__ u32 cnt[MAXBUCK], gbase[MAXBUCK], lcnt[MAXBUCK];
    const int i64 = (int)flags[1];
    for (int base = blockIdx.x * CHUNK; base < E; base += gridDim.x * CHUNK) {
        int nval = E - base; if (nval > CHUNK) nval = CHUNK;
        for (int b = threadIdx.x; b < nbuck; b += 256) { cnt[b] = 0u; lcnt[b] = 0u; }
        __syncthreads();
        for (int j = threadIdx.x; j < nval; j += 256) {
            int e = base + j;
            u32 s = (u32)ei_src(ei, E, e, i64);
            u32 d = (u32)ei_dst(ei, E, e, i64);
            u32 b = d >> GSZ_SHIFT;
            wbuf[j] = s | ((d & (GSZ - 1u)) << shiftN);
            bbuf[j] = (u16)b;
            atomicAdd(&cnt[b], 1u);
        }
        __syncthreads();
        for (int b = threadIdx.x; b < nbuck; b += 256)
            if (cnt[b]) gbase[b] = atomicAdd(&bf[b], cnt[b]);
        __syncthreads();
        for (int j = threadIdx.x; j < nval; j += 256) {
            u32 b = (u32)bbuf[j];
            u32 off = atomicAdd(&lcnt[b], 1u);
            tmp[gbase[b] + off] = wbuf[j];
        }
        __syncthreads();
    }
}

__global__ __launch_bounds__(512) void bucketB(
    const u32* __restrict__ tmp, const u32* __restrict__ rowptr,
    u32* __restrict__ ent, int N, int shiftN)
{
    __shared__ u32 rp[GSZ + 1];
    __shared__ u32 lfill[GSZ];
    const int lo = blockIdx.x << GSZ_SHIFT;
    int hi = lo + GSZ; if (hi > N) hi = N;
    const int nn = hi - lo;
    for (int i = threadIdx.x; i <= nn; i += 512) rp[i] = rowptr[lo + i];
    for (int i = threadIdx.x; i < nn; i += 512) lfill[i] = 0u;
    __syncthreads();
    const u32 pstart = rp[0], pend = rp[nn];
    const u32 mask = (1u << shiftN) - 1u;
    for (u32 p = pstart + threadIdx.x; p < pend; p += 512) {
        u32 wd = tmp[p];
        u32 src = wd & mask;
        u32 dl = wd >> shiftN;
        u32 pos = rp[dl] + atomicAdd(&lfill[dl], 1u);
        ent[pos] = src;
    }
}

// Fallback (packing/ws constraints fail): round-4 grouped scatter.
#define FILL_BPG 128
__global__ __launch_bounds__(256) void fill_kernel(
    const int* __restrict__ ei, int E,
    const u32* __restrict__ rowptr, u32* __restrict__ fillc,
    u32* __restrict__ ent, const u32* __restrict__ flags, int N)
{
    const int group = blockIdx.x & 7;
    const int bchunk = blockIdx.x >> 3;
    const int gsz = (N + 7) / 8;
    const int lo = group * gsz;
    const int hi = (lo + gsz < N) ? lo + gsz : N;
    const int i64 = (int)flags[1];
    const int stride = FILL_BPG * 256;
    for (int e = bchunk * 256 + (int)threadIdx.x; e < E; e += stride) {
        int c = ei_dst(ei, E, e, i64);
        if (c >= lo && c < hi) {
            int r = ei_src(ei, E, e, i64);
            u32 p = rowptr[c] + atomicAdd(&fillc[c], 1u);
            ent[p] = (u32)r;
        }
    }
}

// ---------------- APPNP pull step on scaled state g = D^-1/2 h ----------------
// Wave per node, 4 lanes per edge: lane = (eg = l>>2 edge slot 0..15,
// c4 = (l&3)*4 channel quad). Per 32-edge chunk: 2 idx loads + 2 float4
// gathers per lane (vs 8+8 scalar) -> ~5x fewer VMEM instrs in the
// latency-bound chain. Reduce across eg via shfl_xor; lanes 0..3 epilogue.
__global__ __launch_bounds__(256) void prop_kernel(
    const u32* __restrict__ ent, const u32* __restrict__ rowptr,
    const float* __restrict__ dinv, const float* __restrict__ gcur,
    const float* __restrict__ h0, float* __restrict__ gnext,
    void* __restrict__ outp, const u32* __restrict__ flags, int N)
{
    const int t = threadIdx.x;
    const int wv = t >> 6;               // wave 0..3 in block
    const int l = t & 63;
    const int eg = l >> 2;               // edge slot 0..15
    const int c4 = (l & 3) * 4;          // channel quad base
    const int n = blockIdx.x * 4 + wv;
    if (n >= N) return;

    const u32 rs = rowptr[n], re = rowptr[n + 1];
    f32x4 acc = {0.f, 0.f, 0.f, 0.f};
    for (u32 base = rs; base < re; base += 32) {
        u32 pA = base + (u32)eg;
        u32 pB = pA + 16u;
        u32 iA = ent[pA < re ? pA : re - 1u];   // re > rs inside loop
        u32 iB = ent[pB < re ? pB : re - 1u];
        f32x4 vA = *(const f32x4*)(gcur + (size_t)iA * 16 + c4);
        f32x4 vB = *(const f32x4*)(gcur + (size_t)iB * 16 + c4);
        if (pA < re) acc += vA;
        if (pB < re) acc += vB;
    }
#pragma unroll
    for (int off = 4; off <= 32; off <<= 1) {
        acc[0] += __shfl_xor(acc[0], off);
        acc[1] += __shfl_xor(acc[1], off);
        acc[2] += __shfl_xor(acc[2], off);
        acc[3] += __shfl_xor(acc[3], off);
    }

    if (eg == 0) {                        // lanes 0..3
        f32x4 self = *(const f32x4*)(gcur + (size_t)n * 16 + c4);
        f32x4 h0v  = *(const f32x4*)(h0 + (size_t)n * 16 + c4);
        float dn = dinv[n];
        f32x4 h;
#pragma unroll
        for (int j = 0; j < 4; ++j)
            h[j] = 0.9f * dn * (acc[j] + self[j]) + 0.1f * h0v[j];
        if (gnext) {
            f32x4 gg = {dn * h[0], dn * h[1], dn * h[2], dn * h[3]};
            *(f32x4*)(gnext + (size_t)n * 16 + c4) = gg;
        } else if (flags[0]) {
            *(f32x4*)((float*)outp + (size_t)n * 16 + c4) = h;
        } else {
            ushort4 o = {f2bf(h[0]), f2bf(h[1]), f2bf(h[2]), f2bf(h[3])};
            *(ushort4*)((u16*)outp + (size_t)n * 16 + c4) = o;
        }
    }
}

extern "C" void kernel_launch(void* const* d_in, const int* in_sizes, int n_in,
                              void* d_out, int out_size, void* d_ws, size_t ws_size,
                              hipStream_t stream) {
    const void* x  = d_in[0];
    const int* ei  = (const int*)d_in[1];
    const void* W1 = d_in[2];
    const void* b1 = d_in[3];
    const void* W2 = d_in[4];
    const void* b2 = d_in[5];

    const int N = in_sizes[0] / IN_CH;     // 100000
    const int E = in_sizes[1] / 2;         // 3200000

    float* wf = (float*)d_ws;
    u32*   wu = (u32*)d_ws;

    // workspace layout (4B units)
    size_t oH0   = 0;
    size_t oGA   = oH0 + (size_t)N * 16;
    size_t oGB   = oGA + (size_t)N * 16;
    size_t oCNT  = oGB + (size_t)N * 16;
    size_t oFILL = oCNT + N;
    size_t oDINV = oFILL + N;
    size_t oRP   = oDINV + N;
    size_t oPART = ((oRP + N + 1 + 3) & ~(size_t)3);
    size_t oFLG  = oPART + 512;
    size_t oENT  = oFLG + 4;
    size_t oTMP  = oENT + E;              // bucket staging (E words)
    size_t oBF   = oTMP + E;              // bucket fill counters

    int nbuck = (N + GSZ - 1) >> GSZ_SHIFT;
    int shiftN = 1; while ((1 << shiftN) < N && shiftN < 31) shiftN++;
    bool canBucket = (ws_size >= (oBF + MAXBUCK) * 4) &&
                     (shiftN + GSZ_SHIFT <= 32) && (nbuck <= MAXBUCK);

    // W1T hi/lo scratch (128 KB) overlaid on oGB (dead until prop step 1)
    u16* w1hig = (u16*)(wf + oGB);
    u16* w1log = w1hig + 64 * 512;

    detect_kernel<<<1, 64, 0, stream>>>((const u16*)W1, ei, wu + oFLG);
    w1t_kernel<<<128, 256, 0, stream>>>(W1, w1hig, w1log, wu + oFLG);
    int nzero = canBucket ? N : 2 * N;     // cnt (+fillc only for fallback)
    zero_u32<<<(nzero + 255) / 256, 256, 0, stream>>>(wu + oCNT, nzero);
    deg_kernel<<<(E + 255) / 256, 256, 0, stream>>>(ei, E, wu + oCNT, wu + oFLG);
    dinv_kernel<<<(N + 255) / 256, 256, 0, stream>>>(wu + oCNT, wf + oDINV, N);
    mlp_mfma_f32<<<(N + 127) / 128, 512, 0, stream>>>(
        (const float*)x, w1hig, w1log, (const float*)b1, (const float*)W2,
        (const float*)b2, wf + oDINV, wf + oH0, wf + oGA, wu + oFLG, N);
    mlp_mfma_kernel<<<(N + 63) / 64, 256, 0, stream>>>(
        (const u16*)x, w1hig, b1, W2, b2, wf + oDINV, wf + oH0, wf + oGA,
        wu + oFLG, N);
    int NB = (N + 255) / 256;
    scan1<<<NB, 256, 0, stream>>>(wu + oCNT, wu + oPART, N);
    scan2<<<1, 512, 0, stream>>>(wu + oPART, wu + oRP, NB, N);
    scan3<<<NB, 256, 0, stream>>>(wu + oCNT, wu + oPART, wu + oRP, N);

    if (canBucket) {
        init_bf<<<(nbuck + 255) / 256, 256, 0, stream>>>(wu + oRP, wu + oBF,
                                                         N, nbuck);
        int nblkA = (E + CHUNK - 1) / CHUNK;
        bucketA<<<nblkA, 256, 0, stream>>>(ei, E, shiftN, nbuck,
                                           wu + oTMP, wu + oBF, wu + oFLG);
        bucketB<<<nbuck, 512, 0, stream>>>(wu + oTMP, wu + oRP, wu + oENT,
                                           N, shiftN);
    } else {
        fill_kernel<<<8 * FILL_BPG, 256, 0, stream>>>(ei, E, wu + oRP,
                                                      wu + oFILL, wu + oENT,
                                                      wu + oFLG, N);
    }

    const float* cur = wf + oGA;
    for (int k = 0; k < KSTEPS; ++k) {
        bool last = (k == KSTEPS - 1);
        float* nxt = last ? nullptr : (wf + ((k & 1) ? oGA : oGB));
        prop_kernel<<<(N + 3) / 4, 256, 0, stream>>>(
            wu + oENT, wu + oRP, wf + oDINV, cur, wf + oH0,
            nxt, last ? d_out : nullptr, wu + oFLG, N);
        if (!last) cur = nxt;
    }
}

// Round 7
// 883.907 us; speedup vs baseline: 1.8245x; 1.1228x over previous
//
#include <hip/hip_runtime.h>

#define IN_CH 500
#define KSTEPS 10

typedef unsigned int u32;
typedef unsigned short u16;
typedef short bf16x8 __attribute__((ext_vector_type(8)));
typedef float f32x4 __attribute__((ext_vector_type(4)));

__device__ __forceinline__ float bf2f(u16 u) {
    union { u32 i; float f; } v; v.i = ((u32)u) << 16; return v.f;
}
__device__ __forceinline__ u16 f2bf(float f) {
    union { float f; u32 i; } v; v.f = f;
    u32 x = v.i;
    return (u16)((x + 0x7FFFu + ((x >> 16) & 1u)) >> 16);  // RNE
}
__device__ __forceinline__ u32 f_as_u(float f) {
    union { float f; u32 i; } v; v.f = f; return v.i;
}
__device__ __forceinline__ float u_as_f(u32 i) {
    union { u32 i; float f; } v; v.i = i; return v.f;
}

// ---------------- runtime dtype detection ----------------
__global__ void detect_kernel(const u16* __restrict__ w1raw,
                              const int* __restrict__ ei,
                              u32* __restrict__ flags) {
    int t = threadIdx.x;  // 64 threads
    float m = fabsf(bf2f(w1raw[t]));
    m = fmaxf(m, fabsf(bf2f(w1raw[64 + t])));
    m = fmaxf(m, fabsf(bf2f(w1raw[128 + t])));
    for (int off = 32; off; off >>= 1) m = fmaxf(m, __shfl_down(m, off));
    u32 o = (u32)ei[2 * t + 1];
    o |= (u32)ei[2 * t + 129];
    for (int off = 32; off; off >>= 1) o |= __shfl_down(o, off);
    if (t == 0) {
        flags[0] = (m > 10.0f) ? 1u : 0u;
        flags[1] = (o == 0u) ? 1u : 0u;
    }
}

// ---------------- W1 transpose + hi/lo split precompute ----------------
__global__ void w1t_kernel(const void* __restrict__ W1v,
                           u16* __restrict__ hi, u16* __restrict__ lo,
                           const u32* __restrict__ flags) {
    int i = blockIdx.x * 256 + threadIdx.x;   // 0 .. 32767
    if (i >= 64 * 512) return;
    int h = i >> 9;
    int k = i & 511;
    u16 vh = 0, vl = 0;
    if (k < IN_CH) {
        if (flags[0]) {
            float v = ((const float*)W1v)[(size_t)k * 64 + h];
            u32 bits = f_as_u(v);
            vh = (u16)(bits >> 16);
            float d = v - u_as_f(bits & 0xFFFF0000u);
            vl = (u16)(f_as_u(d) >> 16);
        } else {
            vh = ((const u16*)W1v)[(size_t)k * 64 + h];
        }
    }
    hi[(size_t)h * 512 + k] = vh;
    lo[(size_t)h * 512 + k] = vl;
}

// ---------------- MLP, f32 storage: split-bf16 MFMA path ----------------
__global__ __launch_bounds__(512) void mlp_mfma_f32(
    const float* __restrict__ xf, const u16* __restrict__ w1hig,
    const u16* __restrict__ w1log, const float* __restrict__ b1f,
    const float* __restrict__ W2f, const float* __restrict__ b2f,
    const float* __restrict__ dinv, float* __restrict__ h0,
    float* __restrict__ gout, const u32* __restrict__ flags, int N)
{
    if (flags[0] == 0u) return;          // bf16 storage -> mlp_mfma_kernel

    __shared__ __align__(16) u16 w1hi[64 * 520];
    __shared__ __align__(16) u16 w1lo[64 * 520];
    __shared__ float w2s[64][16];
    __shared__ float b1s[64];
    __shared__ float b2s[16];
    float* hh = (float*)w1hi;            // aliased after K-loop: [64][130]

    const int t = threadIdx.x;
    const int w = t >> 6;                // wave 0..7
    const int l = t & 63;
    const int ln = l & 15;               // node within wave tile
    const int g = l >> 4;                // k-subgroup 0..3
    const int nodeBase = blockIdx.x * 128;

    for (int i = t; i < 1024; i += 512) w2s[i >> 4][i & 15] = W2f[i];
    if (t < 64) b1s[t] = b1f[t];
    if (t < 16) b2s[t] = b2f[t];

#pragma unroll
    for (int i = 0; i < 8; ++i) {
        int c = t + i * 512;
        int row = c >> 6, c8 = c & 63;
        *(bf16x8*)&w1hi[row * 520 + c8 * 8] =
            *(const bf16x8*)(w1hig + (size_t)row * 512 + c8 * 8);
        *(bf16x8*)&w1lo[row * 520 + c8 * 8] =
            *(const bf16x8*)(w1log + (size_t)row * 512 + c8 * 8);
    }
    __syncthreads();

    const int node = nodeBase + w * 16 + ln;
    const bool nv = (node < N);
    const float* xrow = xf + (size_t)node * IN_CH;

    f32x4 acc0 = {0.f, 0.f, 0.f, 0.f};
    f32x4 acc1 = {0.f, 0.f, 0.f, 0.f};
    f32x4 acc2 = {0.f, 0.f, 0.f, 0.f};
    f32x4 acc3 = {0.f, 0.f, 0.f, 0.f};

#pragma unroll
    for (int ki = 0; ki < 16; ++ki) {
        const int kb = ki * 32 + g * 8;
        float xv[8];
#pragma unroll
        for (int e = 0; e < 8; ++e) xv[e] = 0.f;
        if (nv) {
            if (kb + 8 <= IN_CH) {
                float4 v0 = *(const float4*)(xrow + kb);
                float4 v1 = *(const float4*)(xrow + kb + 4);
                xv[0] = v0.x; xv[1] = v0.y; xv[2] = v0.z; xv[3] = v0.w;
                xv[4] = v1.x; xv[5] = v1.y; xv[6] = v1.z; xv[7] = v1.w;
            } else if (kb < IN_CH) {
                float4 v0 = *(const float4*)(xrow + kb);
                xv[0] = v0.x; xv[1] = v0.y; xv[2] = v0.z; xv[3] = v0.w;
            }
        }
        bf16x8 bh, bl;
#pragma unroll
        for (int e = 0; e < 8; ++e) {
            u32 bits = f_as_u(xv[e]);
            bh[e] = (short)(bits >> 16);
            float d = xv[e] - u_as_f(bits & 0xFFFF0000u);
            bl[e] = (short)(f_as_u(d) >> 16);
        }
        const u16* ph = &w1hi[ln * 520 + kb];
        const u16* pl = &w1lo[ln * 520 + kb];
        bf16x8 ah0 = *(const bf16x8*)(ph);
        bf16x8 ah1 = *(const bf16x8*)(ph + 16 * 520);
        bf16x8 ah2 = *(const bf16x8*)(ph + 32 * 520);
        bf16x8 ah3 = *(const bf16x8*)(ph + 48 * 520);
        bf16x8 al0 = *(const bf16x8*)(pl);
        bf16x8 al1 = *(const bf16x8*)(pl + 16 * 520);
        bf16x8 al2 = *(const bf16x8*)(pl + 32 * 520);
        bf16x8 al3 = *(const bf16x8*)(pl + 48 * 520);
        acc0 = __builtin_amdgcn_mfma_f32_16x16x32_bf16(ah0, bh, acc0, 0, 0, 0);
        acc1 = __builtin_amdgcn_mfma_f32_16x16x32_bf16(ah1, bh, acc1, 0, 0, 0);
        acc2 = __builtin_amdgcn_mfma_f32_16x16x32_bf16(ah2, bh, acc2, 0, 0, 0);
        acc3 = __builtin_amdgcn_mfma_f32_16x16x32_bf16(ah3, bh, acc3, 0, 0, 0);
        acc0 = __builtin_amdgcn_mfma_f32_16x16x32_bf16(al0, bh, acc0, 0, 0, 0);
        acc1 = __builtin_amdgcn_mfma_f32_16x16x32_bf16(al1, bh, acc1, 0, 0, 0);
        acc2 = __builtin_amdgcn_mfma_f32_16x16x32_bf16(al2, bh, acc2, 0, 0, 0);
        acc3 = __builtin_amdgcn_mfma_f32_16x16x32_bf16(al3, bh, acc3, 0, 0, 0);
        acc0 = __builtin_amdgcn_mfma_f32_16x16x32_bf16(ah0, bl, acc0, 0, 0, 0);
        acc1 = __builtin_amdgcn_mfma_f32_16x16x32_bf16(ah1, bl, acc1, 0, 0, 0);
        acc2 = __builtin_amdgcn_mfma_f32_16x16x32_bf16(ah2, bl, acc2, 0, 0, 0);
        acc3 = __builtin_amdgcn_mfma_f32_16x16x32_bf16(ah3, bl, acc3, 0, 0, 0);
    }
    __syncthreads();    // all waves done reading w1hi; reuse it as hh

    const int nl = w * 16 + ln;
    const int rb = g * 4;
#pragma unroll
    for (int r = 0; r < 4; ++r) {
        float v0 = acc0[r] + b1s[rb + r];
        float v1 = acc1[r] + b1s[16 + rb + r];
        float v2 = acc2[r] + b1s[32 + rb + r];
        float v3 = acc3[r] + b1s[48 + rb + r];
        hh[(rb + r) * 130 + nl]      = v0 > 0.f ? v0 : 0.f;
        hh[(16 + rb + r) * 130 + nl] = v1 > 0.f ? v1 : 0.f;
        hh[(32 + rb + r) * 130 + nl] = v2 > 0.f ? v2 : 0.f;
        hh[(48 + rb + r) * 130 + nl] = v3 > 0.f ? v3 : 0.f;
    }
    __syncthreads();

    {
        int n = t >> 2;                  // 0..127
        int o4 = (t & 3) * 4;
        float o0 = b2s[o4], o1 = b2s[o4 + 1], o2 = b2s[o4 + 2], o3 = b2s[o4 + 3];
#pragma unroll
        for (int j = 0; j < 64; ++j) {
            float hv = hh[j * 130 + n];
            o0 += hv * w2s[j][o4];     o1 += hv * w2s[j][o4 + 1];
            o2 += hv * w2s[j][o4 + 2]; o3 += hv * w2s[j][o4 + 3];
        }
        int gn = nodeBase + n;
        if (gn < N) {
            float4 o = {o0, o1, o2, o3};
            *(float4*)(h0 + (size_t)gn * 16 + o4) = o;
            float dn = dinv[gn];
            float4 gg = {o0 * dn, o1 * dn, o2 * dn, o3 * dn};
            *(float4*)(gout + (size_t)gn * 16 + o4) = gg;
        }
    }
}

// ---------------- MLP, bf16 storage: MFMA path (hi array only) ----------------
__global__ __launch_bounds__(256) void mlp_mfma_kernel(
    const u16* __restrict__ xh, const u16* __restrict__ w1tg,
    const void* __restrict__ b1v, const void* __restrict__ W2v,
    const void* __restrict__ b2v, const float* __restrict__ dinv,
    float* __restrict__ h0, float* __restrict__ gout,
    const u32* __restrict__ flags, int N)
{
    if (flags[0] != 0u) return;          // f32 storage -> mlp_mfma_f32

    __shared__ __align__(16) u16 w1s[64 * 520];
    __shared__ float w2s[64][16];
    __shared__ float b1s[64];
    __shared__ float b2s[16];
    float* hh = (float*)w1s;

    const u16* b1h = (const u16*)b1v;
    const u16* W2h = (const u16*)W2v;
    const u16* b2h = (const u16*)b2v;

    const int t = threadIdx.x;
    const int w = t >> 6;
    const int l = t & 63;
    const int ln = l & 15;
    const int g = l >> 4;
    const int nodeBase = blockIdx.x * 64;

    for (int i = t; i < 1024; i += 256) w2s[i >> 4][i & 15] = bf2f(W2h[i]);
    if (t < 64) b1s[t] = bf2f(b1h[t]);
    if (t < 16) b2s[t] = bf2f(b2h[t]);

#pragma unroll
    for (int i = 0; i < 16; ++i) {
        int idx = t + i * 256;
        int row = idx >> 6, c8 = idx & 63;
        *(bf16x8*)&w1s[row * 520 + c8 * 8] =
            *(const bf16x8*)(w1tg + (size_t)row * 512 + c8 * 8);
    }
    __syncthreads();

    const int node = nodeBase + w * 16 + ln;
    const bool nv = (node < N);
    const u16* xrow = xh + (size_t)node * IN_CH;

    f32x4 acc0 = {0.f, 0.f, 0.f, 0.f};
    f32x4 acc1 = {0.f, 0.f, 0.f, 0.f};
    f32x4 acc2 = {0.f, 0.f, 0.f, 0.f};
    f32x4 acc3 = {0.f, 0.f, 0.f, 0.f};

#pragma unroll
    for (int ki = 0; ki < 15; ++ki) {
        const int kb = ki * 32 + g * 8;
        bf16x8 b = {0, 0, 0, 0, 0, 0, 0, 0};
        if (nv) b = *(const bf16x8*)(xrow + kb);
        const u16* wp = &w1s[ln * 520 + kb];
        bf16x8 a0 = *(const bf16x8*)(wp);
        bf16x8 a1 = *(const bf16x8*)(wp + 16 * 520);
        bf16x8 a2 = *(const bf16x8*)(wp + 32 * 520);
        bf16x8 a3 = *(const bf16x8*)(wp + 48 * 520);
        acc0 = __builtin_amdgcn_mfma_f32_16x16x32_bf16(a0, b, acc0, 0, 0, 0);
        acc1 = __builtin_amdgcn_mfma_f32_16x16x32_bf16(a1, b, acc1, 0, 0, 0);
        acc2 = __builtin_amdgcn_mfma_f32_16x16x32_bf16(a2, b, acc2, 0, 0, 0);
        acc3 = __builtin_amdgcn_mfma_f32_16x16x32_bf16(a3, b, acc3, 0, 0, 0);
    }
    {
        const int kb = 480 + g * 8;
        bf16x8 b = {0, 0, 0, 0, 0, 0, 0, 0};
        if (nv) {
            if (g < 2) {
                b = *(const bf16x8*)(xrow + kb);
            } else if (g == 2) {
                ushort4 v4 = *(const ushort4*)(xrow + 496);
                b[0] = (short)v4.x; b[1] = (short)v4.y;
                b[2] = (short)v4.z; b[3] = (short)v4.w;
            }
        }
        const u16* wp = &w1s[ln * 520 + kb];
        bf16x8 a0 = *(const bf16x8*)(wp);
        bf16x8 a1 = *(const bf16x8*)(wp + 16 * 520);
        bf16x8 a2 = *(const bf16x8*)(wp + 32 * 520);
        bf16x8 a3 = *(const bf16x8*)(wp + 48 * 520);
        acc0 = __builtin_amdgcn_mfma_f32_16x16x32_bf16(a0, b, acc0, 0, 0, 0);
        acc1 = __builtin_amdgcn_mfma_f32_16x16x32_bf16(a1, b, acc1, 0, 0, 0);
        acc2 = __builtin_amdgcn_mfma_f32_16x16x32_bf16(a2, b, acc2, 0, 0, 0);
        acc3 = __builtin_amdgcn_mfma_f32_16x16x32_bf16(a3, b, acc3, 0, 0, 0);
    }
    __syncthreads();

    const int nl = w * 16 + ln;
    const int rb = g * 4;
#pragma unroll
    for (int r = 0; r < 4; ++r) {
        float v0 = acc0[r] + b1s[rb + r];
        float v1 = acc1[r] + b1s[16 + rb + r];
        float v2 = acc2[r] + b1s[32 + rb + r];
        float v3 = acc3[r] + b1s[48 + rb + r];
        hh[(rb + r) * 65 + nl]      = v0 > 0.f ? v0 : 0.f;
        hh[(16 + rb + r) * 65 + nl] = v1 > 0.f ? v1 : 0.f;
        hh[(32 + rb + r) * 65 + nl] = v2 > 0.f ? v2 : 0.f;
        hh[(48 + rb + r) * 65 + nl] = v3 > 0.f ? v3 : 0.f;
    }
    __syncthreads();

    {
        int n = t >> 2;
        int o4 = (t & 3) * 4;
        float o0 = b2s[o4], o1 = b2s[o4 + 1], o2 = b2s[o4 + 2], o3 = b2s[o4 + 3];
#pragma unroll
        for (int j = 0; j < 64; ++j) {
            float hv = hh[j * 65 + n];
            o0 += hv * w2s[j][o4];     o1 += hv * w2s[j][o4 + 1];
            o2 += hv * w2s[j][o4 + 2]; o3 += hv * w2s[j][o4 + 3];
        }
        int gn = nodeBase + n;
        if (gn < N) {
            float4 o = {o0, o1, o2, o3};
            *(float4*)(h0 + (size_t)gn * 16 + o4) = o;
            float dn = dinv[gn];
            float4 gg = {o0 * dn, o1 * dn, o2 * dn, o3 * dn};
            *(float4*)(gout + (size_t)gn * 16 + o4) = gg;
        }
    }
}

// ---------------- graph preprocessing ----------------
__global__ void zero_u32(u32* __restrict__ p, int n) {
    int i = blockIdx.x * 256 + threadIdx.x;
    if (i < n) p[i] = 0u;
}

__device__ __forceinline__ int ei_src(const int* ei, int E, int e, int i64) {
    return i64 ? ei[2 * e] : ei[e];
}
__device__ __forceinline__ int ei_dst(const int* ei, int E, int e, int i64) {
    return i64 ? ei[2 * (E + e)] : ei[E + e];
}

// -------- fallback-path kernels (non-bucket) --------
__global__ void deg_kernel(const int* __restrict__ ei, int E, u32* __restrict__ cnt,
                           const u32* __restrict__ flags) {
    int e = blockIdx.x * 256 + threadIdx.x;
    int i64 = (int)flags[1];
    if (e < E) atomicAdd(&cnt[ei_dst(ei, E, e, i64)], 1u);
}

__global__ void dinv_kernel(const u32* __restrict__ cnt, float* __restrict__ dinv, int N) {
    int i = blockIdx.x * 256 + threadIdx.x;
    if (i < N) {
        float d = (float)(cnt[i] + 1u);      // +1 self-loop
        dinv[i] = rsqrtf(d);
    }
}

__global__ __launch_bounds__(256) void scan1(const u32* __restrict__ cnt,
                                             u32* __restrict__ part, int N) {
    __shared__ u32 s[256];
    int i = blockIdx.x * 256 + threadIdx.x;
    s[threadIdx.x] = (i < N) ? cnt[i] : 0u;
    __syncthreads();
    for (int off = 128; off > 0; off >>= 1) {
        if (threadIdx.x < off) s[threadIdx.x] += s[threadIdx.x + off];
        __syncthreads();
    }
    if (threadIdx.x == 0) part[blockIdx.x] = s[0];
}

__global__ __launch_bounds__(512) void scan2(u32* __restrict__ part,
                                             u32* __restrict__ rowptr, int NB, int N) {
    __shared__ u32 s[512];
    int t = threadIdx.x;
    u32 v = (t < NB) ? part[t] : 0u;
    s[t] = v;
    __syncthreads();
    for (int off = 1; off < 512; off <<= 1) {
        u32 xv = (t >= off) ? s[t - off] : 0u;
        __syncthreads();
        s[t] += xv;
        __syncthreads();
    }
    if (t < NB) part[t] = s[t] - v;          // exclusive block offsets
    if (t == 511) rowptr[N] = s[511];        // total = E
}

__global__ __launch_bounds__(256) void scan3(const u32* __restrict__ cnt,
                                             const u32* __restrict__ part,
                                             u32* __restrict__ rowptr, int N) {
    __shared__ u32 s[256];
    int t = threadIdx.x;
    int i = blockIdx.x * 256 + t;
    u32 v = (i < N) ? cnt[i] : 0u;
    s[t] = v;
    __syncthreads();
    for (int off = 1; off < 256; off <<= 1) {
        u32 xv = (t >= off) ? s[t - off] : 0u;
        __syncthreads();
        s[t] += xv;
        __syncthreads();
    }
    if (i < N) rowptr[i] = part[blockIdx.x] + s[t] - v;
}

#define FILL_BPG 128
__global__ __launch_bounds__(256) void fill_kernel(
    const int* __restrict__ ei, int E,
    const u32* __restrict__ rowptr, u32* __restrict__ fillc,
    u32* __restrict__ ent, const u32* __restrict__ flags, int N)
{
    const int group = blockIdx.x & 7;
    const int bchunk = blockIdx.x >> 3;
    const int gsz = (N + 7) / 8;
    const int lo = group * gsz;
    const int hi = (lo + gsz < N) ? lo + gsz : N;
    const int i64 = (int)flags[1];
    const int stride = FILL_BPG * 256;
    for (int e = bchunk * 256 + (int)threadIdx.x; e < E; e += stride) {
        int c = ei_dst(ei, E, e, i64);
        if (c >= lo && c < hi) {
            int r = ei_src(ei, E, e, i64);
            u32 p = rowptr[c] + atomicAdd(&fillc[c], 1u);
            ent[p] = (u32)r;
        }
    }
}

// ---------------- bucket-path CSR build, atomics-minimized ----------------
// Round-6 lesson: 3.2M device-scope atomicAdds = ~32B RMW each at the
// coherence point -> 100MB WRITE_SIZE (deg_kernel, 129us). The bucket
// pipeline already owns all the structure needed to avoid them:
//   histA:   per-block LDS histogram of BUCKET counts (196) -> ~100K
//            global atomics total.
//   scanB:   1-block scan -> bucket bases; rowptr[lo_b] == bbase[b] since
//            buckets are contiguous node ranges.
//   bucketA: append packed (src, dstLocal) into tmp regions (coalesced).
//   bucketB2: one block per bucket: LDS degree histogram of its own slice,
//            dinv + global rowptr from an in-block exclusive scan (coalesced
//            writes), then block-private scatter into ent (single writer
//            per line).
#define GSZ_SHIFT 9
#define GSZ 512
#define MAXBUCK 1024
#define CHUNK 4096

__global__ __launch_bounds__(256) void histA(
    const int* __restrict__ ei, int E, int nbuck,
    u32* __restrict__ bcnt, const u32* __restrict__ flags)
{
    __shared__ u32 lb[MAXBUCK];
    const int i64 = (int)flags[1];
    for (int b = threadIdx.x; b < nbuck; b += 256) lb[b] = 0u;
    __syncthreads();
    const int stride = gridDim.x * 256;
    for (int e = blockIdx.x * 256 + (int)threadIdx.x; e < E; e += stride) {
        u32 d = (u32)ei_dst(ei, E, e, i64);
        atomicAdd(&lb[d >> GSZ_SHIFT], 1u);
    }
    __syncthreads();
    for (int b = threadIdx.x; b < nbuck; b += 256)
        if (lb[b]) atomicAdd(&bcnt[b], lb[b]);
}

__global__ __launch_bounds__(1024) void scanB(
    const u32* __restrict__ bcnt, u32* __restrict__ bbase, u32* __restrict__ bf,
    u32* __restrict__ rowptr, int nbuck, int N, int E)
{
    __shared__ u32 s[MAXBUCK];
    int t = threadIdx.x;
    u32 v = (t < nbuck) ? bcnt[t] : 0u;
    s[t] = v;
    __syncthreads();
    for (int off = 1; off < MAXBUCK; off <<= 1) {
        u32 xv = (t >= off) ? s[t - off] : 0u;
        __syncthreads();
        s[t] += xv;
        __syncthreads();
    }
    if (t < nbuck) {
        u32 excl = s[t] - v;
        bbase[t] = excl;
        bf[t] = excl;
    }
    if (t == 0) { bbase[nbuck] = (u32)E; rowptr[N] = (u32)E; }
}

__global__ __launch_bounds__(256) void bucketA(
    const int* __restrict__ ei, int E, int shiftN, int nbuck,
    u32* __restrict__ tmp, u32* __restrict__ bf, const u32* __restrict__ flags)
{
    __shared__ u32 wbuf[CHUNK];
    __shared__ u16 bbuf[CHUNK];
    __shared__ u32 cnt[MAXBUCK], gbase[MAXBUCK], lcnt[MAXBUCK];
    const int i64 = (int)flags[1];
    for (int base = blockIdx.x * CHUNK; base < E; base += gridDim.x * CHUNK) {
        int nval = E - base; if (nval > CHUNK) nval = CHUNK;
        for (int b = threadIdx.x; b < nbuck; b += 256) { cnt[b] = 0u; lcnt[b] = 0u; }
        __syncthreads();
        for (int j = threadIdx.x; j < nval; j += 256) {
            int e = base + j;
            u32 s = (u32)ei_src(ei, E, e, i64);
            u32 d = (u32)ei_dst(ei, E, e, i64);
            u32 b = d >> GSZ_SHIFT;
            wbuf[j] = s | ((d & (GSZ - 1u)) << shiftN);
            bbuf[j] = (u16)b;
            atomicAdd(&cnt[b], 1u);
        }
        __syncthreads();
        for (int b = threadIdx.x; b < nbuck; b += 256)
            if (cnt[b]) gbase[b] = atomicAdd(&bf[b], cnt[b]);
        __syncthreads();
        for (int j = threadIdx.x; j < nval; j += 256) {
            u32 b = (u32)bbuf[j];
            u32 off = atomicAdd(&lcnt[b], 1u);
            tmp[gbase[b] + off] = wbuf[j];
        }
        __syncthreads();
    }
}

__global__ __launch_bounds__(512) void bucketB2(
    const u32* __restrict__ tmp, const u32* __restrict__ bbase,
    u32* __restrict__ rowptr, float* __restrict__ dinv,
    u32* __restrict__ ent, int N, int shiftN)
{
    __shared__ u32 deg[GSZ];
    __shared__ u32 rp[GSZ];
    __shared__ u32 lfill[GSZ];
    const int b = blockIdx.x;
    const int lo = b << GSZ_SHIFT;
    int hi = lo + GSZ; if (hi > N) hi = N;
    const int nn = hi - lo;
    if (nn <= 0) return;
    const u32 base = bbase[b], bend = bbase[b + 1];
    const int t = threadIdx.x;
    deg[t] = 0u; lfill[t] = 0u;
    __syncthreads();
    const u32 mask = (1u << shiftN) - 1u;
    for (u32 p = base + t; p < bend; p += 512)
        atomicAdd(&deg[tmp[p] >> shiftN], 1u);
    __syncthreads();
    u32 v = (t < nn) ? deg[t] : 0u;
    if (t < nn) dinv[lo + t] = rsqrtf((float)(v + 1u));
    rp[t] = v;
    __syncthreads();
    for (int off = 1; off < GSZ; off <<= 1) {
        u32 xv = (t >= off) ? rp[t - off] : 0u;
        __syncthreads();
        rp[t] += xv;
        __syncthreads();
    }
    u32 myrp = base + rp[t] - v;         // exclusive scan + bucket base
    __syncthreads();
    rp[t] = myrp;
    if (t < nn) rowptr[lo + t] = myrp;
    __syncthreads();
    for (u32 p = base + t; p < bend; p += 512) {
        u32 wd = tmp[p];
        u32 src = wd & mask;
        u32 dl = wd >> shiftN;
        u32 pos = rp[dl] + atomicAdd(&lfill[dl], 1u);
        ent[pos] = src;
    }
}

// ---------------- APPNP pull step on scaled state g = D^-1/2 h ----------------
// Wave per node, 4 lanes per edge: lane = (eg = l>>2 edge slot 0..15,
// c4 = (l&3)*4 channel quad). Per 32-edge chunk: 2 idx loads + 2 float4
// gathers per lane. Reduce across eg via shfl_xor; lanes 0..3 epilogue.
__global__ __launch_bounds__(256) void prop_kernel(
    const u32* __restrict__ ent, const u32* __restrict__ rowptr,
    const float* __restrict__ dinv, const float* __restrict__ gcur,
    const float* __restrict__ h0, float* __restrict__ gnext,
    void* __restrict__ outp, const u32* __restrict__ flags, int N)
{
    const int t = threadIdx.x;
    const int wv = t >> 6;               // wave 0..3 in block
    const int l = t & 63;
    const int eg = l >> 2;               // edge slot 0..15
    const int c4 = (l & 3) * 4;          // channel quad base
    const int n = blockIdx.x * 4 + wv;
    if (n >= N) return;

    const u32 rs = rowptr[n], re = rowptr[n + 1];
    f32x4 acc = {0.f, 0.f, 0.f, 0.f};
    for (u32 base = rs; base < re; base += 32) {
        u32 pA = base + (u32)eg;
        u32 pB = pA + 16u;
        u32 iA = ent[pA < re ? pA : re - 1u];   // re > rs inside loop
        u32 iB = ent[pB < re ? pB : re - 1u];
        f32x4 vA = *(const f32x4*)(gcur + (size_t)iA * 16 + c4);
        f32x4 vB = *(const f32x4*)(gcur + (size_t)iB * 16 + c4);
        if (pA < re) acc += vA;
        if (pB < re) acc += vB;
    }
#pragma unroll
    for (int off = 4; off <= 32; off <<= 1) {
        acc[0] += __shfl_xor(acc[0], off);
        acc[1] += __shfl_xor(acc[1], off);
        acc[2] += __shfl_xor(acc[2], off);
        acc[3] += __shfl_xor(acc[3], off);
    }

    if (eg == 0) {                        // lanes 0..3
        f32x4 self = *(const f32x4*)(gcur + (size_t)n * 16 + c4);
        f32x4 h0v  = *(const f32x4*)(h0 + (size_t)n * 16 + c4);
        float dn = dinv[n];
        f32x4 h;
#pragma unroll
        for (int j = 0; j < 4; ++j)
            h[j] = 0.9f * dn * (acc[j] + self[j]) + 0.1f * h0v[j];
        if (gnext) {
            f32x4 gg = {dn * h[0], dn * h[1], dn * h[2], dn * h[3]};
            *(f32x4*)(gnext + (size_t)n * 16 + c4) = gg;
        } else if (flags[0]) {
            *(f32x4*)((float*)outp + (size_t)n * 16 + c4) = h;
        } else {
            ushort4 o = {f2bf(h[0]), f2bf(h[1]), f2bf(h[2]), f2bf(h[3])};
            *(ushort4*)((u16*)outp + (size_t)n * 16 + c4) = o;
        }
    }
}

extern "C" void kernel_launch(void* const* d_in, const int* in_sizes, int n_in,
                              void* d_out, int out_size, void* d_ws, size_t ws_size,
                              hipStream_t stream) {
    const void* x  = d_in[0];
    const int* ei  = (const int*)d_in[1];
    const void* W1 = d_in[2];
    const void* b1 = d_in[3];
    const void* W2 = d_in[4];
    const void* b2 = d_in[5];

    const int N = in_sizes[0] / IN_CH;     // 100000
    const int E = in_sizes[1] / 2;         // 3200000

    float* wf = (float*)d_ws;
    u32*   wu = (u32*)d_ws;

    // workspace layout (4B units)
    size_t oH0   = 0;
    size_t oGA   = oH0 + (size_t)N * 16;
    size_t oGB   = oGA + (size_t)N * 16;
    size_t oCNT  = oGB + (size_t)N * 16;
    size_t oFILL = oCNT + N;
    size_t oDINV = oFILL + N;
    size_t oRP   = oDINV + N;
    size_t oPART = ((oRP + N + 1 + 3) & ~(size_t)3);
    size_t oFLG  = oPART + 512;
    size_t oENT  = oFLG + 4;
    size_t oTMP  = oENT + E;              // bucket staging (E words)
    size_t oBF   = oTMP + E;              // bucket append cursors
    size_t oBC   = oBF + MAXBUCK;         // bucket counts
    size_t oBB   = oBC + MAXBUCK;         // bucket bases (nbuck+1)

    int nbuck = (N + GSZ - 1) >> GSZ_SHIFT;
    int shiftN = 1; while ((1 << shiftN) < N && shiftN < 31) shiftN++;
    bool canBucket = (ws_size >= (oBB + MAXBUCK + 1) * 4) &&
                     (shiftN + GSZ_SHIFT <= 32) && (nbuck <= MAXBUCK);

    // W1T hi/lo scratch (128 KB) overlaid on oGB (dead until prop step 1)
    u16* w1hig = (u16*)(wf + oGB);
    u16* w1log = w1hig + 64 * 512;

    detect_kernel<<<1, 64, 0, stream>>>((const u16*)W1, ei, wu + oFLG);
    w1t_kernel<<<128, 256, 0, stream>>>(W1, w1hig, w1log, wu + oFLG);

    if (canBucket) {
        zero_u32<<<(MAXBUCK + 255) / 256, 256, 0, stream>>>(wu + oBC, MAXBUCK);
        histA<<<512, 256, 0, stream>>>(ei, E, nbuck, wu + oBC, wu + oFLG);
        scanB<<<1, 1024, 0, stream>>>(wu + oBC, wu + oBB, wu + oBF,
                                      wu + oRP, nbuck, N, E);
        int nblkA = (E + CHUNK - 1) / CHUNK;
        bucketA<<<nblkA, 256, 0, stream>>>(ei, E, shiftN, nbuck,
                                           wu + oTMP, wu + oBF, wu + oFLG);
        bucketB2<<<nbuck, 512, 0, stream>>>(wu + oTMP, wu + oBB, wu + oRP,
                                            wf + oDINV, wu + oENT, N, shiftN);
    } else {
        zero_u32<<<(2 * N + 255) / 256, 256, 0, stream>>>(wu + oCNT, 2 * N);
        deg_kernel<<<(E + 255) / 256, 256, 0, stream>>>(ei, E, wu + oCNT,
                                                        wu + oFLG);
        dinv_kernel<<<(N + 255) / 256, 256, 0, stream>>>(wu + oCNT,
                                                         wf + oDINV, N);
        int NB = (N + 255) / 256;
        scan1<<<NB, 256, 0, stream>>>(wu + oCNT, wu + oPART, N);
        scan2<<<1, 512, 0, stream>>>(wu + oPART, wu + oRP, NB, N);
        scan3<<<NB, 256, 0, stream>>>(wu + oCNT, wu + oPART, wu + oRP, N);
        fill_kernel<<<8 * FILL_BPG, 256, 0, stream>>>(ei, E, wu + oRP,
                                                      wu + oFILL, wu + oENT,
                                                      wu + oFLG, N);
    }

    mlp_mfma_f32<<<(N + 127) / 128, 512, 0, stream>>>(
        (const float*)x, w1hig, w1log, (const float*)b1, (const float*)W2,
        (const float*)b2, wf + oDINV, wf + oH0, wf + oGA, wu + oFLG, N);
    mlp_mfma_kernel<<<(N + 63) / 64, 256, 0, stream>>>(
        (const u16*)x, w1hig, b1, W2, b2, wf + oDINV, wf + oH0, wf + oGA,
        wu + oFLG, N);

    const float* cur = wf + oGA;
    for (int k = 0; k < KSTEPS; ++k) {
        bool last = (k == KSTEPS - 1);
        float* nxt = last ? nullptr : (wf + ((k & 1) ? oGA : oGB));
        prop_kernel<<<(N + 3) / 4, 256, 0, stream>>>(
            wu + oENT, wu + oRP, wf + oDINV, cur, wf + oH0,
            nxt, last ? d_out : nullptr, wu + oFLG, N);
        if (!last) cur = nxt;
    }
}